// Round 1
// baseline (9399.149 us; speedup 1.0000x reference)
//
#include <hip/hip_runtime.h>

#define N_NODES 50000
#define E_EDGES 800000
#define E_EXT   850000   // + self loops
#define IN_CH   128
#define HC      256
#define NHEAD   8
#define CH      32
#define NGRAPH  256

// ---------------- GEMM: Hout[M][HC] = X[M][F] @ W[HC][F]^T ----------------
__global__ __launch_bounds__(256) void gemm_kernel(
    const float* __restrict__ X, const float* __restrict__ W,
    float* __restrict__ Hout, int M, int F)
{
    __shared__ float Xs[64][33];
    __shared__ float Ws[64][33];
    const int bm = blockIdx.x * 64;
    const int bn = blockIdx.y * 64;
    const int tid = threadIdx.x;
    const int tm = (tid >> 4) << 2;   // 0..60
    const int tn = (tid & 15) << 2;   // 0..60
    const int lr = tid >> 3;          // 0..31
    const int lc = (tid & 7) << 2;    // 0..28

    float acc[4][4];
    #pragma unroll
    for (int i = 0; i < 4; i++)
        #pragma unroll
        for (int j = 0; j < 4; j++) acc[i][j] = 0.f;

    for (int k0 = 0; k0 < F; k0 += 32) {
        #pragma unroll
        for (int rr = 0; rr < 2; rr++) {
            int row = bm + lr + rr * 32;
            float4 v = make_float4(0.f, 0.f, 0.f, 0.f);
            if (row < M) v = *(const float4*)(X + (size_t)row * F + k0 + lc);
            Xs[lr + rr * 32][lc + 0] = v.x; Xs[lr + rr * 32][lc + 1] = v.y;
            Xs[lr + rr * 32][lc + 2] = v.z; Xs[lr + rr * 32][lc + 3] = v.w;
            int wrow = bn + lr + rr * 32;   // always < HC=256
            float4 wv = *(const float4*)(W + (size_t)wrow * F + k0 + lc);
            Ws[lr + rr * 32][lc + 0] = wv.x; Ws[lr + rr * 32][lc + 1] = wv.y;
            Ws[lr + rr * 32][lc + 2] = wv.z; Ws[lr + rr * 32][lc + 3] = wv.w;
        }
        __syncthreads();
        #pragma unroll
        for (int k = 0; k < 32; k++) {
            float a[4], b[4];
            #pragma unroll
            for (int i = 0; i < 4; i++) a[i] = Xs[tm + i][k];
            #pragma unroll
            for (int j = 0; j < 4; j++) b[j] = Ws[tn + j][k];
            #pragma unroll
            for (int i = 0; i < 4; i++)
                #pragma unroll
                for (int j = 0; j < 4; j++)
                    acc[i][j] = fmaf(a[i], b[j], acc[i][j]);
        }
        __syncthreads();
    }
    #pragma unroll
    for (int i = 0; i < 4; i++) {
        int row = bm + tm + i;
        if (row < M) {
            #pragma unroll
            for (int j = 0; j < 4; j++)
                Hout[(size_t)row * HC + bn + tn + j] = acc[i][j];
        }
    }
}

// ---------------- attention coefficients: a_s[n][h], a_d[n][h] ----------------
__global__ __launch_bounds__(256) void att_kernel(
    const float* __restrict__ h,
    const float* __restrict__ att_s, const float* __restrict__ att_d,
    float* __restrict__ a_s, float* __restrict__ a_d)
{
    int idx = blockIdx.x * blockDim.x + threadIdx.x;
    if (idx >= N_NODES * NHEAD) return;
    int n = idx >> 3, hh = idx & 7;
    const float4* row = (const float4*)(h + (size_t)n * HC + hh * CH);
    const float4* vs  = (const float4*)(att_s + hh * CH);
    const float4* vd  = (const float4*)(att_d + hh * CH);
    float ss = 0.f, sd = 0.f;
    #pragma unroll
    for (int q = 0; q < 8; q++) {
        float4 v = row[q], s4 = vs[q], d4 = vd[q];
        ss += v.x * s4.x + v.y * s4.y + v.z * s4.z + v.w * s4.w;
        sd += v.x * d4.x + v.y * d4.y + v.z * d4.z + v.w * d4.w;
    }
    a_s[idx] = ss; a_d[idx] = sd;
}

// ---------------- edge pass: denom[dst][h] += w ; acc[dst][:] += w*h[src][:] ----
__global__ __launch_bounds__(256) void edge_kernel(
    const int* __restrict__ ei,
    const float* __restrict__ h,
    const float* __restrict__ a_s, const float* __restrict__ a_d,
    float* __restrict__ acc, float* __restrict__ denom)
{
    long long gtid = (long long)blockIdx.x * blockDim.x + threadIdx.x;
    int eid = (int)(gtid >> 6);   // one wave (64 lanes) per edge
    int lane = threadIdx.x & 63;
    if (eid >= E_EXT) return;
    int s, d;
    if (eid < E_EDGES) { s = ei[eid]; d = ei[E_EDGES + eid]; }
    else { s = eid - E_EDGES; d = s; }
    int hh = lane >> 3;           // head for channels lane*4..lane*4+3
    float e = a_s[s * NHEAD + hh] + a_d[d * NHEAD + hh];
    e = (e > 0.f) ? e : 0.2f * e;   // leaky_relu, slope 0.2
    float w = __expf(e);            // max-subtraction cancels in softmax; |e| small
    if ((lane & 7) == 0) atomicAdd(&denom[d * NHEAD + hh], w);
    float4 hv = *(const float4*)(h + (size_t)s * HC + lane * 4);
    float* ap = acc + (size_t)d * HC + lane * 4;
    atomicAdd(ap + 0, w * hv.x);
    atomicAdd(ap + 1, w * hv.y);
    atomicAdd(ap + 2, w * hv.z);
    atomicAdd(ap + 3, w * hv.w);
}

// ---------------- node epilogue: out = acc/denom + bias (+relu) --------------
__global__ __launch_bounds__(256) void node_kernel(
    const float* __restrict__ acc, const float* __restrict__ denom,
    const float* __restrict__ bias, float* __restrict__ outp, int do_relu)
{
    int idx = blockIdx.x * blockDim.x + threadIdx.x;
    if (idx >= N_NODES * HC) return;
    int n = idx >> 8, j = idx & 255;
    float v = acc[idx] / denom[n * NHEAD + (j >> 5)] + bias[j];
    if (do_relu) v = fmaxf(v, 0.f);
    outp[idx] = v;
}

// ---------------- pool: pooled[g][:] += feat[n][:], cnt[g] += 1 --------------
__global__ __launch_bounds__(256) void pool_kernel(
    const float* __restrict__ feat, const int* __restrict__ batch,
    float* __restrict__ pooled, float* __restrict__ cnt)
{
    long long gtid = (long long)blockIdx.x * blockDim.x + threadIdx.x;
    int n = (int)(gtid >> 6);
    int lane = threadIdx.x & 63;
    if (n >= N_NODES) return;
    int g = batch[n];
    float4 v = *(const float4*)(feat + (size_t)n * HC + lane * 4);
    float* p = pooled + (size_t)g * HC + lane * 4;
    atomicAdd(p + 0, v.x);
    atomicAdd(p + 1, v.y);
    atomicAdd(p + 2, v.z);
    atomicAdd(p + 3, v.w);
    if (lane == 0) atomicAdd(&cnt[g], 1.f);
}

// ---------------- final: out[g] = dot(pooled[g]/cnt[g], Wf) + bf -------------
__global__ __launch_bounds__(256) void final_kernel(
    const float* __restrict__ pooled, const float* __restrict__ cnt,
    const float* __restrict__ Wf, const float* __restrict__ bf,
    float* __restrict__ outp)
{
    __shared__ float red[256];
    int g = blockIdx.x, t = threadIdx.x;
    float c = fmaxf(cnt[g], 1.f);
    red[t] = (pooled[(size_t)g * HC + t] / c) * Wf[t];
    __syncthreads();
    for (int s = 128; s > 0; s >>= 1) {
        if (t < s) red[t] += red[t + s];
        __syncthreads();
    }
    if (t == 0) outp[g] = red[0] + bf[0];
}

extern "C" void kernel_launch(void* const* d_in, const int* in_sizes, int n_in,
                              void* d_out, int out_size, void* d_ws, size_t ws_size,
                              hipStream_t stream)
{
    const float* x    = (const float*)d_in[0];
    const int*   ei   = (const int*)d_in[1];
    const int*   batch= (const int*)d_in[2];
    const float* W1   = (const float*)d_in[3];
    const float* as1  = (const float*)d_in[4];
    const float* ad1  = (const float*)d_in[5];
    const float* b1   = (const float*)d_in[6];
    const float* W2   = (const float*)d_in[7];
    const float* as2  = (const float*)d_in[8];
    const float* ad2  = (const float*)d_in[9];
    const float* b2   = (const float*)d_in[10];
    const float* W3   = (const float*)d_in[11];
    const float* as3  = (const float*)d_in[12];
    const float* ad3  = (const float*)d_in[13];
    const float* b3   = (const float*)d_in[14];
    const float* Wf   = (const float*)d_in[15];
    const float* bf   = (const float*)d_in[16];
    float* out = (float*)d_out;

    char* ws = (char*)d_ws;
    size_t off = 0;
    auto alloc = [&](size_t nfloats) {
        float* p = (float*)(ws + off);
        off += nfloats * sizeof(float);
        return p;
    };
    float* buf_h   = alloc((size_t)N_NODES * HC);   // 51.2 MB
    float* buf_io  = alloc((size_t)N_NODES * HC);   // acc AND layer IO (aliased safely)
    float* as_buf  = alloc((size_t)N_NODES * NHEAD);
    float* ad_buf  = alloc((size_t)N_NODES * NHEAD);
    float* dn_buf  = alloc((size_t)N_NODES * NHEAD);
    float* pooled  = alloc((size_t)NGRAPH * HC);
    float* cntbuf  = alloc((size_t)NGRAPH);
    (void)ws_size; (void)in_sizes; (void)n_in; (void)out_size;

    auto run_layer = [&](const float* inp, int F, const float* W,
                         const float* aw_s, const float* aw_d, const float* bias,
                         int relu) {
        dim3 grid((N_NODES + 63) / 64, HC / 64);
        gemm_kernel<<<grid, 256, 0, stream>>>(inp, W, buf_h, N_NODES, F);
        att_kernel<<<(N_NODES * NHEAD + 255) / 256, 256, 0, stream>>>(
            buf_h, aw_s, aw_d, as_buf, ad_buf);
        hipMemsetAsync(buf_io, 0, (size_t)N_NODES * HC * sizeof(float), stream);
        hipMemsetAsync(dn_buf, 0, (size_t)N_NODES * NHEAD * sizeof(float), stream);
        edge_kernel<<<((size_t)E_EXT * 64 + 255) / 256, 256, 0, stream>>>(
            ei, buf_h, as_buf, ad_buf, buf_io, dn_buf);
        node_kernel<<<((size_t)N_NODES * HC + 255) / 256, 256, 0, stream>>>(
            buf_io, dn_buf, bias, buf_io, relu);   // elementwise in-place: safe
    };

    run_layer(x,      IN_CH, W1, as1, ad1, b1, 1);
    run_layer(buf_io, HC,    W2, as2, ad2, b2, 1);
    run_layer(buf_io, HC,    W3, as3, ad3, b3, 0);

    hipMemsetAsync(pooled, 0, (size_t)NGRAPH * HC * sizeof(float), stream);
    hipMemsetAsync(cntbuf, 0, (size_t)NGRAPH * sizeof(float), stream);
    pool_kernel<<<((size_t)N_NODES * 64 + 255) / 256, 256, 0, stream>>>(
        buf_io, batch, pooled, cntbuf);
    final_kernel<<<NGRAPH, 256, 0, stream>>>(pooled, cntbuf, Wf, bf, out);
}

// Round 2
// 1186.613 us; speedup vs baseline: 7.9210x; 7.9210x over previous
//
#include <hip/hip_runtime.h>

#define N_NODES 50000
#define E_EDGES 800000
#define E_EXT   850000   // + self loops
#define IN_CH   128
#define HC      256
#define NHEAD   8
#define CH      32
#define NGRAPH  256

// ---------------- GEMM: Hout[M][HC] = X[M][F] @ W[HC][F]^T ----------------
__global__ __launch_bounds__(256) void gemm_kernel(
    const float* __restrict__ X, const float* __restrict__ W,
    float* __restrict__ Hout, int M, int F)
{
    __shared__ float Xs[64][33];
    __shared__ float Ws[64][33];
    const int bm = blockIdx.x * 64;
    const int bn = blockIdx.y * 64;
    const int tid = threadIdx.x;
    const int tm = (tid >> 4) << 2;
    const int tn = (tid & 15) << 2;
    const int lr = tid >> 3;
    const int lc = (tid & 7) << 2;

    float acc[4][4];
    #pragma unroll
    for (int i = 0; i < 4; i++)
        #pragma unroll
        for (int j = 0; j < 4; j++) acc[i][j] = 0.f;

    for (int k0 = 0; k0 < F; k0 += 32) {
        #pragma unroll
        for (int rr = 0; rr < 2; rr++) {
            int row = bm + lr + rr * 32;
            float4 v = make_float4(0.f, 0.f, 0.f, 0.f);
            if (row < M) v = *(const float4*)(X + (size_t)row * F + k0 + lc);
            Xs[lr + rr * 32][lc + 0] = v.x; Xs[lr + rr * 32][lc + 1] = v.y;
            Xs[lr + rr * 32][lc + 2] = v.z; Xs[lr + rr * 32][lc + 3] = v.w;
            int wrow = bn + lr + rr * 32;
            float4 wv = *(const float4*)(W + (size_t)wrow * F + k0 + lc);
            Ws[lr + rr * 32][lc + 0] = wv.x; Ws[lr + rr * 32][lc + 1] = wv.y;
            Ws[lr + rr * 32][lc + 2] = wv.z; Ws[lr + rr * 32][lc + 3] = wv.w;
        }
        __syncthreads();
        #pragma unroll
        for (int k = 0; k < 32; k++) {
            float a[4], b[4];
            #pragma unroll
            for (int i = 0; i < 4; i++) a[i] = Xs[tm + i][k];
            #pragma unroll
            for (int j = 0; j < 4; j++) b[j] = Ws[tn + j][k];
            #pragma unroll
            for (int i = 0; i < 4; i++)
                #pragma unroll
                for (int j = 0; j < 4; j++)
                    acc[i][j] = fmaf(a[i], b[j], acc[i][j]);
        }
        __syncthreads();
    }
    #pragma unroll
    for (int i = 0; i < 4; i++) {
        int row = bm + tm + i;
        if (row < M) {
            #pragma unroll
            for (int j = 0; j < 4; j++)
                Hout[(size_t)row * HC + bn + tn + j] = acc[i][j];
        }
    }
}

// ---------------- attention coefficients: a_s[n][h], a_d[n][h] ----------------
__global__ __launch_bounds__(256) void att_kernel(
    const float* __restrict__ h,
    const float* __restrict__ att_s, const float* __restrict__ att_d,
    float* __restrict__ a_s, float* __restrict__ a_d)
{
    int idx = blockIdx.x * blockDim.x + threadIdx.x;
    if (idx >= N_NODES * NHEAD) return;
    int n = idx >> 3, hh = idx & 7;
    const float4* row = (const float4*)(h + (size_t)n * HC + hh * CH);
    const float4* vs  = (const float4*)(att_s + hh * CH);
    const float4* vd  = (const float4*)(att_d + hh * CH);
    float ss = 0.f, sd = 0.f;
    #pragma unroll
    for (int q = 0; q < 8; q++) {
        float4 v = row[q], s4 = vs[q], d4 = vd[q];
        ss += v.x * s4.x + v.y * s4.y + v.z * s4.z + v.w * s4.w;
        sd += v.x * d4.x + v.y * d4.y + v.z * d4.z + v.w * d4.w;
    }
    a_s[idx] = ss; a_d[idx] = sd;
}

// ---------------- CSR build ----------------
__global__ __launch_bounds__(256) void hist_kernel(
    const int* __restrict__ ei, int* __restrict__ deg)
{
    int eid = blockIdx.x * blockDim.x + threadIdx.x;
    if (eid >= E_EXT) return;
    int d = (eid < E_EDGES) ? ei[E_EDGES + eid] : (eid - E_EDGES);
    atomicAdd(&deg[d], 1);
}

__global__ void scan_kernel(const int* __restrict__ deg, int* __restrict__ row_ptr)
{
    __shared__ int buf[1024];
    int t = threadIdx.x;
    int running = 0;
    for (int base = 0; base < N_NODES; base += 1024) {
        int v = (base + t < N_NODES) ? deg[base + t] : 0;
        buf[t] = v;
        __syncthreads();
        for (int off = 1; off < 1024; off <<= 1) {
            int x = buf[t];
            int y = (t >= off) ? buf[t - off] : 0;
            __syncthreads();
            buf[t] = x + y;
            __syncthreads();
        }
        int incl = buf[t];
        if (base + t < N_NODES) row_ptr[base + t] = running + incl - v;
        int total = buf[1023];
        __syncthreads();
        running += total;
    }
    if (t == 0) row_ptr[N_NODES] = running;
}

__global__ __launch_bounds__(256) void scatter_kernel(
    const int* __restrict__ ei, const int* __restrict__ row_ptr,
    int* __restrict__ cur, int* __restrict__ esrc)
{
    int eid = blockIdx.x * blockDim.x + threadIdx.x;
    if (eid >= E_EXT) return;
    int s, d;
    if (eid < E_EDGES) { s = ei[eid]; d = ei[E_EDGES + eid]; }
    else { s = eid - E_EDGES; d = s; }
    int pos = row_ptr[d] + atomicAdd(&cur[d], 1);
    esrc[pos] = s;
}

// ------- gather edge pass: one wave per dst node, fused softmax+epilogue -------
__global__ __launch_bounds__(256) void gather_kernel(
    const int* __restrict__ row_ptr, const int* __restrict__ esrc,
    const float* __restrict__ h,
    const float* __restrict__ a_s, const float* __restrict__ a_d,
    const float* __restrict__ bias, float* __restrict__ outp, int do_relu)
{
    int wid = (blockIdx.x * blockDim.x + threadIdx.x) >> 6;
    int lane = threadIdx.x & 63;
    if (wid >= N_NODES) return;
    const int n = wid;
    const int hh = lane >> 3;
    const float adv = a_d[n * NHEAD + hh];
    const int beg = row_ptr[n], end = row_ptr[n + 1];

    float acc0 = 0.f, acc1 = 0.f, acc2 = 0.f, acc3 = 0.f, den = 0.f;
    for (int base = beg; base < end; base += 64) {
        int cnt = min(64, end - base);
        int sv = (base + lane < end) ? esrc[base + lane] : 0;
        for (int j = 0; j < cnt; j++) {
            int s = __shfl(sv, j);
            float e = a_s[s * NHEAD + hh] + adv;
            e = (e > 0.f) ? e : 0.2f * e;          // leaky_relu 0.2
            float w = __expf(e);                   // max cancels in softmax
            den += w;
            float4 hv = *(const float4*)(h + (size_t)s * HC + lane * 4);
            acc0 = fmaf(w, hv.x, acc0);
            acc1 = fmaf(w, hv.y, acc1);
            acc2 = fmaf(w, hv.z, acc2);
            acc3 = fmaf(w, hv.w, acc3);
        }
    }
    float inv = 1.f / den;                          // den>0: self loop present
    float4 b4 = *(const float4*)(bias + lane * 4);
    float o0 = fmaf(acc0, inv, b4.x);
    float o1 = fmaf(acc1, inv, b4.y);
    float o2 = fmaf(acc2, inv, b4.z);
    float o3 = fmaf(acc3, inv, b4.w);
    if (do_relu) {
        o0 = fmaxf(o0, 0.f); o1 = fmaxf(o1, 0.f);
        o2 = fmaxf(o2, 0.f); o3 = fmaxf(o3, 0.f);
    }
    *(float4*)(outp + (size_t)n * HC + lane * 4) = make_float4(o0, o1, o2, o3);
}

// ------- fused pool+final: per-node dot with Wf, scalar atomic per node -------
__global__ __launch_bounds__(256) void nodedot_kernel(
    const float* __restrict__ feat, const int* __restrict__ batch,
    const float* __restrict__ Wf,
    float* __restrict__ gsum, float* __restrict__ gcnt)
{
    long long gtid = (long long)blockIdx.x * blockDim.x + threadIdx.x;
    int n = (int)(gtid >> 6);
    int lane = threadIdx.x & 63;
    if (n >= N_NODES) return;
    float4 v = *(const float4*)(feat + (size_t)n * HC + lane * 4);
    float4 w = *(const float4*)(Wf + lane * 4);
    float p = v.x * w.x + v.y * w.y + v.z * w.z + v.w * w.w;
    #pragma unroll
    for (int off = 32; off > 0; off >>= 1) p += __shfl_xor(p, off);
    if (lane == 0) {
        int g = batch[n];
        atomicAdd(&gsum[g], p);
        atomicAdd(&gcnt[g], 1.f);
    }
}

__global__ __launch_bounds__(256) void final_kernel(
    const float* __restrict__ gsum, const float* __restrict__ gcnt,
    const float* __restrict__ bf, float* __restrict__ outp)
{
    int g = blockIdx.x * blockDim.x + threadIdx.x;
    if (g >= NGRAPH) return;
    outp[g] = gsum[g] / fmaxf(gcnt[g], 1.f) + bf[0];
}

extern "C" void kernel_launch(void* const* d_in, const int* in_sizes, int n_in,
                              void* d_out, int out_size, void* d_ws, size_t ws_size,
                              hipStream_t stream)
{
    const float* x    = (const float*)d_in[0];
    const int*   ei   = (const int*)d_in[1];
    const int*   batch= (const int*)d_in[2];
    const float* W1   = (const float*)d_in[3];
    const float* as1  = (const float*)d_in[4];
    const float* ad1  = (const float*)d_in[5];
    const float* b1   = (const float*)d_in[6];
    const float* W2   = (const float*)d_in[7];
    const float* as2  = (const float*)d_in[8];
    const float* ad2  = (const float*)d_in[9];
    const float* b2   = (const float*)d_in[10];
    const float* W3   = (const float*)d_in[11];
    const float* as3  = (const float*)d_in[12];
    const float* ad3  = (const float*)d_in[13];
    const float* b3   = (const float*)d_in[14];
    const float* Wf   = (const float*)d_in[15];
    const float* bf   = (const float*)d_in[16];
    float* out = (float*)d_out;

    char* ws = (char*)d_ws;
    size_t off = 0;
    auto allocf = [&](size_t n) { float* p = (float*)(ws + off); off += n * 4; return p; };
    auto alloci = [&](size_t n) { int*   p = (int*)  (ws + off); off += n * 4; return p; };

    float* buf_h   = allocf((size_t)N_NODES * HC);   // 51.2 MB
    float* buf_io  = allocf((size_t)N_NODES * HC);   // 51.2 MB
    float* as_buf  = allocf((size_t)N_NODES * NHEAD);
    float* ad_buf  = allocf((size_t)N_NODES * NHEAD);
    int*   deg     = alloci(N_NODES);
    int*   cur     = alloci(N_NODES);
    int*   row_ptr = alloci(N_NODES + 1);
    int*   esrc    = alloci(E_EXT);                  // 3.4 MB
    float* gsum    = allocf(NGRAPH);
    float* gcnt    = allocf(NGRAPH);
    (void)ws_size; (void)in_sizes; (void)n_in; (void)out_size;

    // ---- CSR build (per call; deterministic work) ----
    hipMemsetAsync(deg, 0, N_NODES * sizeof(int), stream);
    hipMemsetAsync(cur, 0, N_NODES * sizeof(int), stream);
    hist_kernel<<<(E_EXT + 255) / 256, 256, 0, stream>>>(ei, deg);
    scan_kernel<<<1, 1024, 0, stream>>>(deg, row_ptr);
    scatter_kernel<<<(E_EXT + 255) / 256, 256, 0, stream>>>(ei, row_ptr, cur, esrc);

    auto run_layer = [&](const float* inp, int F, const float* W,
                         const float* aw_s, const float* aw_d, const float* bias,
                         int relu) {
        dim3 grid((N_NODES + 63) / 64, HC / 64);
        gemm_kernel<<<grid, 256, 0, stream>>>(inp, W, buf_h, N_NODES, F);
        att_kernel<<<(N_NODES * NHEAD + 255) / 256, 256, 0, stream>>>(
            buf_h, aw_s, aw_d, as_buf, ad_buf);
        gather_kernel<<<((size_t)N_NODES * 64 + 255) / 256, 256, 0, stream>>>(
            row_ptr, esrc, buf_h, as_buf, ad_buf, bias, buf_io, relu);
    };

    run_layer(x,      IN_CH, W1, as1, ad1, b1, 1);
    run_layer(buf_io, HC,    W2, as2, ad2, b2, 1);
    run_layer(buf_io, HC,    W3, as3, ad3, b3, 0);

    hipMemsetAsync(gsum, 0, NGRAPH * sizeof(float), stream);
    hipMemsetAsync(gcnt, 0, NGRAPH * sizeof(float), stream);
    nodedot_kernel<<<((size_t)N_NODES * 64 + 255) / 256, 256, 0, stream>>>(
        buf_io, batch, Wf, gsum, gcnt);
    final_kernel<<<1, 256, 0, stream>>>(gsum, gcnt, bf, out);
}

// Round 3
// 657.040 us; speedup vs baseline: 14.3053x; 1.8060x over previous
//
#include <hip/hip_runtime.h>

#define N_NODES 50000
#define E_EDGES 800000
#define E_EXT   850000   // + self loops
#define IN_CH   128
#define HC      256
#define NHEAD   8
#define CH      32
#define NGRAPH  256
#define SCAN_CHUNK 1024
#define N_CHUNKS ((N_NODES + SCAN_CHUNK - 1) / SCAN_CHUNK)

typedef __bf16 bf16x8 __attribute__((ext_vector_type(8)));
typedef float  f32x4  __attribute__((ext_vector_type(4)));

__device__ inline ushort f2bf(float f) {
    union { float f; unsigned u; } v; v.f = f;
    unsigned u = v.u;
    unsigned r = u + 0x7FFFu + ((u >> 16) & 1u);
    return (ushort)(r >> 16);
}

// ---------------- f32 -> bf16 (RNE), n divisible by 4 ----------------
__global__ __launch_bounds__(256) void cvt_bf16_kernel(
    const float* __restrict__ in, ushort* __restrict__ outp, int n4)
{
    int i = blockIdx.x * blockDim.x + threadIdx.x;
    if (i >= n4) return;
    float4 v = *(const float4*)(in + (size_t)i * 4);
    ushort4 o;
    o.x = f2bf(v.x); o.y = f2bf(v.y); o.z = f2bf(v.z); o.w = f2bf(v.w);
    *(ushort4*)(outp + (size_t)i * 4) = o;
}

// ------- MFMA GEMM: Hout[M][HC] = Xb[M][F] @ Wb[HC][F]^T  (bf16 in, f32 out) ----
__global__ __launch_bounds__(256) void mfma_gemm_kernel(
    const ushort* __restrict__ Xb, const ushort* __restrict__ Wb,
    float* __restrict__ Hout, int M, int F)
{
    __shared__ ushort As[64][40];   // stride 40 bf16 = 80B: ~2-way banks (free)
    __shared__ ushort Bs[64][40];
    const int tid  = threadIdx.x;
    const int lane = tid & 63;
    const int wave = tid >> 6;
    const int wr = (wave >> 1) * 32;
    const int wc = (wave & 1) * 32;
    const int bm = blockIdx.x * 64;
    const int bn = blockIdx.y * 64;
    const int lrow = tid >> 2;          // 64 rows, 4 threads/row
    const int lseg = (tid & 3) * 8;     // 8 bf16 = 16B per thread
    const int fr = lane & 15;           // fragment row/col
    const int fk = (lane >> 4) * 8;     // fragment k offset

    f32x4 acc00 = {0.f,0.f,0.f,0.f}, acc01 = {0.f,0.f,0.f,0.f};
    f32x4 acc10 = {0.f,0.f,0.f,0.f}, acc11 = {0.f,0.f,0.f,0.f};

    for (int k0 = 0; k0 < F; k0 += 32) {
        int arow = bm + lrow;
        bf16x8 av = {};
        if (arow < M) av = *(const bf16x8*)(Xb + (size_t)arow * F + k0 + lseg);
        *(bf16x8*)(&As[lrow][lseg]) = av;
        bf16x8 bv = *(const bf16x8*)(Wb + (size_t)(bn + lrow) * F + k0 + lseg);
        *(bf16x8*)(&Bs[lrow][lseg]) = bv;
        __syncthreads();
        bf16x8 a0 = *(const bf16x8*)(&As[wr + fr][fk]);
        bf16x8 a1 = *(const bf16x8*)(&As[wr + 16 + fr][fk]);
        bf16x8 b0 = *(const bf16x8*)(&Bs[wc + fr][fk]);
        bf16x8 b1 = *(const bf16x8*)(&Bs[wc + 16 + fr][fk]);
        acc00 = __builtin_amdgcn_mfma_f32_16x16x32_bf16(a0, b0, acc00, 0, 0, 0);
        acc01 = __builtin_amdgcn_mfma_f32_16x16x32_bf16(a0, b1, acc01, 0, 0, 0);
        acc10 = __builtin_amdgcn_mfma_f32_16x16x32_bf16(a1, b0, acc10, 0, 0, 0);
        acc11 = __builtin_amdgcn_mfma_f32_16x16x32_bf16(a1, b1, acc11, 0, 0, 0);
        __syncthreads();
    }
    const int rb = (lane >> 4) * 4;
    #pragma unroll
    for (int r = 0; r < 4; r++) {
        int m0 = bm + wr + rb + r;
        int m1 = m0 + 16;
        if (m0 < M) {
            Hout[(size_t)m0 * HC + bn + wc + fr]      = acc00[r];
            Hout[(size_t)m0 * HC + bn + wc + 16 + fr] = acc01[r];
        }
        if (m1 < M) {
            Hout[(size_t)m1 * HC + bn + wc + fr]      = acc10[r];
            Hout[(size_t)m1 * HC + bn + wc + 16 + fr] = acc11[r];
        }
    }
}

// ---------------- attention coefficients ----------------
__global__ __launch_bounds__(256) void att_kernel(
    const float* __restrict__ h,
    const float* __restrict__ att_s, const float* __restrict__ att_d,
    float* __restrict__ a_s, float* __restrict__ a_d)
{
    int idx = blockIdx.x * blockDim.x + threadIdx.x;
    if (idx >= N_NODES * NHEAD) return;
    int n = idx >> 3, hh = idx & 7;
    const float4* row = (const float4*)(h + (size_t)n * HC + hh * CH);
    const float4* vs  = (const float4*)(att_s + hh * CH);
    const float4* vd  = (const float4*)(att_d + hh * CH);
    float ss = 0.f, sd = 0.f;
    #pragma unroll
    for (int q = 0; q < 8; q++) {
        float4 v = row[q], s4 = vs[q], d4 = vd[q];
        ss += v.x * s4.x + v.y * s4.y + v.z * s4.z + v.w * s4.w;
        sd += v.x * d4.x + v.y * d4.y + v.z * d4.z + v.w * d4.w;
    }
    a_s[idx] = ss; a_d[idx] = sd;
}

// ---------------- CSR build ----------------
__global__ __launch_bounds__(256) void hist_kernel(
    const int* __restrict__ ei, int* __restrict__ deg)
{
    int eid = blockIdx.x * blockDim.x + threadIdx.x;
    if (eid >= E_EXT) return;
    int d = (eid < E_EDGES) ? ei[E_EDGES + eid] : (eid - E_EDGES);
    atomicAdd(&deg[d], 1);
}

__global__ void scan1_kernel(const int* __restrict__ deg,
                             int* __restrict__ row_ptr, int* __restrict__ csum)
{
    __shared__ int buf[SCAN_CHUNK];
    int t = threadIdx.x;
    int base = blockIdx.x * SCAN_CHUNK;
    int v = (base + t < N_NODES) ? deg[base + t] : 0;
    buf[t] = v;
    __syncthreads();
    for (int off = 1; off < SCAN_CHUNK; off <<= 1) {
        int x = buf[t];
        int y = (t >= off) ? buf[t - off] : 0;
        __syncthreads();
        buf[t] = x + y;
        __syncthreads();
    }
    if (base + t < N_NODES) row_ptr[base + t] = buf[t] - v;  // chunk-local exclusive
    if (t == SCAN_CHUNK - 1) csum[blockIdx.x] = buf[t];
}

__global__ void scan2_kernel(int* __restrict__ csum)
{
    __shared__ int buf[64];
    int t = threadIdx.x;   // 64 threads, N_CHUNKS<=64
    int v = (t < N_CHUNKS) ? csum[t] : 0;
    buf[t] = v;
    __syncthreads();
    for (int off = 1; off < 64; off <<= 1) {
        int x = buf[t];
        int y = (t >= off) ? buf[t - off] : 0;
        __syncthreads();
        buf[t] = x + y;
        __syncthreads();
    }
    if (t < N_CHUNKS) csum[t] = buf[t] - v;  // exclusive
}

__global__ void scan3_kernel(int* __restrict__ row_ptr, const int* __restrict__ csum)
{
    int i = blockIdx.x * blockDim.x + threadIdx.x;
    if (i < N_NODES) row_ptr[i] += csum[i / SCAN_CHUNK];
    if (i == 0) row_ptr[N_NODES] = E_EXT;
}

__global__ __launch_bounds__(256) void scatter_kernel(
    const int* __restrict__ ei, const int* __restrict__ row_ptr,
    int* __restrict__ cur, int* __restrict__ esrc)
{
    int eid = blockIdx.x * blockDim.x + threadIdx.x;
    if (eid >= E_EXT) return;
    int s, d;
    if (eid < E_EDGES) { s = ei[eid]; d = ei[E_EDGES + eid]; }
    else { s = eid - E_EDGES; d = s; }
    int pos = row_ptr[d] + atomicAdd(&cur[d], 1);
    esrc[pos] = s;
}

// ------- gather edge pass: one wave per dst node, fused softmax+epilogue -------
// writes f32 out; optionally a bf16 copy (input to next layer's MFMA GEMM)
__global__ __launch_bounds__(256) void gather_kernel(
    const int* __restrict__ row_ptr, const int* __restrict__ esrc,
    const float* __restrict__ h,
    const float* __restrict__ a_s, const float* __restrict__ a_d,
    const float* __restrict__ bias, float* __restrict__ outp,
    ushort* __restrict__ out_b, int do_relu)
{
    int wid = (blockIdx.x * blockDim.x + threadIdx.x) >> 6;
    int lane = threadIdx.x & 63;
    if (wid >= N_NODES) return;
    const int n = wid;
    const int hh = lane >> 3;
    const float adv = a_d[n * NHEAD + hh];
    const int beg = row_ptr[n], end = row_ptr[n + 1];

    float acc0 = 0.f, acc1 = 0.f, acc2 = 0.f, acc3 = 0.f, den = 0.f;
    for (int base = beg; base < end; base += 64) {
        int cnt = min(64, end - base);
        int sv = (base + lane < end) ? esrc[base + lane] : 0;
        for (int j = 0; j < cnt; j++) {
            int s = __shfl(sv, j);
            float e = a_s[s * NHEAD + hh] + adv;
            e = (e > 0.f) ? e : 0.2f * e;          // leaky_relu 0.2
            float w = __expf(e);                   // max cancels in softmax
            den += w;
            float4 hv = *(const float4*)(h + (size_t)s * HC + lane * 4);
            acc0 = fmaf(w, hv.x, acc0);
            acc1 = fmaf(w, hv.y, acc1);
            acc2 = fmaf(w, hv.z, acc2);
            acc3 = fmaf(w, hv.w, acc3);
        }
    }
    float inv = 1.f / den;
    float4 b4 = *(const float4*)(bias + lane * 4);
    float o0 = fmaf(acc0, inv, b4.x);
    float o1 = fmaf(acc1, inv, b4.y);
    float o2 = fmaf(acc2, inv, b4.z);
    float o3 = fmaf(acc3, inv, b4.w);
    if (do_relu) {
        o0 = fmaxf(o0, 0.f); o1 = fmaxf(o1, 0.f);
        o2 = fmaxf(o2, 0.f); o3 = fmaxf(o3, 0.f);
    }
    *(float4*)(outp + (size_t)n * HC + lane * 4) = make_float4(o0, o1, o2, o3);
    if (out_b) {
        ushort4 ob;
        ob.x = f2bf(o0); ob.y = f2bf(o1); ob.z = f2bf(o2); ob.w = f2bf(o3);
        *(ushort4*)(out_b + (size_t)n * HC + lane * 4) = ob;
    }
}

// ------- per-node dot with Wf (no atomics) -------
__global__ __launch_bounds__(256) void ndot_kernel(
    const float* __restrict__ feat, const float* __restrict__ Wf,
    float* __restrict__ ndot)
{
    long long gtid = (long long)blockIdx.x * blockDim.x + threadIdx.x;
    int n = (int)(gtid >> 6);
    int lane = threadIdx.x & 63;
    if (n >= N_NODES) return;
    float4 v = *(const float4*)(feat + (size_t)n * HC + lane * 4);
    float4 w = *(const float4*)(Wf + lane * 4);
    float p = v.x * w.x + v.y * w.y + v.z * w.z + v.w * w.w;
    #pragma unroll
    for (int off = 32; off > 0; off >>= 1) p += __shfl_xor(p, off);
    if (lane == 0) ndot[n] = p;
}

// ------- per-graph mean over sorted batch (binary search, no atomics) -------
__global__ __launch_bounds__(256) void pool2_kernel(
    const float* __restrict__ ndot, const int* __restrict__ batch,
    const float* __restrict__ bf, float* __restrict__ outp)
{
    __shared__ float red[256];
    int g = blockIdx.x, t = threadIdx.x;
    int lo = 0, hi = N_NODES;
    while (lo < hi) { int mid = (lo + hi) >> 1; if (batch[mid] < g) lo = mid + 1; else hi = mid; }
    int start = lo;
    lo = 0; hi = N_NODES;
    while (lo < hi) { int mid = (lo + hi) >> 1; if (batch[mid] < g + 1) lo = mid + 1; else hi = mid; }
    int end = lo;
    float s = 0.f;
    for (int i = start + t; i < end; i += 256) s += ndot[i];
    red[t] = s;
    __syncthreads();
    for (int k = 128; k > 0; k >>= 1) {
        if (t < k) red[t] += red[t + k];
        __syncthreads();
    }
    if (t == 0) outp[g] = red[0] / fmaxf((float)(end - start), 1.f) + bf[0];
}

extern "C" void kernel_launch(void* const* d_in, const int* in_sizes, int n_in,
                              void* d_out, int out_size, void* d_ws, size_t ws_size,
                              hipStream_t stream)
{
    const float* x    = (const float*)d_in[0];
    const int*   ei   = (const int*)d_in[1];
    const int*   batch= (const int*)d_in[2];
    const float* W1   = (const float*)d_in[3];
    const float* as1  = (const float*)d_in[4];
    const float* ad1  = (const float*)d_in[5];
    const float* b1   = (const float*)d_in[6];
    const float* W2   = (const float*)d_in[7];
    const float* as2  = (const float*)d_in[8];
    const float* ad2  = (const float*)d_in[9];
    const float* b2   = (const float*)d_in[10];
    const float* W3   = (const float*)d_in[11];
    const float* as3  = (const float*)d_in[12];
    const float* ad3  = (const float*)d_in[13];
    const float* b3   = (const float*)d_in[14];
    const float* Wf   = (const float*)d_in[15];
    const float* bf   = (const float*)d_in[16];
    float* out = (float*)d_out;

    char* ws = (char*)d_ws;
    size_t off = 0;
    auto allocb = [&](size_t bytes) {
        void* p = ws + off;
        off += (bytes + 255) & ~(size_t)255;
        return p;
    };
    float*  buf_h   = (float*) allocb((size_t)N_NODES * HC * 4);   // 51.2 MB
    float*  buf_io  = (float*) allocb((size_t)N_NODES * HC * 4);   // 51.2 MB
    ushort* bbuf    = (ushort*)allocb((size_t)N_NODES * HC * 2);   // 25.6 MB (xb then h-bf16)
    ushort* W1b     = (ushort*)allocb((size_t)HC * IN_CH * 2);
    ushort* W2b     = (ushort*)allocb((size_t)HC * HC * 2);
    ushort* W3b     = (ushort*)allocb((size_t)HC * HC * 2);
    float*  as_buf  = (float*) allocb((size_t)N_NODES * NHEAD * 4);
    float*  ad_buf  = (float*) allocb((size_t)N_NODES * NHEAD * 4);
    int*    deg     = (int*)   allocb(N_NODES * 4);
    int*    cur     = (int*)   allocb(N_NODES * 4);
    int*    row_ptr = (int*)   allocb((N_NODES + 1) * 4);
    int*    csum    = (int*)   allocb(64 * 4);
    int*    esrc    = (int*)   allocb(E_EXT * 4);
    float*  ndot    = (float*) allocb(N_NODES * 4);
    (void)ws_size; (void)in_sizes; (void)n_in; (void)out_size;

    // ---- bf16 conversions ----
    cvt_bf16_kernel<<<((size_t)N_NODES * IN_CH / 4 + 255) / 256, 256, 0, stream>>>(
        x, bbuf, N_NODES * IN_CH / 4);
    cvt_bf16_kernel<<<(HC * IN_CH / 4 + 255) / 256, 256, 0, stream>>>(W1, W1b, HC * IN_CH / 4);
    cvt_bf16_kernel<<<(HC * HC / 4 + 255) / 256, 256, 0, stream>>>(W2, W2b, HC * HC / 4);
    cvt_bf16_kernel<<<(HC * HC / 4 + 255) / 256, 256, 0, stream>>>(W3, W3b, HC * HC / 4);

    // ---- CSR build ----
    hipMemsetAsync(deg, 0, N_NODES * sizeof(int), stream);
    hipMemsetAsync(cur, 0, N_NODES * sizeof(int), stream);
    hist_kernel<<<(E_EXT + 255) / 256, 256, 0, stream>>>(ei, deg);
    scan1_kernel<<<N_CHUNKS, SCAN_CHUNK, 0, stream>>>(deg, row_ptr, csum);
    scan2_kernel<<<1, 64, 0, stream>>>(csum);
    scan3_kernel<<<(N_NODES + 255) / 256, 256, 0, stream>>>(row_ptr, csum);
    scatter_kernel<<<(E_EXT + 255) / 256, 256, 0, stream>>>(ei, row_ptr, cur, esrc);

    auto run_layer = [&](const ushort* inp_b, int F, const ushort* Wb,
                         const float* aw_s, const float* aw_d, const float* bias,
                         ushort* next_b, int relu) {
        dim3 grid((N_NODES + 63) / 64, HC / 64);
        mfma_gemm_kernel<<<grid, 256, 0, stream>>>(inp_b, Wb, buf_h, N_NODES, F);
        att_kernel<<<(N_NODES * NHEAD + 255) / 256, 256, 0, stream>>>(
            buf_h, aw_s, aw_d, as_buf, ad_buf);
        gather_kernel<<<((size_t)N_NODES * 64 + 255) / 256, 256, 0, stream>>>(
            row_ptr, esrc, buf_h, as_buf, ad_buf, bias, buf_io, next_b, relu);
    };

    // layer 1 reads bbuf (=x in bf16), then gather overwrites bbuf with h1 bf16
    run_layer(bbuf, IN_CH, W1b, as1, ad1, b1, bbuf, 1);
    run_layer(bbuf, HC,    W2b, as2, ad2, b2, bbuf, 1);
    run_layer(bbuf, HC,    W3b, as3, ad3, b3, nullptr, 0);

    ndot_kernel<<<((size_t)N_NODES * 64 + 255) / 256, 256, 0, stream>>>(buf_io, Wf, ndot);
    pool2_kernel<<<NGRAPH, 256, 0, stream>>>(ndot, batch, bf, out);
}

// Round 4
// 454.001 us; speedup vs baseline: 20.7029x; 1.4472x over previous
//
#include <hip/hip_runtime.h>

#define N_NODES 50000
#define E_EDGES 800000
#define E_EXT   850000   // + self loops
#define IN_CH   128
#define HC      256
#define NHEAD   8
#define CH      32
#define NGRAPH  256
#define SCAN_CHUNK 1024
#define N_CHUNKS ((N_NODES + SCAN_CHUNK - 1) / SCAN_CHUNK)

typedef __bf16 bf16x8 __attribute__((ext_vector_type(8)));
typedef float  f32x4  __attribute__((ext_vector_type(4)));

__device__ inline ushort f2bf(float f) {
    union { float f; unsigned u; } v; v.f = f;
    unsigned u = v.u;
    unsigned r = u + 0x7FFFu + ((u >> 16) & 1u);
    return (ushort)(r >> 16);
}
__device__ inline float bflo(unsigned u) {   // low bf16 of a packed word
    union { unsigned u; float f; } v; v.u = u << 16; return v.f;
}
__device__ inline float bfhi(unsigned u) {   // high bf16 of a packed word
    union { unsigned u; float f; } v; v.u = u & 0xFFFF0000u; return v.f;
}

// ---------------- f32 -> bf16 (RNE), n divisible by 4 ----------------
__global__ __launch_bounds__(256) void cvt_bf16_kernel(
    const float* __restrict__ in, ushort* __restrict__ outp, int n4)
{
    int i = blockIdx.x * blockDim.x + threadIdx.x;
    if (i >= n4) return;
    float4 v = *(const float4*)(in + (size_t)i * 4);
    ushort4 o;
    o.x = f2bf(v.x); o.y = f2bf(v.y); o.z = f2bf(v.z); o.w = f2bf(v.w);
    *(ushort4*)(outp + (size_t)i * 4) = o;
}

// ------- MFMA GEMM: Hb[M][HC] = Xb[M][F] @ Wb[HC][F]^T  (bf16 in, bf16 out) ----
__global__ __launch_bounds__(256) void mfma_gemm_kernel(
    const ushort* __restrict__ Xb, const ushort* __restrict__ Wb,
    ushort* __restrict__ Hb, int M, int F)
{
    __shared__ ushort As[64][40];   // stride 40 bf16 = 80B: 2-way banks (free)
    __shared__ ushort Bs[64][40];
    const int tid  = threadIdx.x;
    const int lane = tid & 63;
    const int wave = tid >> 6;
    const int wr = (wave >> 1) * 32;
    const int wc = (wave & 1) * 32;
    const int bm = blockIdx.x * 64;
    const int bn = blockIdx.y * 64;
    const int lrow = tid >> 2;          // 64 rows, 4 threads/row
    const int lseg = (tid & 3) * 8;     // 8 bf16 = 16B per thread
    const int fr = lane & 15;
    const int fk = (lane >> 4) * 8;

    f32x4 acc00 = {0.f,0.f,0.f,0.f}, acc01 = {0.f,0.f,0.f,0.f};
    f32x4 acc10 = {0.f,0.f,0.f,0.f}, acc11 = {0.f,0.f,0.f,0.f};

    for (int k0 = 0; k0 < F; k0 += 32) {
        int arow = bm + lrow;
        bf16x8 av = {};
        if (arow < M) av = *(const bf16x8*)(Xb + (size_t)arow * F + k0 + lseg);
        *(bf16x8*)(&As[lrow][lseg]) = av;
        bf16x8 bv = *(const bf16x8*)(Wb + (size_t)(bn + lrow) * F + k0 + lseg);
        *(bf16x8*)(&Bs[lrow][lseg]) = bv;
        __syncthreads();
        bf16x8 a0 = *(const bf16x8*)(&As[wr + fr][fk]);
        bf16x8 a1 = *(const bf16x8*)(&As[wr + 16 + fr][fk]);
        bf16x8 b0 = *(const bf16x8*)(&Bs[wc + fr][fk]);
        bf16x8 b1 = *(const bf16x8*)(&Bs[wc + 16 + fr][fk]);
        acc00 = __builtin_amdgcn_mfma_f32_16x16x32_bf16(a0, b0, acc00, 0, 0, 0);
        acc01 = __builtin_amdgcn_mfma_f32_16x16x32_bf16(a0, b1, acc01, 0, 0, 0);
        acc10 = __builtin_amdgcn_mfma_f32_16x16x32_bf16(a1, b0, acc10, 0, 0, 0);
        acc11 = __builtin_amdgcn_mfma_f32_16x16x32_bf16(a1, b1, acc11, 0, 0, 0);
        __syncthreads();
    }
    const int rb = (lane >> 4) * 4;
    #pragma unroll
    for (int r = 0; r < 4; r++) {
        int m0 = bm + wr + rb + r;
        int m1 = m0 + 16;
        if (m0 < M) {
            Hb[(size_t)m0 * HC + bn + wc + fr]      = f2bf(acc00[r]);
            Hb[(size_t)m0 * HC + bn + wc + 16 + fr] = f2bf(acc01[r]);
        }
        if (m1 < M) {
            Hb[(size_t)m1 * HC + bn + wc + fr]      = f2bf(acc10[r]);
            Hb[(size_t)m1 * HC + bn + wc + 16 + fr] = f2bf(acc11[r]);
        }
    }
}

// ---------------- attention coefficients (bf16 h) ----------------
__global__ __launch_bounds__(256) void att_kernel(
    const ushort* __restrict__ hb,
    const float* __restrict__ att_s, const float* __restrict__ att_d,
    float* __restrict__ a_s, float* __restrict__ a_d)
{
    int idx = blockIdx.x * blockDim.x + threadIdx.x;
    if (idx >= N_NODES * NHEAD) return;
    int n = idx >> 3, hh = idx & 7;
    const uint4* row = (const uint4*)(hb + (size_t)n * HC + hh * CH);  // 32 bf16
    const float4* vs = (const float4*)(att_s + hh * CH);
    const float4* vd = (const float4*)(att_d + hh * CH);
    float ss = 0.f, sd = 0.f;
    #pragma unroll
    for (int q = 0; q < 4; q++) {
        uint4 u = row[q];
        float h0 = bflo(u.x), h1 = bfhi(u.x), h2 = bflo(u.y), h3 = bfhi(u.y);
        float h4 = bflo(u.z), h5 = bfhi(u.z), h6 = bflo(u.w), h7 = bfhi(u.w);
        float4 s0 = vs[q * 2], s1 = vs[q * 2 + 1];
        float4 d0 = vd[q * 2], d1 = vd[q * 2 + 1];
        ss += h0 * s0.x + h1 * s0.y + h2 * s0.z + h3 * s0.w
            + h4 * s1.x + h5 * s1.y + h6 * s1.z + h7 * s1.w;
        sd += h0 * d0.x + h1 * d0.y + h2 * d0.z + h3 * d0.w
            + h4 * d1.x + h5 * d1.y + h6 * d1.z + h7 * d1.w;
    }
    a_s[idx] = ss; a_d[idx] = sd;
}

// ---------------- CSR build ----------------
__global__ __launch_bounds__(256) void hist_kernel(
    const int* __restrict__ ei, int* __restrict__ deg)
{
    int eid = blockIdx.x * blockDim.x + threadIdx.x;
    if (eid >= E_EXT) return;
    int d = (eid < E_EDGES) ? ei[E_EDGES + eid] : (eid - E_EDGES);
    atomicAdd(&deg[d], 1);
}

__global__ void scan1_kernel(const int* __restrict__ deg,
                             int* __restrict__ row_ptr, int* __restrict__ csum)
{
    __shared__ int buf[SCAN_CHUNK];
    int t = threadIdx.x;
    int base = blockIdx.x * SCAN_CHUNK;
    int v = (base + t < N_NODES) ? deg[base + t] : 0;
    buf[t] = v;
    __syncthreads();
    for (int off = 1; off < SCAN_CHUNK; off <<= 1) {
        int x = buf[t];
        int y = (t >= off) ? buf[t - off] : 0;
        __syncthreads();
        buf[t] = x + y;
        __syncthreads();
    }
    if (base + t < N_NODES) row_ptr[base + t] = buf[t] - v;
    if (t == SCAN_CHUNK - 1) csum[blockIdx.x] = buf[t];
}

__global__ void scan2_kernel(int* __restrict__ csum)
{
    __shared__ int buf[64];
    int t = threadIdx.x;
    int v = (t < N_CHUNKS) ? csum[t] : 0;
    buf[t] = v;
    __syncthreads();
    for (int off = 1; off < 64; off <<= 1) {
        int x = buf[t];
        int y = (t >= off) ? buf[t - off] : 0;
        __syncthreads();
        buf[t] = x + y;
        __syncthreads();
    }
    if (t < N_CHUNKS) csum[t] = buf[t] - v;
}

__global__ void scan3_kernel(int* __restrict__ row_ptr, const int* __restrict__ csum)
{
    int i = blockIdx.x * blockDim.x + threadIdx.x;
    if (i < N_NODES) row_ptr[i] += csum[i / SCAN_CHUNK];
    if (i == 0) row_ptr[N_NODES] = E_EXT;
}

__global__ __launch_bounds__(256) void scatter_kernel(
    const int* __restrict__ ei, const int* __restrict__ row_ptr,
    int* __restrict__ cur, int* __restrict__ esrc)
{
    int eid = blockIdx.x * blockDim.x + threadIdx.x;
    if (eid >= E_EXT) return;
    int s, d;
    if (eid < E_EDGES) { s = ei[eid]; d = ei[E_EDGES + eid]; }
    else { s = eid - E_EDGES; d = s; }
    int pos = row_ptr[d] + atomicAdd(&cur[d], 1);
    esrc[pos] = s;
}

// ------- gather: one wave per dst, bf16 messages, fused softmax+epilogue -------
// out_b  != null -> write bf16 layer output (next GEMM input)
// Wf     != null -> fused final projection: ndot[n] = dot(out_row, Wf)
__global__ __launch_bounds__(256) void gather_kernel(
    const int* __restrict__ row_ptr, const int* __restrict__ esrc,
    const ushort* __restrict__ hb,
    const float* __restrict__ a_s, const float* __restrict__ a_d,
    const float* __restrict__ bias,
    ushort* __restrict__ out_b,
    const float* __restrict__ Wf, float* __restrict__ ndot,
    int do_relu)
{
    int wid = (blockIdx.x * blockDim.x + threadIdx.x) >> 6;
    int lane = threadIdx.x & 63;
    if (wid >= N_NODES) return;
    const int n = wid;
    const int hh = lane >> 3;
    const float adv = a_d[n * NHEAD + hh];
    const int beg = row_ptr[n], end = row_ptr[n + 1];

    float acc0 = 0.f, acc1 = 0.f, acc2 = 0.f, acc3 = 0.f, den = 0.f;
    for (int base = beg; base < end; base += 64) {
        int cnt = min(64, end - base);
        int sv = (base + lane < end) ? esrc[base + lane] : 0;
        for (int j = 0; j < cnt; j++) {
            int s = __shfl(sv, j);
            float e = a_s[s * NHEAD + hh] + adv;
            e = (e > 0.f) ? e : 0.2f * e;          // leaky_relu 0.2
            float w = __expf(e);                   // max cancels in softmax
            den += w;
            uint2 u = *(const uint2*)(hb + (size_t)s * HC + lane * 4);
            acc0 = fmaf(w, bflo(u.x), acc0);
            acc1 = fmaf(w, bfhi(u.x), acc1);
            acc2 = fmaf(w, bflo(u.y), acc2);
            acc3 = fmaf(w, bfhi(u.y), acc3);
        }
    }
    float inv = 1.f / den;
    float4 b4 = *(const float4*)(bias + lane * 4);
    float o0 = fmaf(acc0, inv, b4.x);
    float o1 = fmaf(acc1, inv, b4.y);
    float o2 = fmaf(acc2, inv, b4.z);
    float o3 = fmaf(acc3, inv, b4.w);
    if (do_relu) {
        o0 = fmaxf(o0, 0.f); o1 = fmaxf(o1, 0.f);
        o2 = fmaxf(o2, 0.f); o3 = fmaxf(o3, 0.f);
    }
    if (out_b) {
        ushort4 ob;
        ob.x = f2bf(o0); ob.y = f2bf(o1); ob.z = f2bf(o2); ob.w = f2bf(o3);
        *(ushort4*)(out_b + (size_t)n * HC + lane * 4) = ob;
    }
    if (Wf) {
        float4 w4 = *(const float4*)(Wf + lane * 4);
        float p = o0 * w4.x + o1 * w4.y + o2 * w4.z + o3 * w4.w;
        #pragma unroll
        for (int off = 32; off > 0; off >>= 1) p += __shfl_xor(p, off);
        if (lane == 0) ndot[n] = p;
    }
}

// ------- per-graph mean over sorted batch (binary search, no atomics) -------
__global__ __launch_bounds__(256) void pool2_kernel(
    const float* __restrict__ ndot, const int* __restrict__ batch,
    const float* __restrict__ bf, float* __restrict__ outp)
{
    __shared__ float red[256];
    int g = blockIdx.x, t = threadIdx.x;
    int lo = 0, hi = N_NODES;
    while (lo < hi) { int mid = (lo + hi) >> 1; if (batch[mid] < g) lo = mid + 1; else hi = mid; }
    int start = lo;
    lo = 0; hi = N_NODES;
    while (lo < hi) { int mid = (lo + hi) >> 1; if (batch[mid] < g + 1) lo = mid + 1; else hi = mid; }
    int end = lo;
    float s = 0.f;
    for (int i = start + t; i < end; i += 256) s += ndot[i];
    red[t] = s;
    __syncthreads();
    for (int k = 128; k > 0; k >>= 1) {
        if (t < k) red[t] += red[t + k];
        __syncthreads();
    }
    if (t == 0) outp[g] = red[0] / fmaxf((float)(end - start), 1.f) + bf[0];
}

extern "C" void kernel_launch(void* const* d_in, const int* in_sizes, int n_in,
                              void* d_out, int out_size, void* d_ws, size_t ws_size,
                              hipStream_t stream)
{
    const float* x    = (const float*)d_in[0];
    const int*   ei   = (const int*)d_in[1];
    const int*   batch= (const int*)d_in[2];
    const float* W1   = (const float*)d_in[3];
    const float* as1  = (const float*)d_in[4];
    const float* ad1  = (const float*)d_in[5];
    const float* b1   = (const float*)d_in[6];
    const float* W2   = (const float*)d_in[7];
    const float* as2  = (const float*)d_in[8];
    const float* ad2  = (const float*)d_in[9];
    const float* b2   = (const float*)d_in[10];
    const float* W3   = (const float*)d_in[11];
    const float* as3  = (const float*)d_in[12];
    const float* ad3  = (const float*)d_in[13];
    const float* b3   = (const float*)d_in[14];
    const float* Wf   = (const float*)d_in[15];
    const float* bf   = (const float*)d_in[16];
    float* out = (float*)d_out;

    char* ws = (char*)d_ws;
    size_t off = 0;
    auto allocb = [&](size_t bytes) {
        void* p = ws + off;
        off += (bytes + 255) & ~(size_t)255;
        return p;
    };
    ushort* bufA    = (ushort*)allocb((size_t)N_NODES * HC * 2);   // 25.6 MB
    ushort* bufB    = (ushort*)allocb((size_t)N_NODES * HC * 2);   // 25.6 MB
    ushort* W1b     = (ushort*)allocb((size_t)HC * IN_CH * 2);
    ushort* W2b     = (ushort*)allocb((size_t)HC * HC * 2);
    ushort* W3b     = (ushort*)allocb((size_t)HC * HC * 2);
    float*  as_buf  = (float*) allocb((size_t)N_NODES * NHEAD * 4);
    float*  ad_buf  = (float*) allocb((size_t)N_NODES * NHEAD * 4);
    int*    deg     = (int*)   allocb(N_NODES * 4);
    int*    cur     = (int*)   allocb(N_NODES * 4);
    int*    row_ptr = (int*)   allocb((N_NODES + 1) * 4);
    int*    csum    = (int*)   allocb(64 * 4);
    int*    esrc    = (int*)   allocb(E_EXT * 4);
    float*  ndot    = (float*) allocb(N_NODES * 4);
    (void)ws_size; (void)in_sizes; (void)n_in; (void)out_size;

    // ---- bf16 conversions ----
    cvt_bf16_kernel<<<((size_t)N_NODES * IN_CH / 4 + 255) / 256, 256, 0, stream>>>(
        x, bufA, N_NODES * IN_CH / 4);
    cvt_bf16_kernel<<<(HC * IN_CH / 4 + 255) / 256, 256, 0, stream>>>(W1, W1b, HC * IN_CH / 4);
    cvt_bf16_kernel<<<(HC * HC / 4 + 255) / 256, 256, 0, stream>>>(W2, W2b, HC * HC / 4);
    cvt_bf16_kernel<<<(HC * HC / 4 + 255) / 256, 256, 0, stream>>>(W3, W3b, HC * HC / 4);

    // ---- CSR build ----
    hipMemsetAsync(deg, 0, N_NODES * sizeof(int), stream);
    hipMemsetAsync(cur, 0, N_NODES * sizeof(int), stream);
    hist_kernel<<<(E_EXT + 255) / 256, 256, 0, stream>>>(ei, deg);
    scan1_kernel<<<N_CHUNKS, SCAN_CHUNK, 0, stream>>>(deg, row_ptr, csum);
    scan2_kernel<<<1, 64, 0, stream>>>(csum);
    scan3_kernel<<<(N_NODES + 255) / 256, 256, 0, stream>>>(row_ptr, csum);
    scatter_kernel<<<(E_EXT + 255) / 256, 256, 0, stream>>>(ei, row_ptr, cur, esrc);

    dim3 ggrid((N_NODES + 63) / 64, HC / 64);
    const int gather_blocks = ((size_t)N_NODES * 64 + 255) / 256;
    const int att_blocks = (N_NODES * NHEAD + 255) / 256;

    // layer 1: A(x) -> B(h1) -> A(h1')
    mfma_gemm_kernel<<<ggrid, 256, 0, stream>>>(bufA, W1b, bufB, N_NODES, IN_CH);
    att_kernel<<<att_blocks, 256, 0, stream>>>(bufB, as1, ad1, as_buf, ad_buf);
    gather_kernel<<<gather_blocks, 256, 0, stream>>>(
        row_ptr, esrc, bufB, as_buf, ad_buf, b1, bufA, nullptr, nullptr, 1);
    // layer 2: A -> B -> A
    mfma_gemm_kernel<<<ggrid, 256, 0, stream>>>(bufA, W2b, bufB, N_NODES, HC);
    att_kernel<<<att_blocks, 256, 0, stream>>>(bufB, as2, ad2, as_buf, ad_buf);
    gather_kernel<<<gather_blocks, 256, 0, stream>>>(
        row_ptr, esrc, bufB, as_buf, ad_buf, b2, bufA, nullptr, nullptr, 1);
    // layer 3: A -> B -> ndot (fused final projection)
    mfma_gemm_kernel<<<ggrid, 256, 0, stream>>>(bufA, W3b, bufB, N_NODES, HC);
    att_kernel<<<att_blocks, 256, 0, stream>>>(bufB, as3, ad3, as_buf, ad_buf);
    gather_kernel<<<gather_blocks, 256, 0, stream>>>(
        row_ptr, esrc, bufB, as_buf, ad_buf, b3, nullptr, Wf, ndot, 0);

    pool2_kernel<<<NGRAPH, 256, 0, stream>>>(ndot, batch, bf, out);
}

// Round 5
// 427.265 us; speedup vs baseline: 21.9984x; 1.0626x over previous
//
#include <hip/hip_runtime.h>

#define N_NODES 50000
#define E_EDGES 800000
#define E_EXT   850000   // + self loops
#define IN_CH   128
#define HC      256
#define NHEAD   8
#define CH      32
#define NGRAPH  256
#define SCAN_CHUNK 1024
#define N_CHUNKS ((N_NODES + SCAN_CHUNK - 1) / SCAN_CHUNK)

typedef __bf16 bf16x8 __attribute__((ext_vector_type(8)));
typedef float  f32x4  __attribute__((ext_vector_type(4)));

__device__ inline ushort f2bf(float f) {
    union { float f; unsigned u; } v; v.f = f;
    unsigned u = v.u;
    unsigned r = u + 0x7FFFu + ((u >> 16) & 1u);
    return (ushort)(r >> 16);
}
__device__ inline float bflo(unsigned u) {
    union { unsigned u; float f; } v; v.u = u << 16; return v.f;
}
__device__ inline float bfhi(unsigned u) {
    union { unsigned u; float f; } v; v.u = u & 0xFFFF0000u; return v.f;
}

// ---------------- f32 -> bf16 (RNE) ----------------
__global__ __launch_bounds__(256) void cvt_bf16_kernel(
    const float* __restrict__ in, ushort* __restrict__ outp, int n4)
{
    int i = blockIdx.x * blockDim.x + threadIdx.x;
    if (i >= n4) return;
    float4 v = *(const float4*)(in + (size_t)i * 4);
    ushort4 o;
    o.x = f2bf(v.x); o.y = f2bf(v.y); o.z = f2bf(v.z); o.w = f2bf(v.w);
    *(ushort4*)(outp + (size_t)i * 4) = o;
}

// ------- MFMA GEMM 128x128 tile: Hb[M][HC] = Xb[M][F] @ Wb[HC][F]^T ----------
// 4 waves (2x2), each wave 64x64 = 4x4 frags of 16x16x32. LDS stride 40 (pad).
__global__ __launch_bounds__(256) void mfma_gemm_kernel(
    const ushort* __restrict__ Xb, const ushort* __restrict__ Wb,
    ushort* __restrict__ Hb, int M, int F)
{
    __shared__ ushort As[128][40];
    __shared__ ushort Bs[128][40];
    const int tid  = threadIdx.x;
    const int lane = tid & 63;
    const int wave = tid >> 6;
    const int wr = (wave >> 1) * 64;
    const int wc = (wave & 1) * 64;
    const int bm = blockIdx.x * 128;
    const int bn = blockIdx.y * 128;
    const int lrow = tid >> 2;          // 0..63
    const int lseg = (tid & 3) * 8;     // 0,8,16,24
    const int fr = lane & 15;
    const int fk = (lane >> 4) * 8;

    f32x4 zero = {0.f, 0.f, 0.f, 0.f};
    f32x4 acc[4][4];
    #pragma unroll
    for (int i = 0; i < 4; i++)
        #pragma unroll
        for (int j = 0; j < 4; j++) acc[i][j] = zero;

    for (int k0 = 0; k0 < F; k0 += 32) {
        #pragma unroll
        for (int rr = 0; rr < 2; rr++) {
            int row = lrow + rr * 64;
            int arow = bm + row;
            bf16x8 av = {};
            if (arow < M) av = *(const bf16x8*)(Xb + (size_t)arow * F + k0 + lseg);
            *(bf16x8*)(&As[row][lseg]) = av;
            bf16x8 bv = *(const bf16x8*)(Wb + (size_t)(bn + row) * F + k0 + lseg);
            *(bf16x8*)(&Bs[row][lseg]) = bv;
        }
        __syncthreads();
        bf16x8 a[4], b[4];
        #pragma unroll
        for (int i = 0; i < 4; i++) {
            a[i] = *(const bf16x8*)(&As[wr + i * 16 + fr][fk]);
            b[i] = *(const bf16x8*)(&Bs[wc + i * 16 + fr][fk]);
        }
        #pragma unroll
        for (int i = 0; i < 4; i++)
            #pragma unroll
            for (int j = 0; j < 4; j++)
                acc[i][j] = __builtin_amdgcn_mfma_f32_16x16x32_bf16(
                    a[i], b[j], acc[i][j], 0, 0, 0);
        __syncthreads();
    }
    const int rb = (lane >> 4) * 4;
    #pragma unroll
    for (int i = 0; i < 4; i++) {
        #pragma unroll
        for (int r = 0; r < 4; r++) {
            int m = bm + wr + i * 16 + rb + r;
            if (m < M) {
                #pragma unroll
                for (int j = 0; j < 4; j++)
                    Hb[(size_t)m * HC + bn + wc + j * 16 + fr] = f2bf(acc[i][j][r]);
            }
        }
    }
}

// ---------------- attention coefficients (bf16 h) ----------------
__global__ __launch_bounds__(256) void att_kernel(
    const ushort* __restrict__ hb,
    const float* __restrict__ att_s, const float* __restrict__ att_d,
    float* __restrict__ a_s, float* __restrict__ a_d)
{
    int idx = blockIdx.x * blockDim.x + threadIdx.x;
    if (idx >= N_NODES * NHEAD) return;
    int n = idx >> 3, hh = idx & 7;
    const uint4* row = (const uint4*)(hb + (size_t)n * HC + hh * CH);
    const float4* vs = (const float4*)(att_s + hh * CH);
    const float4* vd = (const float4*)(att_d + hh * CH);
    float ss = 0.f, sd = 0.f;
    #pragma unroll
    for (int q = 0; q < 4; q++) {
        uint4 u = row[q];
        float h0 = bflo(u.x), h1 = bfhi(u.x), h2 = bflo(u.y), h3 = bfhi(u.y);
        float h4 = bflo(u.z), h5 = bfhi(u.z), h6 = bflo(u.w), h7 = bfhi(u.w);
        float4 s0 = vs[q * 2], s1 = vs[q * 2 + 1];
        float4 d0 = vd[q * 2], d1 = vd[q * 2 + 1];
        ss += h0 * s0.x + h1 * s0.y + h2 * s0.z + h3 * s0.w
            + h4 * s1.x + h5 * s1.y + h6 * s1.z + h7 * s1.w;
        sd += h0 * d0.x + h1 * d0.y + h2 * d0.z + h3 * d0.w
            + h4 * d1.x + h5 * d1.y + h6 * d1.z + h7 * d1.w;
    }
    a_s[idx] = ss; a_d[idx] = sd;
}

// ---------------- CSR build ----------------
__global__ __launch_bounds__(256) void hist_kernel(
    const int* __restrict__ ei, int* __restrict__ deg)
{
    int eid = blockIdx.x * blockDim.x + threadIdx.x;
    if (eid >= E_EXT) return;
    int d = (eid < E_EDGES) ? ei[E_EDGES + eid] : (eid - E_EDGES);
    atomicAdd(&deg[d], 1);
}

__global__ void scan1_kernel(const int* __restrict__ deg,
                             int* __restrict__ row_ptr, int* __restrict__ csum)
{
    __shared__ int buf[SCAN_CHUNK];
    int t = threadIdx.x;
    int base = blockIdx.x * SCAN_CHUNK;
    int v = (base + t < N_NODES) ? deg[base + t] : 0;
    buf[t] = v;
    __syncthreads();
    for (int off = 1; off < SCAN_CHUNK; off <<= 1) {
        int x = buf[t];
        int y = (t >= off) ? buf[t - off] : 0;
        __syncthreads();
        buf[t] = x + y;
        __syncthreads();
    }
    if (base + t < N_NODES) row_ptr[base + t] = buf[t] - v;
    if (t == SCAN_CHUNK - 1) csum[blockIdx.x] = buf[t];
}

__global__ void scan2_kernel(int* __restrict__ csum)
{
    __shared__ int buf[64];
    int t = threadIdx.x;
    int v = (t < N_CHUNKS) ? csum[t] : 0;
    buf[t] = v;
    __syncthreads();
    for (int off = 1; off < 64; off <<= 1) {
        int x = buf[t];
        int y = (t >= off) ? buf[t - off] : 0;
        __syncthreads();
        buf[t] = x + y;
        __syncthreads();
    }
    if (t < N_CHUNKS) csum[t] = buf[t] - v;
}

__global__ void scan3_kernel(int* __restrict__ row_ptr, const int* __restrict__ csum)
{
    int i = blockIdx.x * blockDim.x + threadIdx.x;
    if (i < N_NODES) row_ptr[i] += csum[i / SCAN_CHUNK];
    if (i == 0) row_ptr[N_NODES] = E_EXT;
}

__global__ __launch_bounds__(256) void scatter_kernel(
    const int* __restrict__ ei, const int* __restrict__ row_ptr,
    int* __restrict__ cur, int* __restrict__ esrc)
{
    int eid = blockIdx.x * blockDim.x + threadIdx.x;
    if (eid >= E_EXT) return;
    int s, d;
    if (eid < E_EDGES) { s = ei[eid]; d = ei[E_EDGES + eid]; }
    else { s = eid - E_EDGES; d = s; }
    int pos = row_ptr[d] + atomicAdd(&cur[d], 1);
    esrc[pos] = s;
}

// ------- gather: one wave per dst, bf16 messages, 4x software-pipelined -------
__global__ __launch_bounds__(256) void gather_kernel(
    const int* __restrict__ row_ptr, const int* __restrict__ esrc,
    const ushort* __restrict__ hb,
    const float* __restrict__ a_s, const float* __restrict__ a_d,
    const float* __restrict__ bias,
    ushort* __restrict__ out_b,
    const float* __restrict__ Wf, float* __restrict__ ndot,
    int do_relu)
{
    int wid = (blockIdx.x * blockDim.x + threadIdx.x) >> 6;
    int lane = threadIdx.x & 63;
    if (wid >= N_NODES) return;
    const int n = wid;
    const int hh = lane >> 3;
    const float adv = a_d[n * NHEAD + hh];
    const int beg = row_ptr[n], end = row_ptr[n + 1];

    float acc0 = 0.f, acc1 = 0.f, acc2 = 0.f, acc3 = 0.f, den = 0.f;
    for (int base = beg; base < end; base += 64) {
        int cnt = min(64, end - base);
        int sv = (base + lane < end) ? esrc[base + lane] : 0;
        int j = 0;
        for (; j + 4 <= cnt; j += 4) {
            // 4 independent edges: issue all loads before the dependent math
            int s0 = __shfl(sv, j), s1 = __shfl(sv, j + 1);
            int s2 = __shfl(sv, j + 2), s3 = __shfl(sv, j + 3);
            float e0 = a_s[s0 * NHEAD + hh];
            float e1 = a_s[s1 * NHEAD + hh];
            float e2 = a_s[s2 * NHEAD + hh];
            float e3 = a_s[s3 * NHEAD + hh];
            uint2 u0 = *(const uint2*)(hb + (size_t)s0 * HC + lane * 4);
            uint2 u1 = *(const uint2*)(hb + (size_t)s1 * HC + lane * 4);
            uint2 u2 = *(const uint2*)(hb + (size_t)s2 * HC + lane * 4);
            uint2 u3 = *(const uint2*)(hb + (size_t)s3 * HC + lane * 4);
            e0 += adv; e0 = (e0 > 0.f) ? e0 : 0.2f * e0; float w0 = __expf(e0);
            e1 += adv; e1 = (e1 > 0.f) ? e1 : 0.2f * e1; float w1 = __expf(e1);
            e2 += adv; e2 = (e2 > 0.f) ? e2 : 0.2f * e2; float w2 = __expf(e2);
            e3 += adv; e3 = (e3 > 0.f) ? e3 : 0.2f * e3; float w3 = __expf(e3);
            den += (w0 + w1) + (w2 + w3);
            acc0 = fmaf(w0, bflo(u0.x), acc0); acc1 = fmaf(w0, bfhi(u0.x), acc1);
            acc2 = fmaf(w0, bflo(u0.y), acc2); acc3 = fmaf(w0, bfhi(u0.y), acc3);
            acc0 = fmaf(w1, bflo(u1.x), acc0); acc1 = fmaf(w1, bfhi(u1.x), acc1);
            acc2 = fmaf(w1, bflo(u1.y), acc2); acc3 = fmaf(w1, bfhi(u1.y), acc3);
            acc0 = fmaf(w2, bflo(u2.x), acc0); acc1 = fmaf(w2, bfhi(u2.x), acc1);
            acc2 = fmaf(w2, bflo(u2.y), acc2); acc3 = fmaf(w2, bfhi(u2.y), acc3);
            acc0 = fmaf(w3, bflo(u3.x), acc0); acc1 = fmaf(w3, bfhi(u3.x), acc1);
            acc2 = fmaf(w3, bflo(u3.y), acc2); acc3 = fmaf(w3, bfhi(u3.y), acc3);
        }
        for (; j < cnt; j++) {
            int s = __shfl(sv, j);
            float e = a_s[s * NHEAD + hh] + adv;
            e = (e > 0.f) ? e : 0.2f * e;
            float w = __expf(e);
            den += w;
            uint2 u = *(const uint2*)(hb + (size_t)s * HC + lane * 4);
            acc0 = fmaf(w, bflo(u.x), acc0);
            acc1 = fmaf(w, bfhi(u.x), acc1);
            acc2 = fmaf(w, bflo(u.y), acc2);
            acc3 = fmaf(w, bfhi(u.y), acc3);
        }
    }
    float inv = 1.f / den;
    float4 b4 = *(const float4*)(bias + lane * 4);
    float o0 = fmaf(acc0, inv, b4.x);
    float o1 = fmaf(acc1, inv, b4.y);
    float o2 = fmaf(acc2, inv, b4.z);
    float o3 = fmaf(acc3, inv, b4.w);
    if (do_relu) {
        o0 = fmaxf(o0, 0.f); o1 = fmaxf(o1, 0.f);
        o2 = fmaxf(o2, 0.f); o3 = fmaxf(o3, 0.f);
    }
    if (out_b) {
        ushort4 ob;
        ob.x = f2bf(o0); ob.y = f2bf(o1); ob.z = f2bf(o2); ob.w = f2bf(o3);
        *(ushort4*)(out_b + (size_t)n * HC + lane * 4) = ob;
    }
    if (Wf) {
        float4 w4 = *(const float4*)(Wf + lane * 4);
        float p = o0 * w4.x + o1 * w4.y + o2 * w4.z + o3 * w4.w;
        #pragma unroll
        for (int off = 32; off > 0; off >>= 1) p += __shfl_xor(p, off);
        if (lane == 0) ndot[n] = p;
    }
}

// ------- per-graph mean over sorted batch (binary search, no atomics) -------
__global__ __launch_bounds__(256) void pool2_kernel(
    const float* __restrict__ ndot, const int* __restrict__ batch,
    const float* __restrict__ bf, float* __restrict__ outp)
{
    __shared__ float red[256];
    int g = blockIdx.x, t = threadIdx.x;
    int lo = 0, hi = N_NODES;
    while (lo < hi) { int mid = (lo + hi) >> 1; if (batch[mid] < g) lo = mid + 1; else hi = mid; }
    int start = lo;
    lo = 0; hi = N_NODES;
    while (lo < hi) { int mid = (lo + hi) >> 1; if (batch[mid] < g + 1) lo = mid + 1; else hi = mid; }
    int end = lo;
    float s = 0.f;
    for (int i = start + t; i < end; i += 256) s += ndot[i];
    red[t] = s;
    __syncthreads();
    for (int k = 128; k > 0; k >>= 1) {
        if (t < k) red[t] += red[t + k];
        __syncthreads();
    }
    if (t == 0) outp[g] = red[0] / fmaxf((float)(end - start), 1.f) + bf[0];
}

extern "C" void kernel_launch(void* const* d_in, const int* in_sizes, int n_in,
                              void* d_out, int out_size, void* d_ws, size_t ws_size,
                              hipStream_t stream)
{
    const float* x    = (const float*)d_in[0];
    const int*   ei   = (const int*)d_in[1];
    const int*   batch= (const int*)d_in[2];
    const float* W1   = (const float*)d_in[3];
    const float* as1  = (const float*)d_in[4];
    const float* ad1  = (const float*)d_in[5];
    const float* b1   = (const float*)d_in[6];
    const float* W2   = (const float*)d_in[7];
    const float* as2  = (const float*)d_in[8];
    const float* ad2  = (const float*)d_in[9];
    const float* b2   = (const float*)d_in[10];
    const float* W3   = (const float*)d_in[11];
    const float* as3  = (const float*)d_in[12];
    const float* ad3  = (const float*)d_in[13];
    const float* b3   = (const float*)d_in[14];
    const float* Wf   = (const float*)d_in[15];
    const float* bf   = (const float*)d_in[16];
    float* out = (float*)d_out;

    char* ws = (char*)d_ws;
    size_t off = 0;
    auto allocb = [&](size_t bytes) {
        void* p = ws + off;
        off += (bytes + 255) & ~(size_t)255;
        return p;
    };
    ushort* bufA    = (ushort*)allocb((size_t)N_NODES * HC * 2);
    ushort* bufB    = (ushort*)allocb((size_t)N_NODES * HC * 2);
    ushort* W1b     = (ushort*)allocb((size_t)HC * IN_CH * 2);
    ushort* W2b     = (ushort*)allocb((size_t)HC * HC * 2);
    ushort* W3b     = (ushort*)allocb((size_t)HC * HC * 2);
    float*  as_buf  = (float*) allocb((size_t)N_NODES * NHEAD * 4);
    float*  ad_buf  = (float*) allocb((size_t)N_NODES * NHEAD * 4);
    int*    deg     = (int*)   allocb(N_NODES * 4);
    int*    cur     = (int*)   allocb(N_NODES * 4);
    int*    row_ptr = (int*)   allocb((N_NODES + 1) * 4);
    int*    csum    = (int*)   allocb(64 * 4);
    int*    esrc    = (int*)   allocb(E_EXT * 4);
    float*  ndot    = (float*) allocb(N_NODES * 4);
    (void)ws_size; (void)in_sizes; (void)n_in; (void)out_size;

    // ---- bf16 conversions ----
    cvt_bf16_kernel<<<((size_t)N_NODES * IN_CH / 4 + 255) / 256, 256, 0, stream>>>(
        x, bufA, N_NODES * IN_CH / 4);
    cvt_bf16_kernel<<<(HC * IN_CH / 4 + 255) / 256, 256, 0, stream>>>(W1, W1b, HC * IN_CH / 4);
    cvt_bf16_kernel<<<(HC * HC / 4 + 255) / 256, 256, 0, stream>>>(W2, W2b, HC * HC / 4);
    cvt_bf16_kernel<<<(HC * HC / 4 + 255) / 256, 256, 0, stream>>>(W3, W3b, HC * HC / 4);

    // ---- CSR build ----
    hipMemsetAsync(deg, 0, N_NODES * sizeof(int), stream);
    hipMemsetAsync(cur, 0, N_NODES * sizeof(int), stream);
    hist_kernel<<<(E_EXT + 255) / 256, 256, 0, stream>>>(ei, deg);
    scan1_kernel<<<N_CHUNKS, SCAN_CHUNK, 0, stream>>>(deg, row_ptr, csum);
    scan2_kernel<<<1, 64, 0, stream>>>(csum);
    scan3_kernel<<<(N_NODES + 255) / 256, 256, 0, stream>>>(row_ptr, csum);
    scatter_kernel<<<(E_EXT + 255) / 256, 256, 0, stream>>>(ei, row_ptr, cur, esrc);

    dim3 ggrid((N_NODES + 127) / 128, HC / 128);
    const int gather_blocks = ((size_t)N_NODES * 64 + 255) / 256;
    const int att_blocks = (N_NODES * NHEAD + 255) / 256;

    // layer 1: A(x) -> B(h1) -> A(h1')
    mfma_gemm_kernel<<<ggrid, 256, 0, stream>>>(bufA, W1b, bufB, N_NODES, IN_CH);
    att_kernel<<<att_blocks, 256, 0, stream>>>(bufB, as1, ad1, as_buf, ad_buf);
    gather_kernel<<<gather_blocks, 256, 0, stream>>>(
        row_ptr, esrc, bufB, as_buf, ad_buf, b1, bufA, nullptr, nullptr, 1);
    // layer 2: A -> B -> A
    mfma_gemm_kernel<<<ggrid, 256, 0, stream>>>(bufA, W2b, bufB, N_NODES, HC);
    att_kernel<<<att_blocks, 256, 0, stream>>>(bufB, as2, ad2, as_buf, ad_buf);
    gather_kernel<<<gather_blocks, 256, 0, stream>>>(
        row_ptr, esrc, bufB, as_buf, ad_buf, b2, bufA, nullptr, nullptr, 1);
    // layer 3: A -> B -> ndot (fused final projection)
    mfma_gemm_kernel<<<ggrid, 256, 0, stream>>>(bufA, W3b, bufB, N_NODES, HC);
    att_kernel<<<att_blocks, 256, 0, stream>>>(bufB, as3, ad3, as_buf, ad_buf);
    gather_kernel<<<gather_blocks, 256, 0, stream>>>(
        row_ptr, esrc, bufB, as_buf, ad_buf, b3, nullptr, Wf, ndot, 0);

    pool2_kernel<<<NGRAPH, 256, 0, stream>>>(ndot, batch, bf, out);
}

// Round 6
// 425.078 us; speedup vs baseline: 22.1116x; 1.0051x over previous
//
#include <hip/hip_runtime.h>

#define N_NODES 50000
#define E_EDGES 800000
#define E_EXT   850000   // + self loops
#define IN_CH   128
#define HC      256
#define NHEAD   8
#define CH      32
#define NGRAPH  256
#define SCAN_CHUNK 1024
#define N_CHUNKS ((N_NODES + SCAN_CHUNK - 1) / SCAN_CHUNK)

typedef __bf16 bf16x8 __attribute__((ext_vector_type(8)));
typedef float  f32x4  __attribute__((ext_vector_type(4)));

__device__ inline ushort f2bf(float f) {
    union { float f; unsigned u; } v; v.f = f;
    unsigned u = v.u;
    unsigned r = u + 0x7FFFu + ((u >> 16) & 1u);
    return (ushort)(r >> 16);
}
__device__ inline float bflo(unsigned u) {
    union { unsigned u; float f; } v; v.u = u << 16; return v.f;
}
__device__ inline float bfhi(unsigned u) {
    union { unsigned u; float f; } v; v.u = u & 0xFFFF0000u; return v.f;
}

// ---------------- f32 -> bf16 (RNE) ----------------
__global__ __launch_bounds__(256) void cvt_bf16_kernel(
    const float* __restrict__ in, ushort* __restrict__ outp, int n4)
{
    int i = blockIdx.x * blockDim.x + threadIdx.x;
    if (i >= n4) return;
    float4 v = *(const float4*)(in + (size_t)i * 4);
    ushort4 o;
    o.x = f2bf(v.x); o.y = f2bf(v.y); o.z = f2bf(v.z); o.w = f2bf(v.w);
    *(ushort4*)(outp + (size_t)i * 4) = o;
}

// ------- MFMA GEMM 128x128 tile: Hb[M][HC] = Xb[M][F] @ Wb[HC][F]^T ----------
__global__ __launch_bounds__(256) void mfma_gemm_kernel(
    const ushort* __restrict__ Xb, const ushort* __restrict__ Wb,
    ushort* __restrict__ Hb, int M, int F)
{
    __shared__ ushort As[128][40];
    __shared__ ushort Bs[128][40];
    const int tid  = threadIdx.x;
    const int lane = tid & 63;
    const int wave = tid >> 6;
    const int wr = (wave >> 1) * 64;
    const int wc = (wave & 1) * 64;
    const int bm = blockIdx.x * 128;
    const int bn = blockIdx.y * 128;
    const int lrow = tid >> 2;
    const int lseg = (tid & 3) * 8;
    const int fr = lane & 15;
    const int fk = (lane >> 4) * 8;

    f32x4 zero = {0.f, 0.f, 0.f, 0.f};
    f32x4 acc[4][4];
    #pragma unroll
    for (int i = 0; i < 4; i++)
        #pragma unroll
        for (int j = 0; j < 4; j++) acc[i][j] = zero;

    for (int k0 = 0; k0 < F; k0 += 32) {
        #pragma unroll
        for (int rr = 0; rr < 2; rr++) {
            int row = lrow + rr * 64;
            int arow = bm + row;
            bf16x8 av = {};
            if (arow < M) av = *(const bf16x8*)(Xb + (size_t)arow * F + k0 + lseg);
            *(bf16x8*)(&As[row][lseg]) = av;
            bf16x8 bv = *(const bf16x8*)(Wb + (size_t)(bn + row) * F + k0 + lseg);
            *(bf16x8*)(&Bs[row][lseg]) = bv;
        }
        __syncthreads();
        bf16x8 a[4], b[4];
        #pragma unroll
        for (int i = 0; i < 4; i++) {
            a[i] = *(const bf16x8*)(&As[wr + i * 16 + fr][fk]);
            b[i] = *(const bf16x8*)(&Bs[wc + i * 16 + fr][fk]);
        }
        #pragma unroll
        for (int i = 0; i < 4; i++)
            #pragma unroll
            for (int j = 0; j < 4; j++)
                acc[i][j] = __builtin_amdgcn_mfma_f32_16x16x32_bf16(
                    a[i], b[j], acc[i][j], 0, 0, 0);
        __syncthreads();
    }
    const int rb = (lane >> 4) * 4;
    #pragma unroll
    for (int i = 0; i < 4; i++) {
        #pragma unroll
        for (int r = 0; r < 4; r++) {
            int m = bm + wr + i * 16 + rb + r;
            if (m < M) {
                #pragma unroll
                for (int j = 0; j < 4; j++)
                    Hb[(size_t)m * HC + bn + wc + j * 16 + fr] = f2bf(acc[i][j][r]);
            }
        }
    }
}

// ---------------- attention coefficients (bf16 h) ----------------
__global__ __launch_bounds__(256) void att_kernel(
    const ushort* __restrict__ hb,
    const float* __restrict__ att_s, const float* __restrict__ att_d,
    float* __restrict__ a_s, float* __restrict__ a_d)
{
    int idx = blockIdx.x * blockDim.x + threadIdx.x;
    if (idx >= N_NODES * NHEAD) return;
    int n = idx >> 3, hh = idx & 7;
    const uint4* row = (const uint4*)(hb + (size_t)n * HC + hh * CH);
    const float4* vs = (const float4*)(att_s + hh * CH);
    const float4* vd = (const float4*)(att_d + hh * CH);
    float ss = 0.f, sd = 0.f;
    #pragma unroll
    for (int q = 0; q < 4; q++) {
        uint4 u = row[q];
        float h0 = bflo(u.x), h1 = bfhi(u.x), h2 = bflo(u.y), h3 = bfhi(u.y);
        float h4 = bflo(u.z), h5 = bfhi(u.z), h6 = bflo(u.w), h7 = bfhi(u.w);
        float4 s0 = vs[q * 2], s1 = vs[q * 2 + 1];
        float4 d0 = vd[q * 2], d1 = vd[q * 2 + 1];
        ss += h0 * s0.x + h1 * s0.y + h2 * s0.z + h3 * s0.w
            + h4 * s1.x + h5 * s1.y + h6 * s1.z + h7 * s1.w;
        sd += h0 * d0.x + h1 * d0.y + h2 * d0.z + h3 * d0.w
            + h4 * d1.x + h5 * d1.y + h6 * d1.z + h7 * d1.w;
    }
    a_s[idx] = ss; a_d[idx] = sd;
}

// ---------------- CSR build ----------------
__global__ __launch_bounds__(256) void hist_kernel(
    const int* __restrict__ ei, int* __restrict__ deg)
{
    int eid = blockIdx.x * blockDim.x + threadIdx.x;
    if (eid >= E_EXT) return;
    int d = (eid < E_EDGES) ? ei[E_EDGES + eid] : (eid - E_EDGES);
    atomicAdd(&deg[d], 1);
}

__global__ void scan1_kernel(const int* __restrict__ deg,
                             int* __restrict__ row_ptr, int* __restrict__ csum)
{
    __shared__ int buf[SCAN_CHUNK];
    int t = threadIdx.x;
    int base = blockIdx.x * SCAN_CHUNK;
    int v = (base + t < N_NODES) ? deg[base + t] : 0;
    buf[t] = v;
    __syncthreads();
    for (int off = 1; off < SCAN_CHUNK; off <<= 1) {
        int x = buf[t];
        int y = (t >= off) ? buf[t - off] : 0;
        __syncthreads();
        buf[t] = x + y;
        __syncthreads();
    }
    if (base + t < N_NODES) row_ptr[base + t] = buf[t] - v;
    if (t == SCAN_CHUNK - 1) csum[blockIdx.x] = buf[t];
}

__global__ void scan2_kernel(int* __restrict__ csum)
{
    __shared__ int buf[64];
    int t = threadIdx.x;
    int v = (t < N_CHUNKS) ? csum[t] : 0;
    buf[t] = v;
    __syncthreads();
    for (int off = 1; off < 64; off <<= 1) {
        int x = buf[t];
        int y = (t >= off) ? buf[t - off] : 0;
        __syncthreads();
        buf[t] = x + y;
        __syncthreads();
    }
    if (t < N_CHUNKS) csum[t] = buf[t] - v;
}

__global__ void scan3_kernel(int* __restrict__ row_ptr, const int* __restrict__ csum)
{
    int i = blockIdx.x * blockDim.x + threadIdx.x;
    if (i < N_NODES) row_ptr[i] += csum[i / SCAN_CHUNK];
    if (i == 0) row_ptr[N_NODES] = E_EXT;
}

__global__ __launch_bounds__(256) void scatter_kernel(
    const int* __restrict__ ei, const int* __restrict__ row_ptr,
    int* __restrict__ cur, int* __restrict__ esrc)
{
    int eid = blockIdx.x * blockDim.x + threadIdx.x;
    if (eid >= E_EXT) return;
    int s, d;
    if (eid < E_EDGES) { s = ei[eid]; d = ei[E_EDGES + eid]; }
    else { s = eid - E_EDGES; d = s; }
    int pos = row_ptr[d] + atomicAdd(&cur[d], 1);
    esrc[pos] = s;
}

// ------- gather: 2 dst per wave (half-wave each), 8 ch/lane via uint4 --------
__global__ __launch_bounds__(256) void gather_kernel(
    const int* __restrict__ row_ptr, const int* __restrict__ esrc,
    const ushort* __restrict__ hb,
    const float* __restrict__ a_s, const float* __restrict__ a_d,
    const float* __restrict__ bias,
    ushort* __restrict__ out_b,
    const float* __restrict__ Wf, float* __restrict__ ndot,
    int do_relu)
{
    int wv = (blockIdx.x * blockDim.x + threadIdx.x) >> 6;
    int lane = threadIdx.x & 63;
    int half = lane >> 5;
    int lloc = lane & 31;
    int n = wv * 2 + half;
    if (n >= N_NODES) return;           // N even: whole wave exits together
    const int hh = lloc >> 2;           // head for channels lloc*8..lloc*8+7
    const int shbase = half << 5;
    const float adv = a_d[n * NHEAD + hh];
    const int beg = row_ptr[n], end = row_ptr[n + 1];

    float a0=0.f,a1=0.f,a2=0.f,a3=0.f,a4=0.f,a5=0.f,a6=0.f,a7=0.f,den=0.f;

    for (int base = beg; base < end; base += 32) {
        int cnt = min(32, end - base);
        int sv = (base + lloc < end) ? esrc[base + lloc] : 0;
        int j = 0;
        for (; j + 4 <= cnt; j += 4) {
            int s0 = __shfl(sv, shbase + j);
            int s1 = __shfl(sv, shbase + j + 1);
            int s2 = __shfl(sv, shbase + j + 2);
            int s3 = __shfl(sv, shbase + j + 3);
            float e0 = a_s[s0 * NHEAD + hh];
            float e1 = a_s[s1 * NHEAD + hh];
            float e2 = a_s[s2 * NHEAD + hh];
            float e3 = a_s[s3 * NHEAD + hh];
            uint4 u0 = *(const uint4*)(hb + (size_t)s0 * HC + lloc * 8);
            uint4 u1 = *(const uint4*)(hb + (size_t)s1 * HC + lloc * 8);
            uint4 u2 = *(const uint4*)(hb + (size_t)s2 * HC + lloc * 8);
            uint4 u3 = *(const uint4*)(hb + (size_t)s3 * HC + lloc * 8);
            e0 += adv; e0 = (e0 > 0.f) ? e0 : 0.2f * e0; float w0 = __expf(e0);
            e1 += adv; e1 = (e1 > 0.f) ? e1 : 0.2f * e1; float w1 = __expf(e1);
            e2 += adv; e2 = (e2 > 0.f) ? e2 : 0.2f * e2; float w2 = __expf(e2);
            e3 += adv; e3 = (e3 > 0.f) ? e3 : 0.2f * e3; float w3 = __expf(e3);
            den += (w0 + w1) + (w2 + w3);
            a0 = fmaf(w0, bflo(u0.x), a0); a1 = fmaf(w0, bfhi(u0.x), a1);
            a2 = fmaf(w0, bflo(u0.y), a2); a3 = fmaf(w0, bfhi(u0.y), a3);
            a4 = fmaf(w0, bflo(u0.z), a4); a5 = fmaf(w0, bfhi(u0.z), a5);
            a6 = fmaf(w0, bflo(u0.w), a6); a7 = fmaf(w0, bfhi(u0.w), a7);
            a0 = fmaf(w1, bflo(u1.x), a0); a1 = fmaf(w1, bfhi(u1.x), a1);
            a2 = fmaf(w1, bflo(u1.y), a2); a3 = fmaf(w1, bfhi(u1.y), a3);
            a4 = fmaf(w1, bflo(u1.z), a4); a5 = fmaf(w1, bfhi(u1.z), a5);
            a6 = fmaf(w1, bflo(u1.w), a6); a7 = fmaf(w1, bfhi(u1.w), a7);
            a0 = fmaf(w2, bflo(u2.x), a0); a1 = fmaf(w2, bfhi(u2.x), a1);
            a2 = fmaf(w2, bflo(u2.y), a2); a3 = fmaf(w2, bfhi(u2.y), a3);
            a4 = fmaf(w2, bflo(u2.z), a4); a5 = fmaf(w2, bfhi(u2.z), a5);
            a6 = fmaf(w2, bflo(u2.w), a6); a7 = fmaf(w2, bfhi(u2.w), a7);
            a0 = fmaf(w3, bflo(u3.x), a0); a1 = fmaf(w3, bfhi(u3.x), a1);
            a2 = fmaf(w3, bflo(u3.y), a2); a3 = fmaf(w3, bfhi(u3.y), a3);
            a4 = fmaf(w3, bflo(u3.z), a4); a5 = fmaf(w3, bfhi(u3.z), a5);
            a6 = fmaf(w3, bflo(u3.w), a6); a7 = fmaf(w3, bfhi(u3.w), a7);
        }
        for (; j < cnt; j++) {
            int s = __shfl(sv, shbase + j);
            float e = a_s[s * NHEAD + hh] + adv;
            e = (e > 0.f) ? e : 0.2f * e;
            float w = __expf(e);
            den += w;
            uint4 u = *(const uint4*)(hb + (size_t)s * HC + lloc * 8);
            a0 = fmaf(w, bflo(u.x), a0); a1 = fmaf(w, bfhi(u.x), a1);
            a2 = fmaf(w, bflo(u.y), a2); a3 = fmaf(w, bfhi(u.y), a3);
            a4 = fmaf(w, bflo(u.z), a4); a5 = fmaf(w, bfhi(u.z), a5);
            a6 = fmaf(w, bflo(u.w), a6); a7 = fmaf(w, bfhi(u.w), a7);
        }
    }
    float inv = 1.f / den;
    float4 ba = *(const float4*)(bias + lloc * 8);
    float4 bb = *(const float4*)(bias + lloc * 8 + 4);
    float o0 = fmaf(a0, inv, ba.x), o1 = fmaf(a1, inv, ba.y);
    float o2 = fmaf(a2, inv, ba.z), o3 = fmaf(a3, inv, ba.w);
    float o4 = fmaf(a4, inv, bb.x), o5 = fmaf(a5, inv, bb.y);
    float o6 = fmaf(a6, inv, bb.z), o7 = fmaf(a7, inv, bb.w);
    if (do_relu) {
        o0 = fmaxf(o0, 0.f); o1 = fmaxf(o1, 0.f); o2 = fmaxf(o2, 0.f); o3 = fmaxf(o3, 0.f);
        o4 = fmaxf(o4, 0.f); o5 = fmaxf(o5, 0.f); o6 = fmaxf(o6, 0.f); o7 = fmaxf(o7, 0.f);
    }
    if (out_b) {
        uint4 ob;
        ob.x = (unsigned)f2bf(o0) | ((unsigned)f2bf(o1) << 16);
        ob.y = (unsigned)f2bf(o2) | ((unsigned)f2bf(o3) << 16);
        ob.z = (unsigned)f2bf(o4) | ((unsigned)f2bf(o5) << 16);
        ob.w = (unsigned)f2bf(o6) | ((unsigned)f2bf(o7) << 16);
        *(uint4*)(out_b + (size_t)n * HC + lloc * 8) = ob;
    }
    if (Wf) {
        float4 wa = *(const float4*)(Wf + lloc * 8);
        float4 wb = *(const float4*)(Wf + lloc * 8 + 4);
        float p = o0 * wa.x + o1 * wa.y + o2 * wa.z + o3 * wa.w
                + o4 * wb.x + o5 * wb.y + o6 * wb.z + o7 * wb.w;
        #pragma unroll
        for (int off = 16; off > 0; off >>= 1) p += __shfl_xor(p, off);  // within half
        if (lloc == 0) ndot[n] = p;
    }
}

// ------- per-graph mean over sorted batch (binary search, no atomics) -------
__global__ __launch_bounds__(256) void pool2_kernel(
    const float* __restrict__ ndot, const int* __restrict__ batch,
    const float* __restrict__ bf, float* __restrict__ outp)
{
    __shared__ float red[256];
    int g = blockIdx.x, t = threadIdx.x;
    int lo = 0, hi = N_NODES;
    while (lo < hi) { int mid = (lo + hi) >> 1; if (batch[mid] < g) lo = mid + 1; else hi = mid; }
    int start = lo;
    lo = 0; hi = N_NODES;
    while (lo < hi) { int mid = (lo + hi) >> 1; if (batch[mid] < g + 1) lo = mid + 1; else hi = mid; }
    int end = lo;
    float s = 0.f;
    for (int i = start + t; i < end; i += 256) s += ndot[i];
    red[t] = s;
    __syncthreads();
    for (int k = 128; k > 0; k >>= 1) {
        if (t < k) red[t] += red[t + k];
        __syncthreads();
    }
    if (t == 0) outp[g] = red[0] / fmaxf((float)(end - start), 1.f) + bf[0];
}

extern "C" void kernel_launch(void* const* d_in, const int* in_sizes, int n_in,
                              void* d_out, int out_size, void* d_ws, size_t ws_size,
                              hipStream_t stream)
{
    const float* x    = (const float*)d_in[0];
    const int*   ei   = (const int*)d_in[1];
    const int*   batch= (const int*)d_in[2];
    const float* W1   = (const float*)d_in[3];
    const float* as1  = (const float*)d_in[4];
    const float* ad1  = (const float*)d_in[5];
    const float* b1   = (const float*)d_in[6];
    const float* W2   = (const float*)d_in[7];
    const float* as2  = (const float*)d_in[8];
    const float* ad2  = (const float*)d_in[9];
    const float* b2   = (const float*)d_in[10];
    const float* W3   = (const float*)d_in[11];
    const float* as3  = (const float*)d_in[12];
    const float* ad3  = (const float*)d_in[13];
    const float* b3   = (const float*)d_in[14];
    const float* Wf   = (const float*)d_in[15];
    const float* bf   = (const float*)d_in[16];
    float* out = (float*)d_out;

    char* ws = (char*)d_ws;
    size_t off = 0;
    auto allocb = [&](size_t bytes) {
        void* p = ws + off;
        off += (bytes + 255) & ~(size_t)255;
        return p;
    };
    ushort* bufA    = (ushort*)allocb((size_t)N_NODES * HC * 2);
    ushort* bufB    = (ushort*)allocb((size_t)N_NODES * HC * 2);
    ushort* W1b     = (ushort*)allocb((size_t)HC * IN_CH * 2);
    ushort* W2b     = (ushort*)allocb((size_t)HC * HC * 2);
    ushort* W3b     = (ushort*)allocb((size_t)HC * HC * 2);
    float*  as_buf  = (float*) allocb((size_t)N_NODES * NHEAD * 4);
    float*  ad_buf  = (float*) allocb((size_t)N_NODES * NHEAD * 4);
    int*    deg     = (int*)   allocb(N_NODES * 4);
    int*    cur     = (int*)   allocb(N_NODES * 4);
    int*    row_ptr = (int*)   allocb((N_NODES + 1) * 4);
    int*    csum    = (int*)   allocb(64 * 4);
    int*    esrc    = (int*)   allocb(E_EXT * 4);
    float*  ndot    = (float*) allocb(N_NODES * 4);
    (void)ws_size; (void)in_sizes; (void)n_in; (void)out_size;

    // ---- bf16 conversions ----
    cvt_bf16_kernel<<<((size_t)N_NODES * IN_CH / 4 + 255) / 256, 256, 0, stream>>>(
        x, bufA, N_NODES * IN_CH / 4);
    cvt_bf16_kernel<<<(HC * IN_CH / 4 + 255) / 256, 256, 0, stream>>>(W1, W1b, HC * IN_CH / 4);
    cvt_bf16_kernel<<<(HC * HC / 4 + 255) / 256, 256, 0, stream>>>(W2, W2b, HC * HC / 4);
    cvt_bf16_kernel<<<(HC * HC / 4 + 255) / 256, 256, 0, stream>>>(W3, W3b, HC * HC / 4);

    // ---- CSR build ----
    hipMemsetAsync(deg, 0, N_NODES * sizeof(int), stream);
    hipMemsetAsync(cur, 0, N_NODES * sizeof(int), stream);
    hist_kernel<<<(E_EXT + 255) / 256, 256, 0, stream>>>(ei, deg);
    scan1_kernel<<<N_CHUNKS, SCAN_CHUNK, 0, stream>>>(deg, row_ptr, csum);
    scan2_kernel<<<1, 64, 0, stream>>>(csum);
    scan3_kernel<<<(N_NODES + 255) / 256, 256, 0, stream>>>(row_ptr, csum);
    scatter_kernel<<<(E_EXT + 255) / 256, 256, 0, stream>>>(ei, row_ptr, cur, esrc);

    dim3 ggrid((N_NODES + 127) / 128, HC / 128);
    const int gather_blocks = (((N_NODES + 1) / 2) * 64 + 255) / 256;   // 2 dst per wave
    const int att_blocks = (N_NODES * NHEAD + 255) / 256;

    // layer 1: A(x) -> B(h1) -> A(h1')
    mfma_gemm_kernel<<<ggrid, 256, 0, stream>>>(bufA, W1b, bufB, N_NODES, IN_CH);
    att_kernel<<<att_blocks, 256, 0, stream>>>(bufB, as1, ad1, as_buf, ad_buf);
    gather_kernel<<<gather_blocks, 256, 0, stream>>>(
        row_ptr, esrc, bufB, as_buf, ad_buf, b1, bufA, nullptr, nullptr, 1);
    // layer 2: A -> B -> A
    mfma_gemm_kernel<<<ggrid, 256, 0, stream>>>(bufA, W2b, bufB, N_NODES, HC);
    att_kernel<<<att_blocks, 256, 0, stream>>>(bufB, as2, ad2, as_buf, ad_buf);
    gather_kernel<<<gather_blocks, 256, 0, stream>>>(
        row_ptr, esrc, bufB, as_buf, ad_buf, b2, bufA, nullptr, nullptr, 1);
    // layer 3: A -> B -> ndot (fused final projection)
    mfma_gemm_kernel<<<ggrid, 256, 0, stream>>>(bufA, W3b, bufB, N_NODES, HC);
    att_kernel<<<att_blocks, 256, 0, stream>>>(bufB, as3, ad3, as_buf, ad_buf);
    gather_kernel<<<gather_blocks, 256, 0, stream>>>(
        row_ptr, esrc, bufB, as_buf, ad_buf, b3, nullptr, Wf, ndot, 0);

    pool2_kernel<<<NGRAPH, 256, 0, stream>>>(ndot, batch, bf, out);
}

// Round 7
// 370.102 us; speedup vs baseline: 25.3961x; 1.1485x over previous
//
#include <hip/hip_runtime.h>

#define N_NODES 50000
#define E_EDGES 800000
#define E_EXT   850000   // + self loops
#define IN_CH   128
#define HC      256
#define NHEAD   8
#define CH      32
#define NGRAPH  256
#define SCAN_CHUNK 1024
#define N_CHUNKS ((N_NODES + SCAN_CHUNK - 1) / SCAN_CHUNK)

typedef __bf16 bf16x8 __attribute__((ext_vector_type(8)));
typedef float  f32x4  __attribute__((ext_vector_type(4)));

__device__ inline ushort f2bf(float f) {
    union { float f; unsigned u; } v; v.f = f;
    unsigned u = v.u;
    unsigned r = u + 0x7FFFu + ((u >> 16) & 1u);
    return (ushort)(r >> 16);
}
__device__ inline float bflo(unsigned u) {
    union { unsigned u; float f; } v; v.u = u << 16; return v.f;
}
__device__ inline float bfhi(unsigned u) {
    union { unsigned u; float f; } v; v.u = u & 0xFFFF0000u; return v.f;
}

// ---------------- f32 -> bf16 (RNE) ----------------
__global__ __launch_bounds__(256) void cvt_bf16_kernel(
    const float* __restrict__ in, ushort* __restrict__ outp, int n4)
{
    int i = blockIdx.x * blockDim.x + threadIdx.x;
    if (i >= n4) return;
    float4 v = *(const float4*)(in + (size_t)i * 4);
    ushort4 o;
    o.x = f2bf(v.x); o.y = f2bf(v.y); o.z = f2bf(v.z); o.w = f2bf(v.w);
    *(ushort4*)(outp + (size_t)i * 4) = o;
}

// ------- merged weight cvt: W1 (HC*IN_CH) + W2 (HC*HC) + W3 (HC*HC) ----------
#define W1_N4 (HC * IN_CH / 4)
#define W23_N4 (HC * HC / 4)
__global__ __launch_bounds__(256) void cvt_weights_kernel(
    const float* __restrict__ W1, const float* __restrict__ W2,
    const float* __restrict__ W3,
    ushort* __restrict__ W1b, ushort* __restrict__ W2b, ushort* __restrict__ W3b)
{
    int i = blockIdx.x * blockDim.x + threadIdx.x;
    const float* src; ushort* dst; int k;
    if (i < W1_N4) { src = W1; dst = W1b; k = i; }
    else if (i < W1_N4 + W23_N4) { src = W2; dst = W2b; k = i - W1_N4; }
    else if (i < W1_N4 + 2 * W23_N4) { src = W3; dst = W3b; k = i - W1_N4 - W23_N4; }
    else return;
    float4 v = *(const float4*)(src + (size_t)k * 4);
    ushort4 o;
    o.x = f2bf(v.x); o.y = f2bf(v.y); o.z = f2bf(v.z); o.w = f2bf(v.w);
    *(ushort4*)(dst + (size_t)k * 4) = o;
}

// ------- MFMA GEMM 128x128 tile: Hb[M][HC] = Xb[M][F] @ Wb[HC][F]^T ----------
__global__ __launch_bounds__(256) void mfma_gemm_kernel(
    const ushort* __restrict__ Xb, const ushort* __restrict__ Wb,
    ushort* __restrict__ Hb, int M, int F)
{
    __shared__ ushort As[128][40];
    __shared__ ushort Bs[128][40];
    const int tid  = threadIdx.x;
    const int lane = tid & 63;
    const int wave = tid >> 6;
    const int wr = (wave >> 1) * 64;
    const int wc = (wave & 1) * 64;
    const int bm = blockIdx.x * 128;
    const int bn = blockIdx.y * 128;
    const int lrow = tid >> 2;
    const int lseg = (tid & 3) * 8;
    const int fr = lane & 15;
    const int fk = (lane >> 4) * 8;

    f32x4 zero = {0.f, 0.f, 0.f, 0.f};
    f32x4 acc[4][4];
    #pragma unroll
    for (int i = 0; i < 4; i++)
        #pragma unroll
        for (int j = 0; j < 4; j++) acc[i][j] = zero;

    for (int k0 = 0; k0 < F; k0 += 32) {
        #pragma unroll
        for (int rr = 0; rr < 2; rr++) {
            int row = lrow + rr * 64;
            int arow = bm + row;
            bf16x8 av = {};
            if (arow < M) av = *(const bf16x8*)(Xb + (size_t)arow * F + k0 + lseg);
            *(bf16x8*)(&As[row][lseg]) = av;
            bf16x8 bv = *(const bf16x8*)(Wb + (size_t)(bn + row) * F + k0 + lseg);
            *(bf16x8*)(&Bs[row][lseg]) = bv;
        }
        __syncthreads();
        bf16x8 a[4], b[4];
        #pragma unroll
        for (int i = 0; i < 4; i++) {
            a[i] = *(const bf16x8*)(&As[wr + i * 16 + fr][fk]);
            b[i] = *(const bf16x8*)(&Bs[wc + i * 16 + fr][fk]);
        }
        #pragma unroll
        for (int i = 0; i < 4; i++)
            #pragma unroll
            for (int j = 0; j < 4; j++)
                acc[i][j] = __builtin_amdgcn_mfma_f32_16x16x32_bf16(
                    a[i], b[j], acc[i][j], 0, 0, 0);
        __syncthreads();
    }
    const int rb = (lane >> 4) * 4;
    #pragma unroll
    for (int i = 0; i < 4; i++) {
        #pragma unroll
        for (int r = 0; r < 4; r++) {
            int m = bm + wr + i * 16 + rb + r;
            if (m < M) {
                #pragma unroll
                for (int j = 0; j < 4; j++)
                    Hb[(size_t)m * HC + bn + wc + j * 16 + fr] = f2bf(acc[i][j][r]);
            }
        }
    }
}

// ---------------- attention coefficients, layers 1-2 (bf16 h) ----------------
__global__ __launch_bounds__(256) void att_kernel(
    const ushort* __restrict__ hb,
    const float* __restrict__ att_s, const float* __restrict__ att_d,
    float* __restrict__ a_s, float* __restrict__ a_d)
{
    int idx = blockIdx.x * blockDim.x + threadIdx.x;
    if (idx >= N_NODES * NHEAD) return;
    int n = idx >> 3, hh = idx & 7;
    const uint4* row = (const uint4*)(hb + (size_t)n * HC + hh * CH);
    const float4* vs = (const float4*)(att_s + hh * CH);
    const float4* vd = (const float4*)(att_d + hh * CH);
    float ss = 0.f, sd = 0.f;
    #pragma unroll
    for (int q = 0; q < 4; q++) {
        uint4 u = row[q];
        float h0 = bflo(u.x), h1 = bfhi(u.x), h2 = bflo(u.y), h3 = bfhi(u.y);
        float h4 = bflo(u.z), h5 = bfhi(u.z), h6 = bflo(u.w), h7 = bfhi(u.w);
        float4 s0 = vs[q * 2], s1 = vs[q * 2 + 1];
        float4 d0 = vd[q * 2], d1 = vd[q * 2 + 1];
        ss += h0 * s0.x + h1 * s0.y + h2 * s0.z + h3 * s0.w
            + h4 * s1.x + h5 * s1.y + h6 * s1.z + h7 * s1.w;
        sd += h0 * d0.x + h1 * d0.y + h2 * d0.z + h3 * d0.w
            + h4 * d1.x + h5 * d1.y + h6 * d1.z + h7 * d1.w;
    }
    a_s[idx] = ss; a_d[idx] = sd;
}

// --- layer-3 attention: also hw[n][h] = dot(h_row_head, Wf_head); q={a_s,hw} ---
// block 0 / threads 0..7 additionally produce bw[h] = dot(b3_head, Wf_head)
__global__ __launch_bounds__(256) void att3_kernel(
    const ushort* __restrict__ hb,
    const float* __restrict__ att_s, const float* __restrict__ att_d,
    const float* __restrict__ Wf, const float* __restrict__ b3,
    float2* __restrict__ q, float* __restrict__ a_d, float* __restrict__ bw)
{
    int idx = blockIdx.x * blockDim.x + threadIdx.x;
    if (blockIdx.x == 0 && threadIdx.x < NHEAD) {
        float s = 0.f;
        for (int c = 0; c < CH; c++)
            s += b3[threadIdx.x * CH + c] * Wf[threadIdx.x * CH + c];
        bw[threadIdx.x] = s;
    }
    if (idx >= N_NODES * NHEAD) return;
    int n = idx >> 3, hh = idx & 7;
    const uint4* row = (const uint4*)(hb + (size_t)n * HC + hh * CH);
    const float4* vs = (const float4*)(att_s + hh * CH);
    const float4* vd = (const float4*)(att_d + hh * CH);
    const float4* vw = (const float4*)(Wf + hh * CH);
    float ss = 0.f, sd = 0.f, sw = 0.f;
    #pragma unroll
    for (int qq = 0; qq < 4; qq++) {
        uint4 u = row[qq];
        float h0 = bflo(u.x), h1 = bfhi(u.x), h2 = bflo(u.y), h3 = bfhi(u.y);
        float h4 = bflo(u.z), h5 = bfhi(u.z), h6 = bflo(u.w), h7 = bfhi(u.w);
        float4 s0 = vs[qq * 2], s1 = vs[qq * 2 + 1];
        float4 d0 = vd[qq * 2], d1 = vd[qq * 2 + 1];
        float4 w0 = vw[qq * 2], w1 = vw[qq * 2 + 1];
        ss += h0 * s0.x + h1 * s0.y + h2 * s0.z + h3 * s0.w
            + h4 * s1.x + h5 * s1.y + h6 * s1.z + h7 * s1.w;
        sd += h0 * d0.x + h1 * d0.y + h2 * d0.z + h3 * d0.w
            + h4 * d1.x + h5 * d1.y + h6 * d1.z + h7 * d1.w;
        sw += h0 * w0.x + h1 * w0.y + h2 * w0.z + h3 * w0.w
            + h4 * w1.x + h5 * w1.y + h6 * w1.z + h7 * w1.w;
    }
    q[idx] = make_float2(ss, sw);
    a_d[idx] = sd;
}

// ---------------- CSR build ----------------
__global__ __launch_bounds__(256) void hist_kernel(
    const int* __restrict__ ei, int* __restrict__ deg)
{
    int eid = blockIdx.x * blockDim.x + threadIdx.x;
    if (eid >= E_EXT) return;
    int d = (eid < E_EDGES) ? ei[E_EDGES + eid] : (eid - E_EDGES);
    atomicAdd(&deg[d], 1);
}

__global__ void scan1_kernel(const int* __restrict__ deg,
                             int* __restrict__ row_ptr, int* __restrict__ csum)
{
    __shared__ int buf[SCAN_CHUNK];
    int t = threadIdx.x;
    int base = blockIdx.x * SCAN_CHUNK;
    int v = (base + t < N_NODES) ? deg[base + t] : 0;
    buf[t] = v;
    __syncthreads();
    for (int off = 1; off < SCAN_CHUNK; off <<= 1) {
        int x = buf[t];
        int y = (t >= off) ? buf[t - off] : 0;
        __syncthreads();
        buf[t] = x + y;
        __syncthreads();
    }
    if (base + t < N_NODES) row_ptr[base + t] = buf[t] - v;
    if (t == SCAN_CHUNK - 1) csum[blockIdx.x] = buf[t];
}

__global__ void scan2_kernel(int* __restrict__ csum)
{
    __shared__ int buf[64];
    int t = threadIdx.x;
    int v = (t < N_CHUNKS) ? csum[t] : 0;
    buf[t] = v;
    __syncthreads();
    for (int off = 1; off < 64; off <<= 1) {
        int x = buf[t];
        int y = (t >= off) ? buf[t - off] : 0;
        __syncthreads();
        buf[t] = x + y;
        __syncthreads();
    }
    if (t < N_CHUNKS) csum[t] = buf[t] - v;
}

__global__ void scan3_kernel(int* __restrict__ row_ptr, const int* __restrict__ csum)
{
    int i = blockIdx.x * blockDim.x + threadIdx.x;
    if (i < N_NODES) row_ptr[i] += csum[i / SCAN_CHUNK];
    if (i == 0) row_ptr[N_NODES] = E_EXT;
}

__global__ __launch_bounds__(256) void scatter_kernel(
    const int* __restrict__ ei, const int* __restrict__ row_ptr,
    int* __restrict__ cur, int* __restrict__ esrc)
{
    int eid = blockIdx.x * blockDim.x + threadIdx.x;
    if (eid >= E_EXT) return;
    int s, d;
    if (eid < E_EDGES) { s = ei[eid]; d = ei[E_EDGES + eid]; }
    else { s = eid - E_EDGES; d = s; }
    int pos = row_ptr[d] + atomicAdd(&cur[d], 1);
    esrc[pos] = s;
}

// ------- heavy gather (layers 1-2): 2 dst per wave, 8 ch/lane via uint4 ------
__global__ __launch_bounds__(256) void gather_kernel(
    const int* __restrict__ row_ptr, const int* __restrict__ esrc,
    const ushort* __restrict__ hb,
    const float* __restrict__ a_s, const float* __restrict__ a_d,
    const float* __restrict__ bias,
    ushort* __restrict__ out_b)
{
    int wv = (blockIdx.x * blockDim.x + threadIdx.x) >> 6;
    int lane = threadIdx.x & 63;
    int half = lane >> 5;
    int lloc = lane & 31;
    int n = wv * 2 + half;
    if (n >= N_NODES) return;
    const int hh = lloc >> 2;
    const int shbase = half << 5;
    const float adv = a_d[n * NHEAD + hh];
    const int beg = row_ptr[n], end = row_ptr[n + 1];

    float a0=0.f,a1=0.f,a2=0.f,a3=0.f,a4=0.f,a5=0.f,a6=0.f,a7=0.f,den=0.f;

    for (int base = beg; base < end; base += 32) {
        int cnt = min(32, end - base);
        int sv = (base + lloc < end) ? esrc[base + lloc] : 0;
        int j = 0;
        for (; j + 4 <= cnt; j += 4) {
            int s0 = __shfl(sv, shbase + j);
            int s1 = __shfl(sv, shbase + j + 1);
            int s2 = __shfl(sv, shbase + j + 2);
            int s3 = __shfl(sv, shbase + j + 3);
            float e0 = a_s[s0 * NHEAD + hh];
            float e1 = a_s[s1 * NHEAD + hh];
            float e2 = a_s[s2 * NHEAD + hh];
            float e3 = a_s[s3 * NHEAD + hh];
            uint4 u0 = *(const uint4*)(hb + (size_t)s0 * HC + lloc * 8);
            uint4 u1 = *(const uint4*)(hb + (size_t)s1 * HC + lloc * 8);
            uint4 u2 = *(const uint4*)(hb + (size_t)s2 * HC + lloc * 8);
            uint4 u3 = *(const uint4*)(hb + (size_t)s3 * HC + lloc * 8);
            e0 += adv; e0 = (e0 > 0.f) ? e0 : 0.2f * e0; float w0 = __expf(e0);
            e1 += adv; e1 = (e1 > 0.f) ? e1 : 0.2f * e1; float w1 = __expf(e1);
            e2 += adv; e2 = (e2 > 0.f) ? e2 : 0.2f * e2; float w2 = __expf(e2);
            e3 += adv; e3 = (e3 > 0.f) ? e3 : 0.2f * e3; float w3 = __expf(e3);
            den += (w0 + w1) + (w2 + w3);
            a0 = fmaf(w0, bflo(u0.x), a0); a1 = fmaf(w0, bfhi(u0.x), a1);
            a2 = fmaf(w0, bflo(u0.y), a2); a3 = fmaf(w0, bfhi(u0.y), a3);
            a4 = fmaf(w0, bflo(u0.z), a4); a5 = fmaf(w0, bfhi(u0.z), a5);
            a6 = fmaf(w0, bflo(u0.w), a6); a7 = fmaf(w0, bfhi(u0.w), a7);
            a0 = fmaf(w1, bflo(u1.x), a0); a1 = fmaf(w1, bfhi(u1.x), a1);
            a2 = fmaf(w1, bflo(u1.y), a2); a3 = fmaf(w1, bfhi(u1.y), a3);
            a4 = fmaf(w1, bflo(u1.z), a4); a5 = fmaf(w1, bfhi(u1.z), a5);
            a6 = fmaf(w1, bflo(u1.w), a6); a7 = fmaf(w1, bfhi(u1.w), a7);
            a0 = fmaf(w2, bflo(u2.x), a0); a1 = fmaf(w2, bfhi(u2.x), a1);
            a2 = fmaf(w2, bflo(u2.y), a2); a3 = fmaf(w2, bfhi(u2.y), a3);
            a4 = fmaf(w2, bflo(u2.z), a4); a5 = fmaf(w2, bfhi(u2.z), a5);
            a6 = fmaf(w2, bflo(u2.w), a6); a7 = fmaf(w2, bfhi(u2.w), a7);
            a0 = fmaf(w3, bflo(u3.x), a0); a1 = fmaf(w3, bfhi(u3.x), a1);
            a2 = fmaf(w3, bflo(u3.y), a2); a3 = fmaf(w3, bfhi(u3.y), a3);
            a4 = fmaf(w3, bflo(u3.z), a4); a5 = fmaf(w3, bfhi(u3.z), a5);
            a6 = fmaf(w3, bflo(u3.w), a6); a7 = fmaf(w3, bfhi(u3.w), a7);
        }
        for (; j < cnt; j++) {
            int s = __shfl(sv, shbase + j);
            float e = a_s[s * NHEAD + hh] + adv;
            e = (e > 0.f) ? e : 0.2f * e;
            float w = __expf(e);
            den += w;
            uint4 u = *(const uint4*)(hb + (size_t)s * HC + lloc * 8);
            a0 = fmaf(w, bflo(u.x), a0); a1 = fmaf(w, bfhi(u.x), a1);
            a2 = fmaf(w, bflo(u.y), a2); a3 = fmaf(w, bfhi(u.y), a3);
            a4 = fmaf(w, bflo(u.z), a4); a5 = fmaf(w, bfhi(u.z), a5);
            a6 = fmaf(w, bflo(u.w), a6); a7 = fmaf(w, bfhi(u.w), a7);
        }
    }
    float inv = 1.f / den;
    float4 ba = *(const float4*)(bias + lloc * 8);
    float4 bb = *(const float4*)(bias + lloc * 8 + 4);
    float o0 = fmaf(a0, inv, ba.x), o1 = fmaf(a1, inv, ba.y);
    float o2 = fmaf(a2, inv, ba.z), o3 = fmaf(a3, inv, ba.w);
    float o4 = fmaf(a4, inv, bb.x), o5 = fmaf(a5, inv, bb.y);
    float o6 = fmaf(a6, inv, bb.z), o7 = fmaf(a7, inv, bb.w);
    o0 = fmaxf(o0, 0.f); o1 = fmaxf(o1, 0.f); o2 = fmaxf(o2, 0.f); o3 = fmaxf(o3, 0.f);
    o4 = fmaxf(o4, 0.f); o5 = fmaxf(o5, 0.f); o6 = fmaxf(o6, 0.f); o7 = fmaxf(o7, 0.f);
    uint4 ob;
    ob.x = (unsigned)f2bf(o0) | ((unsigned)f2bf(o1) << 16);
    ob.y = (unsigned)f2bf(o2) | ((unsigned)f2bf(o3) << 16);
    ob.z = (unsigned)f2bf(o4) | ((unsigned)f2bf(o5) << 16);
    ob.w = (unsigned)f2bf(o6) | ((unsigned)f2bf(o7) << 16);
    *(uint4*)(out_b + (size_t)n * HC + lloc * 8) = ob;
}

// ------- light gather (layer 3): thread per (dst,head), 8B per edge ---------
// ndot[n] = sum_h (sum_e w_e * hw[src][h]) / den_h + dot(b3,Wf)
__global__ __launch_bounds__(256) void light_gather_kernel(
    const int* __restrict__ row_ptr, const int* __restrict__ esrc,
    const float2* __restrict__ q, const float* __restrict__ a_d,
    const float* __restrict__ bw, float* __restrict__ ndot)
{
    int idx = blockIdx.x * blockDim.x + threadIdx.x;
    if (idx >= N_NODES * NHEAD) return;
    int n = idx >> 3, hh = idx & 7;
    const float adv = a_d[idx];
    const int beg = row_ptr[n], end = row_ptr[n + 1];
    float acc = 0.f, den = 0.f;
    int e = beg;
    for (; e + 4 <= end; e += 4) {
        int s0 = esrc[e], s1 = esrc[e + 1], s2 = esrc[e + 2], s3 = esrc[e + 3];
        float2 q0 = q[s0 * NHEAD + hh];
        float2 q1 = q[s1 * NHEAD + hh];
        float2 q2 = q[s2 * NHEAD + hh];
        float2 q3 = q[s3 * NHEAD + hh];
        float t0 = q0.x + adv; t0 = (t0 > 0.f) ? t0 : 0.2f * t0; float w0 = __expf(t0);
        float t1 = q1.x + adv; t1 = (t1 > 0.f) ? t1 : 0.2f * t1; float w1 = __expf(t1);
        float t2 = q2.x + adv; t2 = (t2 > 0.f) ? t2 : 0.2f * t2; float w2 = __expf(t2);
        float t3 = q3.x + adv; t3 = (t3 > 0.f) ? t3 : 0.2f * t3; float w3 = __expf(t3);
        den += (w0 + w1) + (w2 + w3);
        acc = fmaf(w0, q0.y, acc); acc = fmaf(w1, q1.y, acc);
        acc = fmaf(w2, q2.y, acc); acc = fmaf(w3, q3.y, acc);
    }
    for (; e < end; e++) {
        int s = esrc[e];
        float2 qv = q[s * NHEAD + hh];
        float t = qv.x + adv; t = (t > 0.f) ? t : 0.2f * t;
        float w = __expf(t);
        den += w;
        acc = fmaf(w, qv.y, acc);
    }
    float p = acc / den + bw[hh];
    #pragma unroll
    for (int off = 4; off > 0; off >>= 1) p += __shfl_xor(p, off);
    if (hh == 0) ndot[n] = p;
}

// ------- per-graph mean over sorted batch (binary search, no atomics) -------
__global__ __launch_bounds__(256) void pool2_kernel(
    const float* __restrict__ ndot, const int* __restrict__ batch,
    const float* __restrict__ bf, float* __restrict__ outp)
{
    __shared__ float red[256];
    int g = blockIdx.x, t = threadIdx.x;
    int lo = 0, hi = N_NODES;
    while (lo < hi) { int mid = (lo + hi) >> 1; if (batch[mid] < g) lo = mid + 1; else hi = mid; }
    int start = lo;
    lo = 0; hi = N_NODES;
    while (lo < hi) { int mid = (lo + hi) >> 1; if (batch[mid] < g + 1) lo = mid + 1; else hi = mid; }
    int end = lo;
    float s = 0.f;
    for (int i = start + t; i < end; i += 256) s += ndot[i];
    red[t] = s;
    __syncthreads();
    for (int k = 128; k > 0; k >>= 1) {
        if (t < k) red[t] += red[t + k];
        __syncthreads();
    }
    if (t == 0) outp[g] = red[0] / fmaxf((float)(end - start), 1.f) + bf[0];
}

extern "C" void kernel_launch(void* const* d_in, const int* in_sizes, int n_in,
                              void* d_out, int out_size, void* d_ws, size_t ws_size,
                              hipStream_t stream)
{
    const float* x    = (const float*)d_in[0];
    const int*   ei   = (const int*)d_in[1];
    const int*   batch= (const int*)d_in[2];
    const float* W1   = (const float*)d_in[3];
    const float* as1  = (const float*)d_in[4];
    const float* ad1  = (const float*)d_in[5];
    const float* b1   = (const float*)d_in[6];
    const float* W2   = (const float*)d_in[7];
    const float* as2  = (const float*)d_in[8];
    const float* ad2  = (const float*)d_in[9];
    const float* b2   = (const float*)d_in[10];
    const float* W3   = (const float*)d_in[11];
    const float* as3  = (const float*)d_in[12];
    const float* ad3  = (const float*)d_in[13];
    const float* b3   = (const float*)d_in[14];
    const float* Wf   = (const float*)d_in[15];
    const float* bf   = (const float*)d_in[16];
    float* out = (float*)d_out;

    char* ws = (char*)d_ws;
    size_t off = 0;
    auto allocb = [&](size_t bytes) {
        void* p = ws + off;
        off += (bytes + 255) & ~(size_t)255;
        return p;
    };
    ushort* bufA    = (ushort*)allocb((size_t)N_NODES * HC * 2);
    ushort* bufB    = (ushort*)allocb((size_t)N_NODES * HC * 2);
    ushort* W1b     = (ushort*)allocb((size_t)HC * IN_CH * 2);
    ushort* W2b     = (ushort*)allocb((size_t)HC * HC * 2);
    ushort* W3b     = (ushort*)allocb((size_t)HC * HC * 2);
    float*  as_buf  = (float*) allocb((size_t)N_NODES * NHEAD * 4);
    float*  ad_buf  = (float*) allocb((size_t)N_NODES * NHEAD * 4);
    float2* q_buf   = (float2*)allocb((size_t)N_NODES * NHEAD * 8);
    float*  bw_buf  = (float*) allocb(NHEAD * 4);
    int*    deg     = (int*)   allocb(N_NODES * 4);
    int*    cur     = (int*)   allocb(N_NODES * 4);
    int*    row_ptr = (int*)   allocb((N_NODES + 1) * 4);
    int*    csum    = (int*)   allocb(64 * 4);
    int*    esrc    = (int*)   allocb(E_EXT * 4);
    float*  ndot    = (float*) allocb(N_NODES * 4);
    (void)ws_size; (void)in_sizes; (void)n_in; (void)out_size;

    // ---- bf16 conversions ----
    cvt_bf16_kernel<<<((size_t)N_NODES * IN_CH / 4 + 255) / 256, 256, 0, stream>>>(
        x, bufA, N_NODES * IN_CH / 4);
    cvt_weights_kernel<<<(W1_N4 + 2 * W23_N4 + 255) / 256, 256, 0, stream>>>(
        W1, W2, W3, W1b, W2b, W3b);

    // ---- CSR build ----
    hipMemsetAsync(deg, 0, N_NODES * sizeof(int), stream);
    hipMemsetAsync(cur, 0, N_NODES * sizeof(int), stream);
    hist_kernel<<<(E_EXT + 255) / 256, 256, 0, stream>>>(ei, deg);
    scan1_kernel<<<N_CHUNKS, SCAN_CHUNK, 0, stream>>>(deg, row_ptr, csum);
    scan2_kernel<<<1, 64, 0, stream>>>(csum);
    scan3_kernel<<<(N_NODES + 255) / 256, 256, 0, stream>>>(row_ptr, csum);
    scatter_kernel<<<(E_EXT + 255) / 256, 256, 0, stream>>>(ei, row_ptr, cur, esrc);

    dim3 ggrid((N_NODES + 127) / 128, HC / 128);
    const int gather_blocks = (((N_NODES + 1) / 2) * 64 + 255) / 256;
    const int att_blocks = (N_NODES * NHEAD + 255) / 256;

    // layer 1: A(x) -> B(h1) -> A(h1')
    mfma_gemm_kernel<<<ggrid, 256, 0, stream>>>(bufA, W1b, bufB, N_NODES, IN_CH);
    att_kernel<<<att_blocks, 256, 0, stream>>>(bufB, as1, ad1, as_buf, ad_buf);
    gather_kernel<<<gather_blocks, 256, 0, stream>>>(
        row_ptr, esrc, bufB, as_buf, ad_buf, b1, bufA);
    // layer 2: A -> B -> A
    mfma_gemm_kernel<<<ggrid, 256, 0, stream>>>(bufA, W2b, bufB, N_NODES, HC);
    att_kernel<<<att_blocks, 256, 0, stream>>>(bufB, as2, ad2, as_buf, ad_buf);
    gather_kernel<<<gather_blocks, 256, 0, stream>>>(
        row_ptr, esrc, bufB, as_buf, ad_buf, b2, bufA);
    // layer 3: A -> B -> q/hw -> ndot (light gather, 8B per edge-head)
    mfma_gemm_kernel<<<ggrid, 256, 0, stream>>>(bufA, W3b, bufB, N_NODES, HC);
    att3_kernel<<<att_blocks, 256, 0, stream>>>(
        bufB, as3, ad3, Wf, b3, q_buf, ad_buf, bw_buf);
    light_gather_kernel<<<att_blocks, 256, 0, stream>>>(
        row_ptr, esrc, q_buf, ad_buf, bw_buf, ndot);

    pool2_kernel<<<NGRAPH, 256, 0, stream>>>(ndot, batch, bf, out);
}

// Round 8
// 358.814 us; speedup vs baseline: 26.1950x; 1.0315x over previous
//
#include <hip/hip_runtime.h>

#define N_NODES 50000
#define E_EDGES 800000
#define E_EXT   850000   // + self loops
#define IN_CH   128
#define HC      256
#define NHEAD   8
#define CH      32
#define NGRAPH  256
#define SCAN_CHUNK 1024
#define N_CHUNKS ((N_NODES + SCAN_CHUNK - 1) / SCAN_CHUNK)

typedef __bf16 bf16x8 __attribute__((ext_vector_type(8)));
typedef float  f32x4  __attribute__((ext_vector_type(4)));

__device__ inline ushort f2bf(float f) {
    union { float f; unsigned u; } v; v.f = f;
    unsigned u = v.u;
    unsigned r = u + 0x7FFFu + ((u >> 16) & 1u);
    return (ushort)(r >> 16);
}
__device__ inline float bflo(unsigned u) {
    union { unsigned u; float f; } v; v.u = u << 16; return v.f;
}
__device__ inline float bfhi(unsigned u) {
    union { unsigned u; float f; } v; v.u = u & 0xFFFF0000u; return v.f;
}

// ------- merged weight cvt: W1 (HC*IN_CH) + W2 (HC*HC) + W3 (HC*HC) ----------
#define W1_N4 (HC * IN_CH / 4)
#define W23_N4 (HC * HC / 4)
__global__ __launch_bounds__(256) void cvt_weights_kernel(
    const float* __restrict__ W1, const float* __restrict__ W2,
    const float* __restrict__ W3,
    ushort* __restrict__ W1b, ushort* __restrict__ W2b, ushort* __restrict__ W3b)
{
    int i = blockIdx.x * blockDim.x + threadIdx.x;
    const float* src; ushort* dst; int k;
    if (i < W1_N4) { src = W1; dst = W1b; k = i; }
    else if (i < W1_N4 + W23_N4) { src = W2; dst = W2b; k = i - W1_N4; }
    else if (i < W1_N4 + 2 * W23_N4) { src = W3; dst = W3b; k = i - W1_N4 - W23_N4; }
    else return;
    float4 v = *(const float4*)(src + (size_t)k * 4);
    ushort4 o;
    o.x = f2bf(v.x); o.y = f2bf(v.y); o.z = f2bf(v.z); o.w = f2bf(v.w);
    *(ushort4*)(dst + (size_t)k * 4) = o;
}

// ------- bw[h] = dot(b3_head, Wf_head) ----------
__global__ void bw_kernel(const float* __restrict__ b3, const float* __restrict__ Wf,
                          float* __restrict__ bw)
{
    int h = threadIdx.x;
    if (h >= NHEAD) return;
    float s = 0.f;
    for (int c = 0; c < CH; c++) s += b3[h * CH + c] * Wf[h * CH + c];
    bw[h] = s;
}

// ------- MFMA GEMM 128x128 tile + fused attention-coefficient epilogue -------
// Hb[M][HC] = X @ W^T. X is bf16 (Xb) or f32 (Xf, converted in-register).
// Epilogue (from f32 accumulators, 16-lane shfl reduction per head):
//   a_s[m][h], a_d[m][h]  (att_s/att_d per-channel weights)
//   layer 3 (wf != null): q[m][h] = {a_s, dot(h_row_head, Wf_head)}, Hb skipped
__global__ __launch_bounds__(256) void mfma_gemm_kernel(
    const ushort* __restrict__ Xb, const float* __restrict__ Xf,
    const ushort* __restrict__ Wb,
    ushort* __restrict__ Hb, int M, int F,
    const float* __restrict__ att_s, const float* __restrict__ att_d,
    const float* __restrict__ wf,
    float* __restrict__ as_out, float* __restrict__ ad_out,
    float2* __restrict__ q_out)
{
    __shared__ ushort As[128][40];
    __shared__ ushort Bs[128][40];
    const int tid  = threadIdx.x;
    const int lane = tid & 63;
    const int wave = tid >> 6;
    const int wr = (wave >> 1) * 64;
    const int wc = (wave & 1) * 64;
    const int bm = blockIdx.x * 128;
    const int bn = blockIdx.y * 128;
    const int lrow = tid >> 2;
    const int lseg = (tid & 3) * 8;
    const int fr = lane & 15;
    const int fk = (lane >> 4) * 8;

    f32x4 zero = {0.f, 0.f, 0.f, 0.f};
    f32x4 acc[4][4];
    #pragma unroll
    for (int i = 0; i < 4; i++)
        #pragma unroll
        for (int j = 0; j < 4; j++) acc[i][j] = zero;

    for (int k0 = 0; k0 < F; k0 += 32) {
        #pragma unroll
        for (int rr = 0; rr < 2; rr++) {
            int row = lrow + rr * 64;
            int arow = bm + row;
            bf16x8 av = {};
            if (Xf) {
                if (arow < M) {
                    float4 lo = *(const float4*)(Xf + (size_t)arow * F + k0 + lseg);
                    float4 hi = *(const float4*)(Xf + (size_t)arow * F + k0 + lseg + 4);
                    ushort t[8] = { f2bf(lo.x), f2bf(lo.y), f2bf(lo.z), f2bf(lo.w),
                                    f2bf(hi.x), f2bf(hi.y), f2bf(hi.z), f2bf(hi.w) };
                    av = *(const bf16x8*)t;
                }
            } else {
                if (arow < M) av = *(const bf16x8*)(Xb + (size_t)arow * F + k0 + lseg);
            }
            *(bf16x8*)(&As[row][lseg]) = av;
            bf16x8 bv = *(const bf16x8*)(Wb + (size_t)(bn + row) * F + k0 + lseg);
            *(bf16x8*)(&Bs[row][lseg]) = bv;
        }
        __syncthreads();
        bf16x8 a[4], b[4];
        #pragma unroll
        for (int i = 0; i < 4; i++) {
            a[i] = *(const bf16x8*)(&As[wr + i * 16 + fr][fk]);
            b[i] = *(const bf16x8*)(&Bs[wc + i * 16 + fr][fk]);
        }
        #pragma unroll
        for (int i = 0; i < 4; i++)
            #pragma unroll
            for (int j = 0; j < 4; j++)
                acc[i][j] = __builtin_amdgcn_mfma_f32_16x16x32_bf16(
                    a[i], b[j], acc[i][j], 0, 0, 0);
        __syncthreads();
    }

    const int rb = (lane >> 4) * 4;
    const int h0 = (bn >> 5) + (wc >> 5);   // head of cols j=0,1; h0+1 for j=2,3

    // per-lane attention weights (channel within head = j*16 + fr)
    const float wsa0 = att_s[h0 * CH + fr],        wsa1 = att_s[h0 * CH + 16 + fr];
    const float wda0 = att_d[h0 * CH + fr],        wda1 = att_d[h0 * CH + 16 + fr];
    const float wsb0 = att_s[(h0 + 1) * CH + fr],  wsb1 = att_s[(h0 + 1) * CH + 16 + fr];
    const float wdb0 = att_d[(h0 + 1) * CH + fr],  wdb1 = att_d[(h0 + 1) * CH + 16 + fr];
    float wfa0 = 0.f, wfa1 = 0.f, wfb0 = 0.f, wfb1 = 0.f;
    if (wf) {
        wfa0 = wf[h0 * CH + fr];       wfa1 = wf[h0 * CH + 16 + fr];
        wfb0 = wf[(h0 + 1) * CH + fr]; wfb1 = wf[(h0 + 1) * CH + 16 + fr];
    }

    #pragma unroll
    for (int i = 0; i < 4; i++) {
        #pragma unroll
        for (int r = 0; r < 4; r++) {
            int m = bm + wr + i * 16 + rb + r;
            if (Hb && m < M) {
                #pragma unroll
                for (int j = 0; j < 4; j++)
                    Hb[(size_t)m * HC + bn + wc + j * 16 + fr] = f2bf(acc[i][j][r]);
            }
            // fused attention coefficients (reduce 16 cols per head over 16 lanes)
            float psa = acc[i][0][r] * wsa0 + acc[i][1][r] * wsa1;
            float pda = acc[i][0][r] * wda0 + acc[i][1][r] * wda1;
            float psb = acc[i][2][r] * wsb0 + acc[i][3][r] * wsb1;
            float pdb = acc[i][2][r] * wdb0 + acc[i][3][r] * wdb1;
            float pwa = 0.f, pwb = 0.f;
            if (wf) {
                pwa = acc[i][0][r] * wfa0 + acc[i][1][r] * wfa1;
                pwb = acc[i][2][r] * wfb0 + acc[i][3][r] * wfb1;
            }
            #pragma unroll
            for (int off = 1; off < 16; off <<= 1) {
                psa += __shfl_xor(psa, off);
                pda += __shfl_xor(pda, off);
                psb += __shfl_xor(psb, off);
                pdb += __shfl_xor(pdb, off);
                if (wf) { pwa += __shfl_xor(pwa, off); pwb += __shfl_xor(pwb, off); }
            }
            if (fr == 0 && m < M) {
                if (q_out) {
                    q_out[m * NHEAD + h0]     = make_float2(psa, pwa);
                    q_out[m * NHEAD + h0 + 1] = make_float2(psb, pwb);
                } else {
                    as_out[m * NHEAD + h0]     = psa;
                    as_out[m * NHEAD + h0 + 1] = psb;
                }
                ad_out[m * NHEAD + h0]     = pda;
                ad_out[m * NHEAD + h0 + 1] = pdb;
            }
        }
    }
}

// ---------------- CSR build ----------------
__global__ __launch_bounds__(256) void hist_kernel(
    const int* __restrict__ ei, int* __restrict__ deg)
{
    int eid = blockIdx.x * blockDim.x + threadIdx.x;
    if (eid >= E_EXT) return;
    int d = (eid < E_EDGES) ? ei[E_EDGES + eid] : (eid - E_EDGES);
    atomicAdd(&deg[d], 1);
}

__global__ void scan1_kernel(const int* __restrict__ deg,
                             int* __restrict__ row_ptr, int* __restrict__ csum)
{
    __shared__ int buf[SCAN_CHUNK];
    int t = threadIdx.x;
    int base = blockIdx.x * SCAN_CHUNK;
    int v = (base + t < N_NODES) ? deg[base + t] : 0;
    buf[t] = v;
    __syncthreads();
    for (int off = 1; off < SCAN_CHUNK; off <<= 1) {
        int x = buf[t];
        int y = (t >= off) ? buf[t - off] : 0;
        __syncthreads();
        buf[t] = x + y;
        __syncthreads();
    }
    if (base + t < N_NODES) row_ptr[base + t] = buf[t] - v;
    if (t == SCAN_CHUNK - 1) csum[blockIdx.x] = buf[t];
}

__global__ void scan2_kernel(int* __restrict__ csum)
{
    __shared__ int buf[64];
    int t = threadIdx.x;
    int v = (t < N_CHUNKS) ? csum[t] : 0;
    buf[t] = v;
    __syncthreads();
    for (int off = 1; off < 64; off <<= 1) {
        int x = buf[t];
        int y = (t >= off) ? buf[t - off] : 0;
        __syncthreads();
        buf[t] = x + y;
        __syncthreads();
    }
    if (t < N_CHUNKS) csum[t] = buf[t] - v;
}

__global__ void scan3_kernel(int* __restrict__ row_ptr, const int* __restrict__ csum)
{
    int i = blockIdx.x * blockDim.x + threadIdx.x;
    if (i < N_NODES) row_ptr[i] += csum[i / SCAN_CHUNK];
    if (i == 0) row_ptr[N_NODES] = E_EXT;
}

__global__ __launch_bounds__(256) void scatter_kernel(
    const int* __restrict__ ei, const int* __restrict__ row_ptr,
    int* __restrict__ cur, int* __restrict__ esrc)
{
    int eid = blockIdx.x * blockDim.x + threadIdx.x;
    if (eid >= E_EXT) return;
    int s, d;
    if (eid < E_EDGES) { s = ei[eid]; d = ei[E_EDGES + eid]; }
    else { s = eid - E_EDGES; d = s; }
    int pos = row_ptr[d] + atomicAdd(&cur[d], 1);
    esrc[pos] = s;
}

// ------- heavy gather (layers 1-2): 2 dst per wave, 8 ch/lane via uint4 ------
__global__ __launch_bounds__(256) void gather_kernel(
    const int* __restrict__ row_ptr, const int* __restrict__ esrc,
    const ushort* __restrict__ hb,
    const float* __restrict__ a_s, const float* __restrict__ a_d,
    const float* __restrict__ bias,
    ushort* __restrict__ out_b)
{
    int wv = (blockIdx.x * blockDim.x + threadIdx.x) >> 6;
    int lane = threadIdx.x & 63;
    int half = lane >> 5;
    int lloc = lane & 31;
    int n = wv * 2 + half;
    if (n >= N_NODES) return;
    const int hh = lloc >> 2;
    const int shbase = half << 5;
    const float adv = a_d[n * NHEAD + hh];
    const int beg = row_ptr[n], end = row_ptr[n + 1];

    float a0=0.f,a1=0.f,a2=0.f,a3=0.f,a4=0.f,a5=0.f,a6=0.f,a7=0.f,den=0.f;

    for (int base = beg; base < end; base += 32) {
        int cnt = min(32, end - base);
        int sv = (base + lloc < end) ? esrc[base + lloc] : 0;
        int j = 0;
        for (; j + 4 <= cnt; j += 4) {
            int s0 = __shfl(sv, shbase + j);
            int s1 = __shfl(sv, shbase + j + 1);
            int s2 = __shfl(sv, shbase + j + 2);
            int s3 = __shfl(sv, shbase + j + 3);
            float e0 = a_s[s0 * NHEAD + hh];
            float e1 = a_s[s1 * NHEAD + hh];
            float e2 = a_s[s2 * NHEAD + hh];
            float e3 = a_s[s3 * NHEAD + hh];
            uint4 u0 = *(const uint4*)(hb + (size_t)s0 * HC + lloc * 8);
            uint4 u1 = *(const uint4*)(hb + (size_t)s1 * HC + lloc * 8);
            uint4 u2 = *(const uint4*)(hb + (size_t)s2 * HC + lloc * 8);
            uint4 u3 = *(const uint4*)(hb + (size_t)s3 * HC + lloc * 8);
            e0 += adv; e0 = (e0 > 0.f) ? e0 : 0.2f * e0; float w0 = __expf(e0);
            e1 += adv; e1 = (e1 > 0.f) ? e1 : 0.2f * e1; float w1 = __expf(e1);
            e2 += adv; e2 = (e2 > 0.f) ? e2 : 0.2f * e2; float w2 = __expf(e2);
            e3 += adv; e3 = (e3 > 0.f) ? e3 : 0.2f * e3; float w3 = __expf(e3);
            den += (w0 + w1) + (w2 + w3);
            a0 = fmaf(w0, bflo(u0.x), a0); a1 = fmaf(w0, bfhi(u0.x), a1);
            a2 = fmaf(w0, bflo(u0.y), a2); a3 = fmaf(w0, bfhi(u0.y), a3);
            a4 = fmaf(w0, bflo(u0.z), a4); a5 = fmaf(w0, bfhi(u0.z), a5);
            a6 = fmaf(w0, bflo(u0.w), a6); a7 = fmaf(w0, bfhi(u0.w), a7);
            a0 = fmaf(w1, bflo(u1.x), a0); a1 = fmaf(w1, bfhi(u1.x), a1);
            a2 = fmaf(w1, bflo(u1.y), a2); a3 = fmaf(w1, bfhi(u1.y), a3);
            a4 = fmaf(w1, bflo(u1.z), a4); a5 = fmaf(w1, bfhi(u1.z), a5);
            a6 = fmaf(w1, bflo(u1.w), a6); a7 = fmaf(w1, bfhi(u1.w), a7);
            a0 = fmaf(w2, bflo(u2.x), a0); a1 = fmaf(w2, bfhi(u2.x), a1);
            a2 = fmaf(w2, bflo(u2.y), a2); a3 = fmaf(w2, bfhi(u2.y), a3);
            a4 = fmaf(w2, bflo(u2.z), a4); a5 = fmaf(w2, bfhi(u2.z), a5);
            a6 = fmaf(w2, bflo(u2.w), a6); a7 = fmaf(w2, bfhi(u2.w), a7);
            a0 = fmaf(w3, bflo(u3.x), a0); a1 = fmaf(w3, bfhi(u3.x), a1);
            a2 = fmaf(w3, bflo(u3.y), a2); a3 = fmaf(w3, bfhi(u3.y), a3);
            a4 = fmaf(w3, bflo(u3.z), a4); a5 = fmaf(w3, bfhi(u3.z), a5);
            a6 = fmaf(w3, bflo(u3.w), a6); a7 = fmaf(w3, bfhi(u3.w), a7);
        }
        for (; j < cnt; j++) {
            int s = __shfl(sv, shbase + j);
            float e = a_s[s * NHEAD + hh] + adv;
            e = (e > 0.f) ? e : 0.2f * e;
            float w = __expf(e);
            den += w;
            uint4 u = *(const uint4*)(hb + (size_t)s * HC + lloc * 8);
            a0 = fmaf(w, bflo(u.x), a0); a1 = fmaf(w, bfhi(u.x), a1);
            a2 = fmaf(w, bflo(u.y), a2); a3 = fmaf(w, bfhi(u.y), a3);
            a4 = fmaf(w, bflo(u.z), a4); a5 = fmaf(w, bfhi(u.z), a5);
            a6 = fmaf(w, bflo(u.w), a6); a7 = fmaf(w, bfhi(u.w), a7);
        }
    }
    float inv = 1.f / den;
    float4 ba = *(const float4*)(bias + lloc * 8);
    float4 bb = *(const float4*)(bias + lloc * 8 + 4);
    float o0 = fmaf(a0, inv, ba.x), o1 = fmaf(a1, inv, ba.y);
    float o2 = fmaf(a2, inv, ba.z), o3 = fmaf(a3, inv, ba.w);
    float o4 = fmaf(a4, inv, bb.x), o5 = fmaf(a5, inv, bb.y);
    float o6 = fmaf(a6, inv, bb.z), o7 = fmaf(a7, inv, bb.w);
    o0 = fmaxf(o0, 0.f); o1 = fmaxf(o1, 0.f); o2 = fmaxf(o2, 0.f); o3 = fmaxf(o3, 0.f);
    o4 = fmaxf(o4, 0.f); o5 = fmaxf(o5, 0.f); o6 = fmaxf(o6, 0.f); o7 = fmaxf(o7, 0.f);
    uint4 ob;
    ob.x = (unsigned)f2bf(o0) | ((unsigned)f2bf(o1) << 16);
    ob.y = (unsigned)f2bf(o2) | ((unsigned)f2bf(o3) << 16);
    ob.z = (unsigned)f2bf(o4) | ((unsigned)f2bf(o5) << 16);
    ob.w = (unsigned)f2bf(o6) | ((unsigned)f2bf(o7) << 16);
    *(uint4*)(out_b + (size_t)n * HC + lloc * 8) = ob;
}

// ------- light gather (layer 3): thread per (dst,head), 8B per edge ---------
__global__ __launch_bounds__(256) void light_gather_kernel(
    const int* __restrict__ row_ptr, const int* __restrict__ esrc,
    const float2* __restrict__ q, const float* __restrict__ a_d,
    const float* __restrict__ bw, float* __restrict__ ndot)
{
    int idx = blockIdx.x * blockDim.x + threadIdx.x;
    if (idx >= N_NODES * NHEAD) return;
    int n = idx >> 3, hh = idx & 7;
    const float adv = a_d[idx];
    const int beg = row_ptr[n], end = row_ptr[n + 1];
    float acc = 0.f, den = 0.f;
    int e = beg;
    for (; e + 4 <= end; e += 4) {
        int s0 = esrc[e], s1 = esrc[e + 1], s2 = esrc[e + 2], s3 = esrc[e + 3];
        float2 q0 = q[s0 * NHEAD + hh];
        float2 q1 = q[s1 * NHEAD + hh];
        float2 q2 = q[s2 * NHEAD + hh];
        float2 q3 = q[s3 * NHEAD + hh];
        float t0 = q0.x + adv; t0 = (t0 > 0.f) ? t0 : 0.2f * t0; float w0 = __expf(t0);
        float t1 = q1.x + adv; t1 = (t1 > 0.f) ? t1 : 0.2f * t1; float w1 = __expf(t1);
        float t2 = q2.x + adv; t2 = (t2 > 0.f) ? t2 : 0.2f * t2; float w2 = __expf(t2);
        float t3 = q3.x + adv; t3 = (t3 > 0.f) ? t3 : 0.2f * t3; float w3 = __expf(t3);
        den += (w0 + w1) + (w2 + w3);
        acc = fmaf(w0, q0.y, acc); acc = fmaf(w1, q1.y, acc);
        acc = fmaf(w2, q2.y, acc); acc = fmaf(w3, q3.y, acc);
    }
    for (; e < end; e++) {
        int s = esrc[e];
        float2 qv = q[s * NHEAD + hh];
        float t = qv.x + adv; t = (t > 0.f) ? t : 0.2f * t;
        float w = __expf(t);
        den += w;
        acc = fmaf(w, qv.y, acc);
    }
    float p = acc / den + bw[hh];
    #pragma unroll
    for (int off = 4; off > 0; off >>= 1) p += __shfl_xor(p, off);
    if (hh == 0) ndot[n] = p;
}

// ------- per-graph mean over sorted batch (binary search, no atomics) -------
__global__ __launch_bounds__(256) void pool2_kernel(
    const float* __restrict__ ndot, const int* __restrict__ batch,
    const float* __restrict__ bf, float* __restrict__ outp)
{
    __shared__ float red[256];
    int g = blockIdx.x, t = threadIdx.x;
    int lo = 0, hi = N_NODES;
    while (lo < hi) { int mid = (lo + hi) >> 1; if (batch[mid] < g) lo = mid + 1; else hi = mid; }
    int start = lo;
    lo = 0; hi = N_NODES;
    while (lo < hi) { int mid = (lo + hi) >> 1; if (batch[mid] < g + 1) lo = mid + 1; else hi = mid; }
    int end = lo;
    float s = 0.f;
    for (int i = start + t; i < end; i += 256) s += ndot[i];
    red[t] = s;
    __syncthreads();
    for (int k = 128; k > 0; k >>= 1) {
        if (t < k) red[t] += red[t + k];
        __syncthreads();
    }
    if (t == 0) outp[g] = red[0] / fmaxf((float)(end - start), 1.f) + bf[0];
}

extern "C" void kernel_launch(void* const* d_in, const int* in_sizes, int n_in,
                              void* d_out, int out_size, void* d_ws, size_t ws_size,
                              hipStream_t stream)
{
    const float* x    = (const float*)d_in[0];
    const int*   ei   = (const int*)d_in[1];
    const int*   batch= (const int*)d_in[2];
    const float* W1   = (const float*)d_in[3];
    const float* as1  = (const float*)d_in[4];
    const float* ad1  = (const float*)d_in[5];
    const float* b1   = (const float*)d_in[6];
    const float* W2   = (const float*)d_in[7];
    const float* as2  = (const float*)d_in[8];
    const float* ad2  = (const float*)d_in[9];
    const float* b2   = (const float*)d_in[10];
    const float* W3   = (const float*)d_in[11];
    const float* as3  = (const float*)d_in[12];
    const float* ad3  = (const float*)d_in[13];
    const float* b3   = (const float*)d_in[14];
    const float* Wf   = (const float*)d_in[15];
    const float* bf   = (const float*)d_in[16];
    float* out = (float*)d_out;

    char* ws = (char*)d_ws;
    size_t off = 0;
    auto allocb = [&](size_t bytes) {
        void* p = ws + off;
        off += (bytes + 255) & ~(size_t)255;
        return p;
    };
    ushort* bufA    = (ushort*)allocb((size_t)N_NODES * HC * 2);
    ushort* bufB    = (ushort*)allocb((size_t)N_NODES * HC * 2);
    ushort* W1b     = (ushort*)allocb((size_t)HC * IN_CH * 2);
    ushort* W2b     = (ushort*)allocb((size_t)HC * HC * 2);
    ushort* W3b     = (ushort*)allocb((size_t)HC * HC * 2);
    float*  as_buf  = (float*) allocb((size_t)N_NODES * NHEAD * 4);
    float*  ad_buf  = (float*) allocb((size_t)N_NODES * NHEAD * 4);
    float2* q_buf   = (float2*)allocb((size_t)N_NODES * NHEAD * 8);
    float*  bw_buf  = (float*) allocb(NHEAD * 4);
    int*    deg     = (int*)   allocb(N_NODES * 4);
    int*    cur     = (int*)   allocb(N_NODES * 4);
    int*    row_ptr = (int*)   allocb((N_NODES + 1) * 4);
    int*    csum    = (int*)   allocb(64 * 4);
    int*    esrc    = (int*)   allocb(E_EXT * 4);
    float*  ndot    = (float*) allocb(N_NODES * 4);
    (void)ws_size; (void)in_sizes; (void)n_in; (void)out_size;

    // ---- weight bf16 conversion + bw ----
    cvt_weights_kernel<<<(W1_N4 + 2 * W23_N4 + 255) / 256, 256, 0, stream>>>(
        W1, W2, W3, W1b, W2b, W3b);
    bw_kernel<<<1, 64, 0, stream>>>(b3, Wf, bw_buf);

    // ---- CSR build ----
    hipMemsetAsync(deg, 0, N_NODES * sizeof(int), stream);
    hipMemsetAsync(cur, 0, N_NODES * sizeof(int), stream);
    hist_kernel<<<(E_EXT + 255) / 256, 256, 0, stream>>>(ei, deg);
    scan1_kernel<<<N_CHUNKS, SCAN_CHUNK, 0, stream>>>(deg, row_ptr, csum);
    scan2_kernel<<<1, 64, 0, stream>>>(csum);
    scan3_kernel<<<(N_NODES + 255) / 256, 256, 0, stream>>>(row_ptr, csum);
    scatter_kernel<<<(E_EXT + 255) / 256, 256, 0, stream>>>(ei, row_ptr, cur, esrc);

    dim3 ggrid((N_NODES + 127) / 128, HC / 128);
    const int gather_blocks = (((N_NODES + 1) / 2) * 64 + 255) / 256;

    // layer 1: x(f32) -> B(h1 + a_s/a_d) -> A(h1')
    mfma_gemm_kernel<<<ggrid, 256, 0, stream>>>(
        nullptr, x, W1b, bufB, N_NODES, IN_CH, as1, ad1, nullptr,
        as_buf, ad_buf, nullptr);
    gather_kernel<<<gather_blocks, 256, 0, stream>>>(
        row_ptr, esrc, bufB, as_buf, ad_buf, b1, bufA);
    // layer 2: A -> B(h2 + a_s/a_d) -> A
    mfma_gemm_kernel<<<ggrid, 256, 0, stream>>>(
        bufA, nullptr, W2b, bufB, N_NODES, HC, as2, ad2, nullptr,
        as_buf, ad_buf, nullptr);
    gather_kernel<<<gather_blocks, 256, 0, stream>>>(
        row_ptr, esrc, bufB, as_buf, ad_buf, b2, bufA);
    // layer 3: A -> q/a_d only (no Hb store) -> ndot (light gather)
    mfma_gemm_kernel<<<ggrid, 256, 0, stream>>>(
        bufA, nullptr, W3b, nullptr, N_NODES, HC, as3, ad3, Wf,
        nullptr, ad_buf, q_buf);
    light_gather_kernel<<<(N_NODES * NHEAD + 255) / 256, 256, 0, stream>>>(
        row_ptr, esrc, q_buf, ad_buf, bw_buf, ndot);

    pool2_kernel<<<NGRAPH, 256, 0, stream>>>(ndot, batch, bf, out);
}

// Round 9
// 348.832 us; speedup vs baseline: 26.9446x; 1.0286x over previous
//
#include <hip/hip_runtime.h>

#define N_NODES 50000
#define E_EDGES 800000
#define E_EXT   850000   // + self loops
#define IN_CH   128
#define HC      256
#define NHEAD   8
#define CH      32
#define NGRAPH  256
#define SCAN_CHUNK 1024
#define N_CHUNKS ((N_NODES + SCAN_CHUNK - 1) / SCAN_CHUNK)

typedef __bf16 bf16x8 __attribute__((ext_vector_type(8)));
typedef float  f32x4  __attribute__((ext_vector_type(4)));

__device__ inline ushort f2bf(float f) {
    union { float f; unsigned u; } v; v.f = f;
    unsigned u = v.u;
    unsigned r = u + 0x7FFFu + ((u >> 16) & 1u);
    return (ushort)(r >> 16);
}
__device__ inline float bflo(unsigned u) {
    union { unsigned u; float f; } v; v.u = u << 16; return v.f;
}
__device__ inline float bfhi(unsigned u) {
    union { unsigned u; float f; } v; v.u = u & 0xFFFF0000u; return v.f;
}

// ------- merged weight cvt: W1 + W2 + W3 (+ bw[h] = dot(b3_h, Wf_h)) ---------
#define W1_N4 (HC * IN_CH / 4)
#define W23_N4 (HC * HC / 4)
__global__ __launch_bounds__(256) void cvt_weights_kernel(
    const float* __restrict__ W1, const float* __restrict__ W2,
    const float* __restrict__ W3,
    ushort* __restrict__ W1b, ushort* __restrict__ W2b, ushort* __restrict__ W3b,
    const float* __restrict__ b3, const float* __restrict__ Wf,
    float* __restrict__ bw)
{
    int i = blockIdx.x * blockDim.x + threadIdx.x;
    if (blockIdx.x == 0 && threadIdx.x < NHEAD) {
        float s = 0.f;
        for (int c = 0; c < CH; c++)
            s += b3[threadIdx.x * CH + c] * Wf[threadIdx.x * CH + c];
        bw[threadIdx.x] = s;
    }
    const float* src; ushort* dst; int k;
    if (i < W1_N4) { src = W1; dst = W1b; k = i; }
    else if (i < W1_N4 + W23_N4) { src = W2; dst = W2b; k = i - W1_N4; }
    else if (i < W1_N4 + 2 * W23_N4) { src = W3; dst = W3b; k = i - W1_N4 - W23_N4; }
    else return;
    float4 v = *(const float4*)(src + (size_t)k * 4);
    ushort4 o;
    o.x = f2bf(v.x); o.y = f2bf(v.y); o.z = f2bf(v.z); o.w = f2bf(v.w);
    *(ushort4*)(dst + (size_t)k * 4) = o;
}

// ------- MFMA GEMM 128x128 tile + fused attention-coefficient epilogue -------
__global__ __launch_bounds__(256) void mfma_gemm_kernel(
    const ushort* __restrict__ Xb, const float* __restrict__ Xf,
    const ushort* __restrict__ Wb,
    ushort* __restrict__ Hb, int M, int F,
    const float* __restrict__ att_s, const float* __restrict__ att_d,
    const float* __restrict__ wf,
    float* __restrict__ as_out, float* __restrict__ ad_out,
    float2* __restrict__ q_out)
{
    __shared__ ushort As[128][40];
    __shared__ ushort Bs[128][40];
    const int tid  = threadIdx.x;
    const int lane = tid & 63;
    const int wave = tid >> 6;
    const int wr = (wave >> 1) * 64;
    const int wc = (wave & 1) * 64;
    const int bm = blockIdx.x * 128;
    const int bn = blockIdx.y * 128;
    const int lrow = tid >> 2;
    const int lseg = (tid & 3) * 8;
    const int fr = lane & 15;
    const int fk = (lane >> 4) * 8;

    f32x4 zero = {0.f, 0.f, 0.f, 0.f};
    f32x4 acc[4][4];
    #pragma unroll
    for (int i = 0; i < 4; i++)
        #pragma unroll
        for (int j = 0; j < 4; j++) acc[i][j] = zero;

    for (int k0 = 0; k0 < F; k0 += 32) {
        #pragma unroll
        for (int rr = 0; rr < 2; rr++) {
            int row = lrow + rr * 64;
            int arow = bm + row;
            bf16x8 av = {};
            if (Xf) {
                if (arow < M) {
                    float4 lo = *(const float4*)(Xf + (size_t)arow * F + k0 + lseg);
                    float4 hi = *(const float4*)(Xf + (size_t)arow * F + k0 + lseg + 4);
                    ushort t[8] = { f2bf(lo.x), f2bf(lo.y), f2bf(lo.z), f2bf(lo.w),
                                    f2bf(hi.x), f2bf(hi.y), f2bf(hi.z), f2bf(hi.w) };
                    av = *(const bf16x8*)t;
                }
            } else {
                if (arow < M) av = *(const bf16x8*)(Xb + (size_t)arow * F + k0 + lseg);
            }
            *(bf16x8*)(&As[row][lseg]) = av;
            bf16x8 bv = *(const bf16x8*)(Wb + (size_t)(bn + row) * F + k0 + lseg);
            *(bf16x8*)(&Bs[row][lseg]) = bv;
        }
        __syncthreads();
        bf16x8 a[4], b[4];
        #pragma unroll
        for (int i = 0; i < 4; i++) {
            a[i] = *(const bf16x8*)(&As[wr + i * 16 + fr][fk]);
            b[i] = *(const bf16x8*)(&Bs[wc + i * 16 + fr][fk]);
        }
        #pragma unroll
        for (int i = 0; i < 4; i++)
            #pragma unroll
            for (int j = 0; j < 4; j++)
                acc[i][j] = __builtin_amdgcn_mfma_f32_16x16x32_bf16(
                    a[i], b[j], acc[i][j], 0, 0, 0);
        __syncthreads();
    }

    const int rb = (lane >> 4) * 4;
    const int h0 = (bn >> 5) + (wc >> 5);

    const float wsa0 = att_s[h0 * CH + fr],        wsa1 = att_s[h0 * CH + 16 + fr];
    const float wda0 = att_d[h0 * CH + fr],        wda1 = att_d[h0 * CH + 16 + fr];
    const float wsb0 = att_s[(h0 + 1) * CH + fr],  wsb1 = att_s[(h0 + 1) * CH + 16 + fr];
    const float wdb0 = att_d[(h0 + 1) * CH + fr],  wdb1 = att_d[(h0 + 1) * CH + 16 + fr];
    float wfa0 = 0.f, wfa1 = 0.f, wfb0 = 0.f, wfb1 = 0.f;
    if (wf) {
        wfa0 = wf[h0 * CH + fr];       wfa1 = wf[h0 * CH + 16 + fr];
        wfb0 = wf[(h0 + 1) * CH + fr]; wfb1 = wf[(h0 + 1) * CH + 16 + fr];
    }

    #pragma unroll
    for (int i = 0; i < 4; i++) {
        #pragma unroll
        for (int r = 0; r < 4; r++) {
            int m = bm + wr + i * 16 + rb + r;
            if (Hb && m < M) {
                #pragma unroll
                for (int j = 0; j < 4; j++)
                    Hb[(size_t)m * HC + bn + wc + j * 16 + fr] = f2bf(acc[i][j][r]);
            }
            float psa = acc[i][0][r] * wsa0 + acc[i][1][r] * wsa1;
            float pda = acc[i][0][r] * wda0 + acc[i][1][r] * wda1;
            float psb = acc[i][2][r] * wsb0 + acc[i][3][r] * wsb1;
            float pdb = acc[i][2][r] * wdb0 + acc[i][3][r] * wdb1;
            float pwa = 0.f, pwb = 0.f;
            if (wf) {
                pwa = acc[i][0][r] * wfa0 + acc[i][1][r] * wfa1;
                pwb = acc[i][2][r] * wfb0 + acc[i][3][r] * wfb1;
            }
            #pragma unroll
            for (int off = 1; off < 16; off <<= 1) {
                psa += __shfl_xor(psa, off);
                pda += __shfl_xor(pda, off);
                psb += __shfl_xor(psb, off);
                pdb += __shfl_xor(pdb, off);
                if (wf) { pwa += __shfl_xor(pwa, off); pwb += __shfl_xor(pwb, off); }
            }
            if (fr == 0 && m < M) {
                if (q_out) {
                    q_out[m * NHEAD + h0]     = make_float2(psa, pwa);
                    q_out[m * NHEAD + h0 + 1] = make_float2(psb, pwb);
                } else {
                    as_out[m * NHEAD + h0]     = psa;
                    as_out[m * NHEAD + h0 + 1] = psb;
                }
                ad_out[m * NHEAD + h0]     = pda;
                ad_out[m * NHEAD + h0 + 1] = pdb;
            }
        }
    }
}

// ---------------- CSR build ----------------
__global__ __launch_bounds__(256) void hist_kernel(
    const int* __restrict__ ei, int* __restrict__ deg)
{
    int eid = blockIdx.x * blockDim.x + threadIdx.x;
    if (eid >= E_EXT) return;
    int d = (eid < E_EDGES) ? ei[E_EDGES + eid] : (eid - E_EDGES);
    atomicAdd(&deg[d], 1);
}

__global__ void scan1_kernel(const int* __restrict__ deg,
                             int* __restrict__ row_ptr, int* __restrict__ csum)
{
    __shared__ int buf[SCAN_CHUNK];
    int t = threadIdx.x;
    int base = blockIdx.x * SCAN_CHUNK;
    int v = (base + t < N_NODES) ? deg[base + t] : 0;
    buf[t] = v;
    __syncthreads();
    for (int off = 1; off < SCAN_CHUNK; off <<= 1) {
        int x = buf[t];
        int y = (t >= off) ? buf[t - off] : 0;
        __syncthreads();
        buf[t] = x + y;
        __syncthreads();
    }
    if (base + t < N_NODES) row_ptr[base + t] = buf[t] - v;
    if (t == SCAN_CHUNK - 1) csum[blockIdx.x] = buf[t];
}

__global__ void scan2_kernel(int* __restrict__ csum)
{
    __shared__ int buf[64];
    int t = threadIdx.x;
    int v = (t < N_CHUNKS) ? csum[t] : 0;
    buf[t] = v;
    __syncthreads();
    for (int off = 1; off < 64; off <<= 1) {
        int x = buf[t];
        int y = (t >= off) ? buf[t - off] : 0;
        __syncthreads();
        buf[t] = x + y;
        __syncthreads();
    }
    if (t < N_CHUNKS) csum[t] = buf[t] - v;
}

__global__ void scan3_kernel(int* __restrict__ row_ptr, const int* __restrict__ csum)
{
    int i = blockIdx.x * blockDim.x + threadIdx.x;
    if (i < N_NODES) row_ptr[i] += csum[i / SCAN_CHUNK];
    if (i == 0) row_ptr[N_NODES] = E_EXT;
}

__global__ __launch_bounds__(256) void scatter_kernel(
    const int* __restrict__ ei, const int* __restrict__ row_ptr,
    int* __restrict__ cur, int* __restrict__ esrc)
{
    int eid = blockIdx.x * blockDim.x + threadIdx.x;
    if (eid >= E_EXT) return;
    int s, d;
    if (eid < E_EDGES) { s = ei[eid]; d = ei[E_EDGES + eid]; }
    else { s = eid - E_EDGES; d = s; }
    int pos = row_ptr[d] + atomicAdd(&cur[d], 1);
    esrc[pos] = s;
}

// ------- heavy gather: 2 dst/wave, 8 ch/lane, 8-deep load pipeline ----------
__global__ __launch_bounds__(256) void gather_kernel(
    const int* __restrict__ row_ptr, const int* __restrict__ esrc,
    const ushort* __restrict__ hb,
    const float* __restrict__ a_s, const float* __restrict__ a_d,
    const float* __restrict__ bias,
    ushort* __restrict__ out_b)
{
    int wv = (blockIdx.x * blockDim.x + threadIdx.x) >> 6;
    int lane = threadIdx.x & 63;
    int half = lane >> 5;
    int lloc = lane & 31;
    int n = wv * 2 + half;
    if (n >= N_NODES) return;
    const int hh = lloc >> 2;
    const int shbase = half << 5;
    const float adv = a_d[n * NHEAD + hh];
    const int beg = row_ptr[n], end = row_ptr[n + 1];

    float a0=0.f,a1=0.f,a2=0.f,a3=0.f,a4=0.f,a5=0.f,a6=0.f,a7=0.f,den=0.f;

    for (int base = beg; base < end; base += 32) {
        int cnt = min(32, end - base);
        int sv = (base + lloc < end) ? esrc[base + lloc] : 0;
        int j = 0;
        for (; j + 8 <= cnt; j += 8) {
            // 8 independent edges: all loads issued before dependent math
            int s0 = __shfl(sv, shbase + j + 0), s1 = __shfl(sv, shbase + j + 1);
            int s2 = __shfl(sv, shbase + j + 2), s3 = __shfl(sv, shbase + j + 3);
            int s4 = __shfl(sv, shbase + j + 4), s5 = __shfl(sv, shbase + j + 5);
            int s6 = __shfl(sv, shbase + j + 6), s7 = __shfl(sv, shbase + j + 7);
            float e0 = a_s[s0 * NHEAD + hh], e1 = a_s[s1 * NHEAD + hh];
            float e2 = a_s[s2 * NHEAD + hh], e3 = a_s[s3 * NHEAD + hh];
            float e4 = a_s[s4 * NHEAD + hh], e5 = a_s[s5 * NHEAD + hh];
            float e6 = a_s[s6 * NHEAD + hh], e7 = a_s[s7 * NHEAD + hh];
            uint4 u0 = *(const uint4*)(hb + (size_t)s0 * HC + lloc * 8);
            uint4 u1 = *(const uint4*)(hb + (size_t)s1 * HC + lloc * 8);
            uint4 u2 = *(const uint4*)(hb + (size_t)s2 * HC + lloc * 8);
            uint4 u3 = *(const uint4*)(hb + (size_t)s3 * HC + lloc * 8);
            uint4 u4 = *(const uint4*)(hb + (size_t)s4 * HC + lloc * 8);
            uint4 u5 = *(const uint4*)(hb + (size_t)s5 * HC + lloc * 8);
            uint4 u6 = *(const uint4*)(hb + (size_t)s6 * HC + lloc * 8);
            uint4 u7 = *(const uint4*)(hb + (size_t)s7 * HC + lloc * 8);
            e0 += adv; e0 = (e0 > 0.f) ? e0 : 0.2f * e0; float w0 = __expf(e0);
            e1 += adv; e1 = (e1 > 0.f) ? e1 : 0.2f * e1; float w1 = __expf(e1);
            e2 += adv; e2 = (e2 > 0.f) ? e2 : 0.2f * e2; float w2 = __expf(e2);
            e3 += adv; e3 = (e3 > 0.f) ? e3 : 0.2f * e3; float w3 = __expf(e3);
            e4 += adv; e4 = (e4 > 0.f) ? e4 : 0.2f * e4; float w4 = __expf(e4);
            e5 += adv; e5 = (e5 > 0.f) ? e5 : 0.2f * e5; float w5 = __expf(e5);
            e6 += adv; e6 = (e6 > 0.f) ? e6 : 0.2f * e6; float w6 = __expf(e6);
            e7 += adv; e7 = (e7 > 0.f) ? e7 : 0.2f * e7; float w7 = __expf(e7);
            den += ((w0 + w1) + (w2 + w3)) + ((w4 + w5) + (w6 + w7));
            a0 = fmaf(w0, bflo(u0.x), a0); a1 = fmaf(w0, bfhi(u0.x), a1);
            a2 = fmaf(w0, bflo(u0.y), a2); a3 = fmaf(w0, bfhi(u0.y), a3);
            a4 = fmaf(w0, bflo(u0.z), a4); a5 = fmaf(w0, bfhi(u0.z), a5);
            a6 = fmaf(w0, bflo(u0.w), a6); a7 = fmaf(w0, bfhi(u0.w), a7);
            a0 = fmaf(w1, bflo(u1.x), a0); a1 = fmaf(w1, bfhi(u1.x), a1);
            a2 = fmaf(w1, bflo(u1.y), a2); a3 = fmaf(w1, bfhi(u1.y), a3);
            a4 = fmaf(w1, bflo(u1.z), a4); a5 = fmaf(w1, bfhi(u1.z), a5);
            a6 = fmaf(w1, bflo(u1.w), a6); a7 = fmaf(w1, bfhi(u1.w), a7);
            a0 = fmaf(w2, bflo(u2.x), a0); a1 = fmaf(w2, bfhi(u2.x), a1);
            a2 = fmaf(w2, bflo(u2.y), a2); a3 = fmaf(w2, bfhi(u2.y), a3);
            a4 = fmaf(w2, bflo(u2.z), a4); a5 = fmaf(w2, bfhi(u2.z), a5);
            a6 = fmaf(w2, bflo(u2.w), a6); a7 = fmaf(w2, bfhi(u2.w), a7);
            a0 = fmaf(w3, bflo(u3.x), a0); a1 = fmaf(w3, bfhi(u3.x), a1);
            a2 = fmaf(w3, bflo(u3.y), a2); a3 = fmaf(w3, bfhi(u3.y), a3);
            a4 = fmaf(w3, bflo(u3.z), a4); a5 = fmaf(w3, bfhi(u3.z), a5);
            a6 = fmaf(w3, bflo(u3.w), a6); a7 = fmaf(w3, bfhi(u3.w), a7);
            a0 = fmaf(w4, bflo(u4.x), a0); a1 = fmaf(w4, bfhi(u4.x), a1);
            a2 = fmaf(w4, bflo(u4.y), a2); a3 = fmaf(w4, bfhi(u4.y), a3);
            a4 = fmaf(w4, bflo(u4.z), a4); a5 = fmaf(w4, bfhi(u4.z), a5);
            a6 = fmaf(w4, bflo(u4.w), a6); a7 = fmaf(w4, bfhi(u4.w), a7);
            a0 = fmaf(w5, bflo(u5.x), a0); a1 = fmaf(w5, bfhi(u5.x), a1);
            a2 = fmaf(w5, bflo(u5.y), a2); a3 = fmaf(w5, bfhi(u5.y), a3);
            a4 = fmaf(w5, bflo(u5.z), a4); a5 = fmaf(w5, bfhi(u5.z), a5);
            a6 = fmaf(w5, bflo(u5.w), a6); a7 = fmaf(w5, bfhi(u5.w), a7);
            a0 = fmaf(w6, bflo(u6.x), a0); a1 = fmaf(w6, bfhi(u6.x), a1);
            a2 = fmaf(w6, bflo(u6.y), a2); a3 = fmaf(w6, bfhi(u6.y), a3);
            a4 = fmaf(w6, bflo(u6.z), a4); a5 = fmaf(w6, bfhi(u6.z), a5);
            a6 = fmaf(w6, bflo(u6.w), a6); a7 = fmaf(w6, bfhi(u6.w), a7);
            a0 = fmaf(w7, bflo(u7.x), a0); a1 = fmaf(w7, bfhi(u7.x), a1);
            a2 = fmaf(w7, bflo(u7.y), a2); a3 = fmaf(w7, bfhi(u7.y), a3);
            a4 = fmaf(w7, bflo(u7.z), a4); a5 = fmaf(w7, bfhi(u7.z), a5);
            a6 = fmaf(w7, bflo(u7.w), a6); a7 = fmaf(w7, bfhi(u7.w), a7);
        }
        for (; j + 4 <= cnt; j += 4) {
            int s0 = __shfl(sv, shbase + j), s1 = __shfl(sv, shbase + j + 1);
            int s2 = __shfl(sv, shbase + j + 2), s3 = __shfl(sv, shbase + j + 3);
            float e0 = a_s[s0 * NHEAD + hh], e1 = a_s[s1 * NHEAD + hh];
            float e2 = a_s[s2 * NHEAD + hh], e3 = a_s[s3 * NHEAD + hh];
            uint4 u0 = *(const uint4*)(hb + (size_t)s0 * HC + lloc * 8);
            uint4 u1 = *(const uint4*)(hb + (size_t)s1 * HC + lloc * 8);
            uint4 u2 = *(const uint4*)(hb + (size_t)s2 * HC + lloc * 8);
            uint4 u3 = *(const uint4*)(hb + (size_t)s3 * HC + lloc * 8);
            e0 += adv; e0 = (e0 > 0.f) ? e0 : 0.2f * e0; float w0 = __expf(e0);
            e1 += adv; e1 = (e1 > 0.f) ? e1 : 0.2f * e1; float w1 = __expf(e1);
            e2 += adv; e2 = (e2 > 0.f) ? e2 : 0.2f * e2; float w2 = __expf(e2);
            e3 += adv; e3 = (e3 > 0.f) ? e3 : 0.2f * e3; float w3 = __expf(e3);
            den += (w0 + w1) + (w2 + w3);
            a0 = fmaf(w0, bflo(u0.x), a0); a1 = fmaf(w0, bfhi(u0.x), a1);
            a2 = fmaf(w0, bflo(u0.y), a2); a3 = fmaf(w0, bfhi(u0.y), a3);
            a4 = fmaf(w0, bflo(u0.z), a4); a5 = fmaf(w0, bfhi(u0.z), a5);
            a6 = fmaf(w0, bflo(u0.w), a6); a7 = fmaf(w0, bfhi(u0.w), a7);
            a0 = fmaf(w1, bflo(u1.x), a0); a1 = fmaf(w1, bfhi(u1.x), a1);
            a2 = fmaf(w1, bflo(u1.y), a2); a3 = fmaf(w1, bfhi(u1.y), a3);
            a4 = fmaf(w1, bflo(u1.z), a4); a5 = fmaf(w1, bfhi(u1.z), a5);
            a6 = fmaf(w1, bflo(u1.w), a6); a7 = fmaf(w1, bfhi(u1.w), a7);
            a0 = fmaf(w2, bflo(u2.x), a0); a1 = fmaf(w2, bfhi(u2.x), a1);
            a2 = fmaf(w2, bflo(u2.y), a2); a3 = fmaf(w2, bfhi(u2.y), a3);
            a4 = fmaf(w2, bflo(u2.z), a4); a5 = fmaf(w2, bfhi(u2.z), a5);
            a6 = fmaf(w2, bflo(u2.w), a6); a7 = fmaf(w2, bfhi(u2.w), a7);
            a0 = fmaf(w3, bflo(u3.x), a0); a1 = fmaf(w3, bfhi(u3.x), a1);
            a2 = fmaf(w3, bflo(u3.y), a2); a3 = fmaf(w3, bfhi(u3.y), a3);
            a4 = fmaf(w3, bflo(u3.z), a4); a5 = fmaf(w3, bfhi(u3.z), a5);
            a6 = fmaf(w3, bflo(u3.w), a6); a7 = fmaf(w3, bfhi(u3.w), a7);
        }
        for (; j < cnt; j++) {
            int s = __shfl(sv, shbase + j);
            float e = a_s[s * NHEAD + hh] + adv;
            e = (e > 0.f) ? e : 0.2f * e;
            float w = __expf(e);
            den += w;
            uint4 u = *(const uint4*)(hb + (size_t)s * HC + lloc * 8);
            a0 = fmaf(w, bflo(u.x), a0); a1 = fmaf(w, bfhi(u.x), a1);
            a2 = fmaf(w, bflo(u.y), a2); a3 = fmaf(w, bfhi(u.y), a3);
            a4 = fmaf(w, bflo(u.z), a4); a5 = fmaf(w, bfhi(u.z), a5);
            a6 = fmaf(w, bflo(u.w), a6); a7 = fmaf(w, bfhi(u.w), a7);
        }
    }
    float inv = 1.f / den;
    float4 ba = *(const float4*)(bias + lloc * 8);
    float4 bb = *(const float4*)(bias + lloc * 8 + 4);
    float o0 = fmaf(a0, inv, ba.x), o1 = fmaf(a1, inv, ba.y);
    float o2 = fmaf(a2, inv, ba.z), o3 = fmaf(a3, inv, ba.w);
    float o4 = fmaf(a4, inv, bb.x), o5 = fmaf(a5, inv, bb.y);
    float o6 = fmaf(a6, inv, bb.z), o7 = fmaf(a7, inv, bb.w);
    o0 = fmaxf(o0, 0.f); o1 = fmaxf(o1, 0.f); o2 = fmaxf(o2, 0.f); o3 = fmaxf(o3, 0.f);
    o4 = fmaxf(o4, 0.f); o5 = fmaxf(o5, 0.f); o6 = fmaxf(o6, 0.f); o7 = fmaxf(o7, 0.f);
    uint4 ob;
    ob.x = (unsigned)f2bf(o0) | ((unsigned)f2bf(o1) << 16);
    ob.y = (unsigned)f2bf(o2) | ((unsigned)f2bf(o3) << 16);
    ob.z = (unsigned)f2bf(o4) | ((unsigned)f2bf(o5) << 16);
    ob.w = (unsigned)f2bf(o6) | ((unsigned)f2bf(o7) << 16);
    *(uint4*)(out_b + (size_t)n * HC + lloc * 8) = ob;
}

// ------- light gather (layer 3): thread per (dst,head), 8B per edge ---------
__global__ __launch_bounds__(256) void light_gather_kernel(
    const int* __restrict__ row_ptr, const int* __restrict__ esrc,
    const float2* __restrict__ q, const float* __restrict__ a_d,
    const float* __restrict__ bw, float* __restrict__ ndot)
{
    int idx = blockIdx.x * blockDim.x + threadIdx.x;
    if (idx >= N_NODES * NHEAD) return;
    int n = idx >> 3, hh = idx & 7;
    const float adv = a_d[idx];
    const int beg = row_ptr[n], end = row_ptr[n + 1];
    float acc = 0.f, den = 0.f;
    int e = beg;
    for (; e + 4 <= end; e += 4) {
        int s0 = esrc[e], s1 = esrc[e + 1], s2 = esrc[e + 2], s3 = esrc[e + 3];
        float2 q0 = q[s0 * NHEAD + hh];
        float2 q1 = q[s1 * NHEAD + hh];
        float2 q2 = q[s2 * NHEAD + hh];
        float2 q3 = q[s3 * NHEAD + hh];
        float t0 = q0.x + adv; t0 = (t0 > 0.f) ? t0 : 0.2f * t0; float w0 = __expf(t0);
        float t1 = q1.x + adv; t1 = (t1 > 0.f) ? t1 : 0.2f * t1; float w1 = __expf(t1);
        float t2 = q2.x + adv; t2 = (t2 > 0.f) ? t2 : 0.2f * t2; float w2 = __expf(t2);
        float t3 = q3.x + adv; t3 = (t3 > 0.f) ? t3 : 0.2f * t3; float w3 = __expf(t3);
        den += (w0 + w1) + (w2 + w3);
        acc = fmaf(w0, q0.y, acc); acc = fmaf(w1, q1.y, acc);
        acc = fmaf(w2, q2.y, acc); acc = fmaf(w3, q3.y, acc);
    }
    for (; e < end; e++) {
        int s = esrc[e];
        float2 qv = q[s * NHEAD + hh];
        float t = qv.x + adv; t = (t > 0.f) ? t : 0.2f * t;
        float w = __expf(t);
        den += w;
        acc = fmaf(w, qv.y, acc);
    }
    float p = acc / den + bw[hh];
    #pragma unroll
    for (int off = 4; off > 0; off >>= 1) p += __shfl_xor(p, off);
    if (hh == 0) ndot[n] = p;
}

// ------- per-graph mean over sorted batch (binary search, no atomics) -------
__global__ __launch_bounds__(256) void pool2_kernel(
    const float* __restrict__ ndot, const int* __restrict__ batch,
    const float* __restrict__ bf, float* __restrict__ outp)
{
    __shared__ float red[256];
    int g = blockIdx.x, t = threadIdx.x;
    int lo = 0, hi = N_NODES;
    while (lo < hi) { int mid = (lo + hi) >> 1; if (batch[mid] < g) lo = mid + 1; else hi = mid; }
    int start = lo;
    lo = 0; hi = N_NODES;
    while (lo < hi) { int mid = (lo + hi) >> 1; if (batch[mid] < g + 1) lo = mid + 1; else hi = mid; }
    int end = lo;
    float s = 0.f;
    for (int i = start + t; i < end; i += 256) s += ndot[i];
    red[t] = s;
    __syncthreads();
    for (int k = 128; k > 0; k >>= 1) {
        if (t < k) red[t] += red[t + k];
        __syncthreads();
    }
    if (t == 0) outp[g] = red[0] / fmaxf((float)(end - start), 1.f) + bf[0];
}

extern "C" void kernel_launch(void* const* d_in, const int* in_sizes, int n_in,
                              void* d_out, int out_size, void* d_ws, size_t ws_size,
                              hipStream_t stream)
{
    const float* x    = (const float*)d_in[0];
    const int*   ei   = (const int*)d_in[1];
    const int*   batch= (const int*)d_in[2];
    const float* W1   = (const float*)d_in[3];
    const float* as1  = (const float*)d_in[4];
    const float* ad1  = (const float*)d_in[5];
    const float* b1   = (const float*)d_in[6];
    const float* W2   = (const float*)d_in[7];
    const float* as2  = (const float*)d_in[8];
    const float* ad2  = (const float*)d_in[9];
    const float* b2   = (const float*)d_in[10];
    const float* W3   = (const float*)d_in[11];
    const float* as3  = (const float*)d_in[12];
    const float* ad3  = (const float*)d_in[13];
    const float* b3   = (const float*)d_in[14];
    const float* Wf   = (const float*)d_in[15];
    const float* bf   = (const float*)d_in[16];
    float* out = (float*)d_out;

    char* ws = (char*)d_ws;
    size_t off = 0;
    auto allocb = [&](size_t bytes) {
        void* p = ws + off;
        off += (bytes + 255) & ~(size_t)255;
        return p;
    };
    ushort* bufA    = (ushort*)allocb((size_t)N_NODES * HC * 2);
    ushort* bufB    = (ushort*)allocb((size_t)N_NODES * HC * 2);
    ushort* W1b     = (ushort*)allocb((size_t)HC * IN_CH * 2);
    ushort* W2b     = (ushort*)allocb((size_t)HC * HC * 2);
    ushort* W3b     = (ushort*)allocb((size_t)HC * HC * 2);
    float*  as_buf  = (float*) allocb((size_t)N_NODES * NHEAD * 4);
    float*  ad_buf  = (float*) allocb((size_t)N_NODES * NHEAD * 4);
    float2* q_buf   = (float2*)allocb((size_t)N_NODES * NHEAD * 8);
    float*  bw_buf  = (float*) allocb(NHEAD * 4);
    int*    deg     = (int*)   allocb(N_NODES * 4);      // deg+cur adjacent: one memset
    int*    cur     = (int*)   allocb(N_NODES * 4);
    int*    row_ptr = (int*)   allocb((N_NODES + 1) * 4);
    int*    csum    = (int*)   allocb(64 * 4);
    int*    esrc    = (int*)   allocb(E_EXT * 4);
    float*  ndot    = (float*) allocb(N_NODES * 4);
    (void)ws_size; (void)in_sizes; (void)n_in; (void)out_size;

    // ---- weight bf16 conversion (+bw fused) ----
    cvt_weights_kernel<<<(W1_N4 + 2 * W23_N4 + 255) / 256, 256, 0, stream>>>(
        W1, W2, W3, W1b, W2b, W3b, b3, Wf, bw_buf);

    // ---- CSR build ----
    const size_t deg_pad = ((size_t)N_NODES * 4 + 255) & ~(size_t)255;
    hipMemsetAsync(deg, 0, deg_pad + (size_t)N_NODES * 4, stream);  // deg + cur
    hist_kernel<<<(E_EXT + 255) / 256, 256, 0, stream>>>(ei, deg);
    scan1_kernel<<<N_CHUNKS, SCAN_CHUNK, 0, stream>>>(deg, row_ptr, csum);
    scan2_kernel<<<1, 64, 0, stream>>>(csum);
    scan3_kernel<<<(N_NODES + 255) / 256, 256, 0, stream>>>(row_ptr, csum);
    scatter_kernel<<<(E_EXT + 255) / 256, 256, 0, stream>>>(ei, row_ptr, cur, esrc);

    dim3 ggrid((N_NODES + 127) / 128, HC / 128);
    const int gather_blocks = (((N_NODES + 1) / 2) * 64 + 255) / 256;

    // layer 1: x(f32) -> B(h1 + a_s/a_d) -> A(h1')
    mfma_gemm_kernel<<<ggrid, 256, 0, stream>>>(
        nullptr, x, W1b, bufB, N_NODES, IN_CH, as1, ad1, nullptr,
        as_buf, ad_buf, nullptr);
    gather_kernel<<<gather_blocks, 256, 0, stream>>>(
        row_ptr, esrc, bufB, as_buf, ad_buf, b1, bufA);
    // layer 2: A -> B(h2 + a_s/a_d) -> A
    mfma_gemm_kernel<<<ggrid, 256, 0, stream>>>(
        bufA, nullptr, W2b, bufB, N_NODES, HC, as2, ad2, nullptr,
        as_buf, ad_buf, nullptr);
    gather_kernel<<<gather_blocks, 256, 0, stream>>>(
        row_ptr, esrc, bufB, as_buf, ad_buf, b2, bufA);
    // layer 3: A -> q/a_d only (no Hb store) -> ndot (light gather)
    mfma_gemm_kernel<<<ggrid, 256, 0, stream>>>(
        bufA, nullptr, W3b, nullptr, N_NODES, HC, as3, ad3, Wf,
        nullptr, ad_buf, q_buf);
    light_gather_kernel<<<(N_NODES * NHEAD + 255) / 256, 256, 0, stream>>>(
        row_ptr, esrc, q_buf, ad_buf, bw_buf, ndot);

    pool2_kernel<<<NGRAPH, 256, 0, stream>>>(ndot, batch, bf, out);
}

// Round 10
// 319.077 us; speedup vs baseline: 29.4573x; 1.0933x over previous
//
#include <hip/hip_runtime.h>

#define N_NODES 50000
#define E_EDGES 800000
#define E_EXT   850000   // + self loops
#define IN_CH   128
#define HC      256
#define NHEAD   8
#define CH      32
#define NGRAPH  256
#define SCAN_CHUNK 1024
#define N_CHUNKS ((N_NODES + SCAN_CHUNK - 1) / SCAN_CHUNK)

typedef __bf16 bf16x8 __attribute__((ext_vector_type(8)));
typedef float  f32x4  __attribute__((ext_vector_type(4)));

__device__ inline ushort f2bf(float f) {
    union { float f; unsigned u; } v; v.f = f;
    unsigned u = v.u;
    unsigned r = u + 0x7FFFu + ((u >> 16) & 1u);
    return (ushort)(r >> 16);
}
__device__ inline float bflo(unsigned u) {
    union { unsigned u; float f; } v; v.u = u << 16; return v.f;
}
__device__ inline float bfhi(unsigned u) {
    union { unsigned u; float f; } v; v.u = u & 0xFFFF0000u; return v.f;
}

// ------- merged prep: W1/W2/W3 -> bf16, bw[h], composite Vb[32][HC] ----------
// Vb rows 0..7  = vs3[h][k] = sum_c as3[h,c] * W3[h*32+c][k]
// Vb rows 8..15 = vw3[h][k] = sum_c Wf [h*32+c] * W3[h*32+c][k]
// Vb rows 16..23= vd3[h][k] = sum_c ad3[h,c] * W3[h*32+c][k];  rows 24..31 = 0
#define W1_N4 (HC * IN_CH / 4)
#define W23_N4 (HC * HC / 4)
#define CVT_N4 (W1_N4 + 2 * W23_N4)
#define COMP_N (32 * HC)
__global__ __launch_bounds__(256) void cvt_weights_kernel(
    const float* __restrict__ W1, const float* __restrict__ W2,
    const float* __restrict__ W3,
    ushort* __restrict__ W1b, ushort* __restrict__ W2b, ushort* __restrict__ W3b,
    const float* __restrict__ as3, const float* __restrict__ ad3,
    const float* __restrict__ b3, const float* __restrict__ Wf,
    float* __restrict__ bw, ushort* __restrict__ Vb)
{
    int i = blockIdx.x * blockDim.x + threadIdx.x;
    if (blockIdx.x == 0 && threadIdx.x < NHEAD) {
        float s = 0.f;
        for (int c = 0; c < CH; c++)
            s += b3[threadIdx.x * CH + c] * Wf[threadIdx.x * CH + c];
        bw[threadIdx.x] = s;
    }
    if (i < CVT_N4) {
        const float* src; ushort* dst; int k;
        if (i < W1_N4) { src = W1; dst = W1b; k = i; }
        else if (i < W1_N4 + W23_N4) { src = W2; dst = W2b; k = i - W1_N4; }
        else { src = W3; dst = W3b; k = i - W1_N4 - W23_N4; }
        float4 v = *(const float4*)(src + (size_t)k * 4);
        ushort4 o;
        o.x = f2bf(v.x); o.y = f2bf(v.y); o.z = f2bf(v.z); o.w = f2bf(v.w);
        *(ushort4*)(dst + (size_t)k * 4) = o;
        return;
    }
    int c2 = i - CVT_N4;
    if (c2 >= COMP_N) return;
    int j = c2 >> 8, k = c2 & 255;
    float v = 0.f;
    if (j < 24) {
        int h = j & 7;
        const float* aw = (j < 8) ? as3 : (j < 16 ? Wf : ad3);
        // Wf is flat [HC]; as3/ad3 are [H][CH] — both index as aw[h*CH+c]
        for (int c = 0; c < CH; c++)
            v += aw[h * CH + c] * W3[(size_t)(h * CH + c) * HC + k];
    }
    Vb[j * HC + k] = f2bf(v);
}

// ------- MFMA GEMM 128x128 tile + fused a_s/a_d epilogue (layers 1-2) -------
__global__ __launch_bounds__(256) void mfma_gemm_kernel(
    const ushort* __restrict__ Xb, const float* __restrict__ Xf,
    const ushort* __restrict__ Wb,
    ushort* __restrict__ Hb, int M, int F,
    const float* __restrict__ att_s, const float* __restrict__ att_d,
    float* __restrict__ as_out, float* __restrict__ ad_out)
{
    __shared__ ushort As[128][40];
    __shared__ ushort Bs[128][40];
    const int tid  = threadIdx.x;
    const int lane = tid & 63;
    const int wave = tid >> 6;
    const int wr = (wave >> 1) * 64;
    const int wc = (wave & 1) * 64;
    const int bm = blockIdx.x * 128;
    const int bn = blockIdx.y * 128;
    const int lrow = tid >> 2;
    const int lseg = (tid & 3) * 8;
    const int fr = lane & 15;
    const int fk = (lane >> 4) * 8;

    f32x4 zero = {0.f, 0.f, 0.f, 0.f};
    f32x4 acc[4][4];
    #pragma unroll
    for (int i = 0; i < 4; i++)
        #pragma unroll
        for (int j = 0; j < 4; j++) acc[i][j] = zero;

    for (int k0 = 0; k0 < F; k0 += 32) {
        #pragma unroll
        for (int rr = 0; rr < 2; rr++) {
            int row = lrow + rr * 64;
            int arow = bm + row;
            bf16x8 av = {};
            if (Xf) {
                if (arow < M) {
                    float4 lo = *(const float4*)(Xf + (size_t)arow * F + k0 + lseg);
                    float4 hi = *(const float4*)(Xf + (size_t)arow * F + k0 + lseg + 4);
                    ushort t[8] = { f2bf(lo.x), f2bf(lo.y), f2bf(lo.z), f2bf(lo.w),
                                    f2bf(hi.x), f2bf(hi.y), f2bf(hi.z), f2bf(hi.w) };
                    av = *(const bf16x8*)t;
                }
            } else {
                if (arow < M) av = *(const bf16x8*)(Xb + (size_t)arow * F + k0 + lseg);
            }
            *(bf16x8*)(&As[row][lseg]) = av;
            bf16x8 bv = *(const bf16x8*)(Wb + (size_t)(bn + row) * F + k0 + lseg);
            *(bf16x8*)(&Bs[row][lseg]) = bv;
        }
        __syncthreads();
        bf16x8 a[4], b[4];
        #pragma unroll
        for (int i = 0; i < 4; i++) {
            a[i] = *(const bf16x8*)(&As[wr + i * 16 + fr][fk]);
            b[i] = *(const bf16x8*)(&Bs[wc + i * 16 + fr][fk]);
        }
        #pragma unroll
        for (int i = 0; i < 4; i++)
            #pragma unroll
            for (int j = 0; j < 4; j++)
                acc[i][j] = __builtin_amdgcn_mfma_f32_16x16x32_bf16(
                    a[i], b[j], acc[i][j], 0, 0, 0);
        __syncthreads();
    }

    const int rb = (lane >> 4) * 4;
    const int h0 = (bn >> 5) + (wc >> 5);

    const float wsa0 = att_s[h0 * CH + fr],        wsa1 = att_s[h0 * CH + 16 + fr];
    const float wda0 = att_d[h0 * CH + fr],        wda1 = att_d[h0 * CH + 16 + fr];
    const float wsb0 = att_s[(h0 + 1) * CH + fr],  wsb1 = att_s[(h0 + 1) * CH + 16 + fr];
    const float wdb0 = att_d[(h0 + 1) * CH + fr],  wdb1 = att_d[(h0 + 1) * CH + 16 + fr];

    #pragma unroll
    for (int i = 0; i < 4; i++) {
        #pragma unroll
        for (int r = 0; r < 4; r++) {
            int m = bm + wr + i * 16 + rb + r;
            if (m < M) {
                #pragma unroll
                for (int j = 0; j < 4; j++)
                    Hb[(size_t)m * HC + bn + wc + j * 16 + fr] = f2bf(acc[i][j][r]);
            }
            float psa = acc[i][0][r] * wsa0 + acc[i][1][r] * wsa1;
            float pda = acc[i][0][r] * wda0 + acc[i][1][r] * wda1;
            float psb = acc[i][2][r] * wsb0 + acc[i][3][r] * wsb1;
            float pdb = acc[i][2][r] * wdb0 + acc[i][3][r] * wdb1;
            #pragma unroll
            for (int off = 1; off < 16; off <<= 1) {
                psa += __shfl_xor(psa, off);
                pda += __shfl_xor(pda, off);
                psb += __shfl_xor(psb, off);
                pdb += __shfl_xor(pdb, off);
            }
            if (fr == 0 && m < M) {
                as_out[m * NHEAD + h0]     = psa;
                as_out[m * NHEAD + h0 + 1] = psb;
                ad_out[m * NHEAD + h0]     = pda;
                ad_out[m * NHEAD + h0 + 1] = pdb;
            }
        }
    }
}

// ------- thin MFMA GEMM (layer 3): [M,HC] @ Vb[32][HC]^T -> q/a_d directly ---
// col j<8: q[m][j].x (a_s);  8..15: q[m][j-8].y (hw);  16..23: ad[m][j-16]
__global__ __launch_bounds__(256) void gemm3_kernel(
    const ushort* __restrict__ Xb, const ushort* __restrict__ Vb, int M,
    float2* __restrict__ q_out, float* __restrict__ ad_out)
{
    __shared__ ushort As[128][40];
    __shared__ ushort Bs[32][40];
    const int tid  = threadIdx.x;
    const int lane = tid & 63;
    const int wave = tid >> 6;
    const int bm = blockIdx.x * 128;
    const int lrow = tid >> 2;
    const int lseg = (tid & 3) * 8;
    const int fr = lane & 15;
    const int fk = (lane >> 4) * 8;

    f32x4 zero = {0.f, 0.f, 0.f, 0.f};
    f32x4 acc[2][2];
    #pragma unroll
    for (int i = 0; i < 2; i++)
        #pragma unroll
        for (int j = 0; j < 2; j++) acc[i][j] = zero;

    for (int k0 = 0; k0 < HC; k0 += 32) {
        #pragma unroll
        for (int rr = 0; rr < 2; rr++) {
            int row = lrow + rr * 64;
            int arow = bm + row;
            bf16x8 av = {};
            if (arow < M) av = *(const bf16x8*)(Xb + (size_t)arow * HC + k0 + lseg);
            *(bf16x8*)(&As[row][lseg]) = av;
        }
        if (tid < 128) {
            int brow = tid >> 2;
            bf16x8 bv = *(const bf16x8*)(Vb + (size_t)brow * HC + k0 + lseg);
            *(bf16x8*)(&Bs[brow][lseg]) = bv;
        }
        __syncthreads();
        bf16x8 a[2], b[2];
        #pragma unroll
        for (int i = 0; i < 2; i++) {
            a[i] = *(const bf16x8*)(&As[wave * 32 + i * 16 + fr][fk]);
            b[i] = *(const bf16x8*)(&Bs[i * 16 + fr][fk]);
        }
        #pragma unroll
        for (int i = 0; i < 2; i++)
            #pragma unroll
            for (int j = 0; j < 2; j++)
                acc[i][j] = __builtin_amdgcn_mfma_f32_16x16x32_bf16(
                    a[i], b[j], acc[i][j], 0, 0, 0);
        __syncthreads();
    }

    const int rb = (lane >> 4) * 4;
    #pragma unroll
    for (int i = 0; i < 2; i++) {
        #pragma unroll
        for (int r = 0; r < 4; r++) {
            int m = bm + wave * 32 + i * 16 + rb + r;
            if (m >= M) continue;
            #pragma unroll
            for (int j = 0; j < 2; j++) {
                int jj = j * 16 + fr;
                float v = acc[i][j][r];
                if (jj < 8)       ((float*)q_out)[(size_t)(m * NHEAD + jj) * 2]     = v;
                else if (jj < 16) ((float*)q_out)[(size_t)(m * NHEAD + jj - 8) * 2 + 1] = v;
                else if (jj < 24) ad_out[m * NHEAD + jj - 16] = v;
            }
        }
    }
}

// ---------------- CSR build ----------------
__global__ __launch_bounds__(256) void hist_kernel(
    const int* __restrict__ ei, int* __restrict__ deg)
{
    int eid = blockIdx.x * blockDim.x + threadIdx.x;
    if (eid >= E_EXT) return;
    int d = (eid < E_EDGES) ? ei[E_EDGES + eid] : (eid - E_EDGES);
    atomicAdd(&deg[d], 1);
}

__global__ void scan1_kernel(const int* __restrict__ deg,
                             int* __restrict__ row_ptr, int* __restrict__ csum)
{
    __shared__ int buf[SCAN_CHUNK];
    int t = threadIdx.x;
    int base = blockIdx.x * SCAN_CHUNK;
    int v = (base + t < N_NODES) ? deg[base + t] : 0;
    buf[t] = v;
    __syncthreads();
    for (int off = 1; off < SCAN_CHUNK; off <<= 1) {
        int x = buf[t];
        int y = (t >= off) ? buf[t - off] : 0;
        __syncthreads();
        buf[t] = x + y;
        __syncthreads();
    }
    if (base + t < N_NODES) row_ptr[base + t] = buf[t] - v;
    if (t == SCAN_CHUNK - 1) csum[blockIdx.x] = buf[t];
}

__global__ void scan2_kernel(int* __restrict__ csum)
{
    __shared__ int buf[64];
    int t = threadIdx.x;
    int v = (t < N_CHUNKS) ? csum[t] : 0;
    buf[t] = v;
    __syncthreads();
    for (int off = 1; off < 64; off <<= 1) {
        int x = buf[t];
        int y = (t >= off) ? buf[t - off] : 0;
        __syncthreads();
        buf[t] = x + y;
        __syncthreads();
    }
    if (t < N_CHUNKS) csum[t] = buf[t] - v;
}

__global__ void scan3_kernel(int* __restrict__ row_ptr, const int* __restrict__ csum)
{
    int i = blockIdx.x * blockDim.x + threadIdx.x;
    if (i < N_NODES) row_ptr[i] += csum[i / SCAN_CHUNK];
    if (i == 0) row_ptr[N_NODES] = E_EXT;
}

__global__ __launch_bounds__(256) void scatter_kernel(
    const int* __restrict__ ei, const int* __restrict__ row_ptr,
    int* __restrict__ cur, int* __restrict__ esrc)
{
    int eid = blockIdx.x * blockDim.x + threadIdx.x;
    if (eid >= E_EXT) return;
    int s, d;
    if (eid < E_EDGES) { s = ei[eid]; d = ei[E_EDGES + eid]; }
    else { s = eid - E_EDGES; d = s; }
    int pos = row_ptr[d] + atomicAdd(&cur[d], 1);
    esrc[pos] = s;
}

// ------- heavy gather: 2 dst/wave, 8 ch/lane, 4-deep pipeline ---------------
__global__ __launch_bounds__(256) void gather_kernel(
    const int* __restrict__ row_ptr, const int* __restrict__ esrc,
    const ushort* __restrict__ hb,
    const float* __restrict__ a_s, const float* __restrict__ a_d,
    const float* __restrict__ bias,
    ushort* __restrict__ out_b)
{
    int wv = (blockIdx.x * blockDim.x + threadIdx.x) >> 6;
    int lane = threadIdx.x & 63;
    int half = lane >> 5;
    int lloc = lane & 31;
    int n = wv * 2 + half;
    if (n >= N_NODES) return;
    const int hh = lloc >> 2;
    const int shbase = half << 5;
    const float adv = a_d[n * NHEAD + hh];
    const int beg = row_ptr[n], end = row_ptr[n + 1];

    float a0=0.f,a1=0.f,a2=0.f,a3=0.f,a4=0.f,a5=0.f,a6=0.f,a7=0.f,den=0.f;

    for (int base = beg; base < end; base += 32) {
        int cnt = min(32, end - base);
        int sv = (base + lloc < end) ? esrc[base + lloc] : 0;
        int j = 0;
        for (; j + 4 <= cnt; j += 4) {
            int s0 = __shfl(sv, shbase + j);
            int s1 = __shfl(sv, shbase + j + 1);
            int s2 = __shfl(sv, shbase + j + 2);
            int s3 = __shfl(sv, shbase + j + 3);
            float e0 = a_s[s0 * NHEAD + hh];
            float e1 = a_s[s1 * NHEAD + hh];
            float e2 = a_s[s2 * NHEAD + hh];
            float e3 = a_s[s3 * NHEAD + hh];
            uint4 u0 = *(const uint4*)(hb + (size_t)s0 * HC + lloc * 8);
            uint4 u1 = *(const uint4*)(hb + (size_t)s1 * HC + lloc * 8);
            uint4 u2 = *(const uint4*)(hb + (size_t)s2 * HC + lloc * 8);
            uint4 u3 = *(const uint4*)(hb + (size_t)s3 * HC + lloc * 8);
            e0 += adv; e0 = (e0 > 0.f) ? e0 : 0.2f * e0; float w0 = __expf(e0);
            e1 += adv; e1 = (e1 > 0.f) ? e1 : 0.2f * e1; float w1 = __expf(e1);
            e2 += adv; e2 = (e2 > 0.f) ? e2 : 0.2f * e2; float w2 = __expf(e2);
            e3 += adv; e3 = (e3 > 0.f) ? e3 : 0.2f * e3; float w3 = __expf(e3);
            den += (w0 + w1) + (w2 + w3);
            a0 = fmaf(w0, bflo(u0.x), a0); a1 = fmaf(w0, bfhi(u0.x), a1);
            a2 = fmaf(w0, bflo(u0.y), a2); a3 = fmaf(w0, bfhi(u0.y), a3);
            a4 = fmaf(w0, bflo(u0.z), a4); a5 = fmaf(w0, bfhi(u0.z), a5);
            a6 = fmaf(w0, bflo(u0.w), a6); a7 = fmaf(w0, bfhi(u0.w), a7);
            a0 = fmaf(w1, bflo(u1.x), a0); a1 = fmaf(w1, bfhi(u1.x), a1);
            a2 = fmaf(w1, bflo(u1.y), a2); a3 = fmaf(w1, bfhi(u1.y), a3);
            a4 = fmaf(w1, bflo(u1.z), a4); a5 = fmaf(w1, bfhi(u1.z), a5);
            a6 = fmaf(w1, bflo(u1.w), a6); a7 = fmaf(w1, bfhi(u1.w), a7);
            a0 = fmaf(w2, bflo(u2.x), a0); a1 = fmaf(w2, bfhi(u2.x), a1);
            a2 = fmaf(w2, bflo(u2.y), a2); a3 = fmaf(w2, bfhi(u2.y), a3);
            a4 = fmaf(w2, bflo(u2.z), a4); a5 = fmaf(w2, bfhi(u2.z), a5);
            a6 = fmaf(w2, bflo(u2.w), a6); a7 = fmaf(w2, bfhi(u2.w), a7);
            a0 = fmaf(w3, bflo(u3.x), a0); a1 = fmaf(w3, bfhi(u3.x), a1);
            a2 = fmaf(w3, bflo(u3.y), a2); a3 = fmaf(w3, bfhi(u3.y), a3);
            a4 = fmaf(w3, bflo(u3.z), a4); a5 = fmaf(w3, bfhi(u3.z), a5);
            a6 = fmaf(w3, bflo(u3.w), a6); a7 = fmaf(w3, bfhi(u3.w), a7);
        }
        for (; j < cnt; j++) {
            int s = __shfl(sv, shbase + j);
            float e = a_s[s * NHEAD + hh] + adv;
            e = (e > 0.f) ? e : 0.2f * e;
            float w = __expf(e);
            den += w;
            uint4 u = *(const uint4*)(hb + (size_t)s * HC + lloc * 8);
            a0 = fmaf(w, bflo(u.x), a0); a1 = fmaf(w, bfhi(u.x), a1);
            a2 = fmaf(w, bflo(u.y), a2); a3 = fmaf(w, bfhi(u.y), a3);
            a4 = fmaf(w, bflo(u.z), a4); a5 = fmaf(w, bfhi(u.z), a5);
            a6 = fmaf(w, bflo(u.w), a6); a7 = fmaf(w, bfhi(u.w), a7);
        }
    }
    float inv = 1.f / den;
    float4 ba = *(const float4*)(bias + lloc * 8);
    float4 bb = *(const float4*)(bias + lloc * 8 + 4);
    float o0 = fmaf(a0, inv, ba.x), o1 = fmaf(a1, inv, ba.y);
    float o2 = fmaf(a2, inv, ba.z), o3 = fmaf(a3, inv, ba.w);
    float o4 = fmaf(a4, inv, bb.x), o5 = fmaf(a5, inv, bb.y);
    float o6 = fmaf(a6, inv, bb.z), o7 = fmaf(a7, inv, bb.w);
    o0 = fmaxf(o0, 0.f); o1 = fmaxf(o1, 0.f); o2 = fmaxf(o2, 0.f); o3 = fmaxf(o3, 0.f);
    o4 = fmaxf(o4, 0.f); o5 = fmaxf(o5, 0.f); o6 = fmaxf(o6, 0.f); o7 = fmaxf(o7, 0.f);
    uint4 ob;
    ob.x = (unsigned)f2bf(o0) | ((unsigned)f2bf(o1) << 16);
    ob.y = (unsigned)f2bf(o2) | ((unsigned)f2bf(o3) << 16);
    ob.z = (unsigned)f2bf(o4) | ((unsigned)f2bf(o5) << 16);
    ob.w = (unsigned)f2bf(o6) | ((unsigned)f2bf(o7) << 16);
    *(uint4*)(out_b + (size_t)n * HC + lloc * 8) = ob;
}

// ------- light gather (layer 3): thread per (dst,head), 8B per edge ---------
__global__ __launch_bounds__(256) void light_gather_kernel(
    const int* __restrict__ row_ptr, const int* __restrict__ esrc,
    const float2* __restrict__ q, const float* __restrict__ a_d,
    const float* __restrict__ bw, float* __restrict__ ndot)
{
    int idx = blockIdx.x * blockDim.x + threadIdx.x;
    if (idx >= N_NODES * NHEAD) return;
    int n = idx >> 3, hh = idx & 7;
    const float adv = a_d[idx];
    const int beg = row_ptr[n], end = row_ptr[n + 1];
    float acc = 0.f, den = 0.f;
    int e = beg;
    for (; e + 4 <= end; e += 4) {
        int s0 = esrc[e], s1 = esrc[e + 1], s2 = esrc[e + 2], s3 = esrc[e + 3];
        float2 q0 = q[s0 * NHEAD + hh];
        float2 q1 = q[s1 * NHEAD + hh];
        float2 q2 = q[s2 * NHEAD + hh];
        float2 q3 = q[s3 * NHEAD + hh];
        float t0 = q0.x + adv; t0 = (t0 > 0.f) ? t0 : 0.2f * t0; float w0 = __expf(t0);
        float t1 = q1.x + adv; t1 = (t1 > 0.f) ? t1 : 0.2f * t1; float w1 = __expf(t1);
        float t2 = q2.x + adv; t2 = (t2 > 0.f) ? t2 : 0.2f * t2; float w2 = __expf(t2);
        float t3 = q3.x + adv; t3 = (t3 > 0.f) ? t3 : 0.2f * t3; float w3 = __expf(t3);
        den += (w0 + w1) + (w2 + w3);
        acc = fmaf(w0, q0.y, acc); acc = fmaf(w1, q1.y, acc);
        acc = fmaf(w2, q2.y, acc); acc = fmaf(w3, q3.y, acc);
    }
    for (; e < end; e++) {
        int s = esrc[e];
        float2 qv = q[s * NHEAD + hh];
        float t = qv.x + adv; t = (t > 0.f) ? t : 0.2f * t;
        float w = __expf(t);
        den += w;
        acc = fmaf(w, qv.y, acc);
    }
    float p = acc / den + bw[hh];
    #pragma unroll
    for (int off = 4; off > 0; off >>= 1) p += __shfl_xor(p, off);
    if (hh == 0) ndot[n] = p;
}

// ------- per-graph mean over sorted batch (binary search, no atomics) -------
__global__ __launch_bounds__(256) void pool2_kernel(
    const float* __restrict__ ndot, const int* __restrict__ batch,
    const float* __restrict__ bf, float* __restrict__ outp)
{
    __shared__ float red[256];
    int g = blockIdx.x, t = threadIdx.x;
    int lo = 0, hi = N_NODES;
    while (lo < hi) { int mid = (lo + hi) >> 1; if (batch[mid] < g) lo = mid + 1; else hi = mid; }
    int start = lo;
    lo = 0; hi = N_NODES;
    while (lo < hi) { int mid = (lo + hi) >> 1; if (batch[mid] < g + 1) lo = mid + 1; else hi = mid; }
    int end = lo;
    float s = 0.f;
    for (int i = start + t; i < end; i += 256) s += ndot[i];
    red[t] = s;
    __syncthreads();
    for (int k = 128; k > 0; k >>= 1) {
        if (t < k) red[t] += red[t + k];
        __syncthreads();
    }
    if (t == 0) outp[g] = red[0] / fmaxf((float)(end - start), 1.f) + bf[0];
}

extern "C" void kernel_launch(void* const* d_in, const int* in_sizes, int n_in,
                              void* d_out, int out_size, void* d_ws, size_t ws_size,
                              hipStream_t stream)
{
    const float* x    = (const float*)d_in[0];
    const int*   ei   = (const int*)d_in[1];
    const int*   batch= (const int*)d_in[2];
    const float* W1   = (const float*)d_in[3];
    const float* as1  = (const float*)d_in[4];
    const float* ad1  = (const float*)d_in[5];
    const float* b1   = (const float*)d_in[6];
    const float* W2   = (const float*)d_in[7];
    const float* as2  = (const float*)d_in[8];
    const float* ad2  = (const float*)d_in[9];
    const float* b2   = (const float*)d_in[10];
    const float* W3   = (const float*)d_in[11];
    const float* as3  = (const float*)d_in[12];
    const float* ad3  = (const float*)d_in[13];
    const float* b3   = (const float*)d_in[14];
    const float* Wf   = (const float*)d_in[15];
    const float* bf   = (const float*)d_in[16];
    float* out = (float*)d_out;

    char* ws = (char*)d_ws;
    size_t off = 0;
    auto allocb = [&](size_t bytes) {
        void* p = ws + off;
        off += (bytes + 255) & ~(size_t)255;
        return p;
    };
    ushort* bufA    = (ushort*)allocb((size_t)N_NODES * HC * 2);
    ushort* bufB    = (ushort*)allocb((size_t)N_NODES * HC * 2);
    ushort* W1b     = (ushort*)allocb((size_t)HC * IN_CH * 2);
    ushort* W2b     = (ushort*)allocb((size_t)HC * HC * 2);
    ushort* W3b     = (ushort*)allocb((size_t)HC * HC * 2);
    ushort* Vb      = (ushort*)allocb((size_t)32 * HC * 2);
    float*  as_buf  = (float*) allocb((size_t)N_NODES * NHEAD * 4);
    float*  ad_buf  = (float*) allocb((size_t)N_NODES * NHEAD * 4);
    float2* q_buf   = (float2*)allocb((size_t)N_NODES * NHEAD * 8);
    float*  bw_buf  = (float*) allocb(NHEAD * 4);
    int*    deg     = (int*)   allocb(N_NODES * 4);      // deg+cur adjacent: one memset
    int*    cur     = (int*)   allocb(N_NODES * 4);
    int*    row_ptr = (int*)   allocb((N_NODES + 1) * 4);
    int*    csum    = (int*)   allocb(64 * 4);
    int*    esrc    = (int*)   allocb(E_EXT * 4);
    float*  ndot    = (float*) allocb(N_NODES * 4);
    (void)ws_size; (void)in_sizes; (void)n_in; (void)out_size;

    // ---- weight bf16 conversion + bw + layer-3 composite vectors ----
    cvt_weights_kernel<<<(CVT_N4 + COMP_N + 255) / 256, 256, 0, stream>>>(
        W1, W2, W3, W1b, W2b, W3b, as3, ad3, b3, Wf, bw_buf, Vb);

    // ---- CSR build ----
    const size_t deg_pad = ((size_t)N_NODES * 4 + 255) & ~(size_t)255;
    hipMemsetAsync(deg, 0, deg_pad + (size_t)N_NODES * 4, stream);  // deg + cur
    hist_kernel<<<(E_EXT + 255) / 256, 256, 0, stream>>>(ei, deg);
    scan1_kernel<<<N_CHUNKS, SCAN_CHUNK, 0, stream>>>(deg, row_ptr, csum);
    scan2_kernel<<<1, 64, 0, stream>>>(csum);
    scan3_kernel<<<(N_NODES + 255) / 256, 256, 0, stream>>>(row_ptr, csum);
    scatter_kernel<<<(E_EXT + 255) / 256, 256, 0, stream>>>(ei, row_ptr, cur, esrc);

    dim3 ggrid((N_NODES + 127) / 128, HC / 128);
    const int gather_blocks = (((N_NODES + 1) / 2) * 64 + 255) / 256;

    // layer 1: x(f32) -> B(h1 + a_s/a_d) -> A(h1')
    mfma_gemm_kernel<<<ggrid, 256, 0, stream>>>(
        nullptr, x, W1b, bufB, N_NODES, IN_CH, as1, ad1, as_buf, ad_buf);
    gather_kernel<<<gather_blocks, 256, 0, stream>>>(
        row_ptr, esrc, bufB, as_buf, ad_buf, b1, bufA);
    // layer 2: A -> B(h2 + a_s/a_d) -> A
    mfma_gemm_kernel<<<ggrid, 256, 0, stream>>>(
        bufA, nullptr, W2b, bufB, N_NODES, HC, as2, ad2, as_buf, ad_buf);
    gather_kernel<<<gather_blocks, 256, 0, stream>>>(
        row_ptr, esrc, bufB, as_buf, ad_buf, b2, bufA);
    // layer 3: thin GEMM A @ Vb^T -> q/a_d directly, then light gather
    gemm3_kernel<<<(N_NODES + 127) / 128, 256, 0, stream>>>(
        bufA, Vb, N_NODES, q_buf, ad_buf);
    light_gather_kernel<<<(N_NODES * NHEAD + 255) / 256, 256, 0, stream>>>(
        row_ptr, esrc, q_buf, ad_buf, bw_buf, ndot);

    pool2_kernel<<<NGRAPH, 256, 0, stream>>>(ndot, batch, bf, out);
}